// Round 5
// baseline (1095.090 us; speedup 1.0000x reference)
//
#include <hip/hip_runtime.h>
#include <cstdint>
#include <cstddef>

// ---------------- problem constants ----------------
#define NU_C   20000
#define NI_C   8000
#define NTOT_C 28000          // NU+NI
#define NE_C   200000
#define B_C    4096
#define NPAD_C 8064           // NI padded to 63*128 rows
#define NCHUNK 63
#define NPAIR  2016           // 63*64/2 upper-triangle chunk pairs

typedef unsigned short u16;
typedef unsigned int   u32;
typedef unsigned char  u8;
typedef __bf16 bf16x8 __attribute__((ext_vector_type(8)));
typedef float  f32x4  __attribute__((ext_vector_type(4)));

static __device__ __forceinline__ u16 f2bf(float f) {
  u32 u = __float_as_uint(f);
  return (u16)((u + 0x7fffu + ((u >> 16) & 1u)) >> 16);   // RNE
}

// async global->LDS, 16B per lane; LDS dest is wave-uniform base + lane*16
static __device__ __forceinline__ void gl_lds16(const void* g, void* l) {
  __builtin_amdgcn_global_load_lds(
      (const __attribute__((address_space(1))) void*)g,
      (__attribute__((address_space(3))) void*)l, 16, 0, 0);
}

// XCD-chunked block swizzle (T1). Sub-blocks sit at blockIdx 0..NPAIR-1 of the
// fused grids, so the physical dispatch pattern matches the standalone launch.
static __device__ __forceinline__ int xcd_swz(int b) {
  return (b & 7) * (NPAIR / 8) + (b >> 3);
}

// ---------------- bf16/fp8 convert + row 1/norm, both modalities ----------------
__global__ void conv_kernel2(const float* __restrict__ Fv, const float* __restrict__ Ft,
                             u16* __restrict__ Fbv, u16* __restrict__ Fbt,
                             u8* __restrict__ Fv8,
                             float* __restrict__ rnv, float* __restrict__ rnt) {
  int b = blockIdx.x;
  const int tid = threadIdx.x;
  float ss = 0.f;
  if (b < NPAD_C) {                                       // modality v, D=4096
    const int row = b;
    u16* dst  = Fbv + (size_t)row * 4096;
    u8*  dst8 = Fv8 + (size_t)row * 4096;
    if (row < NI_C) {
      const float* src = Fv + (size_t)row * 4096;
      for (int c = tid * 4; c < 4096; c += 1024) {
        float4 f = *(const float4*)(src + c);
        ss += f.x*f.x + f.y*f.y + f.z*f.z + f.w*f.w;
        ushort4 v; v.x = f2bf(f.x); v.y = f2bf(f.y); v.z = f2bf(f.z); v.w = f2bf(f.w);
        *(ushort4*)(dst + c) = v;
        int w8 = __builtin_amdgcn_cvt_pk_fp8_f32(f.x, f.y, 0, false);
        w8 = __builtin_amdgcn_cvt_pk_fp8_f32(f.z, f.w, w8, true);
        *(u32*)(dst8 + c) = (u32)w8;
      }
    } else {
      for (int c = tid * 4; c < 4096; c += 1024) {
        ushort4 v; v.x = v.y = v.z = v.w = 0;
        *(ushort4*)(dst + c) = v;
        *(u32*)(dst8 + c) = 0u;
      }
    }
    #pragma unroll
    for (int off = 32; off; off >>= 1) ss += __shfl_xor(ss, off);
    __shared__ float red[4];
    if ((tid & 63) == 0) red[tid >> 6] = ss;
    __syncthreads();
    if (tid == 0) {
      float s = red[0] + red[1] + red[2] + red[3];
      rnv[row] = (row < NI_C) ? rsqrtf(s) : 0.f;
    }
  } else {                                                // modality t, D=768
    const int row = b - NPAD_C;
    u16* dst = Fbt + (size_t)row * 768;
    if (row < NI_C) {
      const float* src = Ft + (size_t)row * 768;
      for (int c = tid * 4; c < 768; c += 1024) {
        float4 f = *(const float4*)(src + c);
        ss += f.x*f.x + f.y*f.y + f.z*f.z + f.w*f.w;
        ushort4 v; v.x = f2bf(f.x); v.y = f2bf(f.y); v.z = f2bf(f.z); v.w = f2bf(f.w);
        *(ushort4*)(dst + c) = v;
      }
    } else {
      for (int c = tid * 4; c < 768; c += 1024) {
        ushort4 v; v.x = v.y = v.z = v.w = 0;
        *(ushort4*)(dst + c) = v;
      }
    }
    #pragma unroll
    for (int off = 32; off; off >>= 1) ss += __shfl_xor(ss, off);
    __shared__ float red[4];
    if ((tid & 63) == 0) red[tid >> 6] = ss;
    __syncthreads();
    if (tid == 0) {
      float s = red[0] + red[1] + red[2] + red[3];
      rnt[row] = (row < NI_C) ? rsqrtf(s) : 0.f;
    }
  }
}

// ---------------- fp8 symmetric fused Gram + top-10 body (v-graph, D=4096) ----------------
// r2/r4 structure: BK=128 single-buffer, 2 barriers per 128-K tile, seg-swizzled
// LDS, XCD-chunked pair map. Selection numerics identical to the standalone kernel.
static __device__ __forceinline__ void simtopk_fp8_body(
    int bid, char* smem, const u8* __restrict__ F, const float* __restrict__ rn,
    u32* __restrict__ tv) {
  u8*    sB   = (u8*)smem;                   // I rows, cols [k0,k0+64)    [128][64B]
  u8*    sA   = (u8*)(smem + 16384);         // J rows, cols [k0,k0+64)    [128][64B]
  // region +8192 within each: cols [k0+64,k0+128), same layout
  float* T    = (float*)smem;                // transpose [128][66] = 33792 B (epilogue)
  int*   mk   = (int*)smem;                  // merge dump [128][40] (epilogue)
  int*   mk2  = (int*)(smem + 20480);        // repacked [128][10] (epilogue)
  float* sRNI = (float*)(smem + 33792);
  float* sRNJ = (float*)(smem + 34304);

  const int tid  = threadIdx.x;
  const int lane = tid & 63;
  const int wv   = tid >> 6;
  const int n15  = lane & 15;
  const int quad = lane >> 4;

  int I = 0, rem = xcd_swz(bid);
  { int rowlen = NCHUNK;
    while (rem >= rowlen) { rem -= rowlen; rowlen--; I++; } }
  const int J = I + rem;

  const int l2   = lane >> 2;
  const int lseg = (lane & 3) ^ (l2 & 3) ^ (lane >> 4);   // logical seg to fetch
  const u8* gB[2]; const u8* gA[2]; u8* lB[2]; u8* lA[2];
  #pragma unroll
  for (int rep = 0; rep < 2; ++rep) {
    int row = wv * 32 + rep * 16 + l2;
    gB[rep] = F + (size_t)(I * 128 + row) * 4096 + lseg * 16;
    gA[rep] = F + (size_t)(J * 128 + row) * 4096 + lseg * 16;
    lB[rep] = sB + (wv * 32 + rep * 16) * 64;
    lA[rep] = sA + (wv * 32 + rep * 16) * 64;
  }
  const int s_n = (n15 & 3) ^ (n15 >> 2);
  const int q2  = quad >> 1;
  const int q8  = (quad & 1) * 8;
  const int rB0 = (wv * 32 + n15) * 64;
  const int rB1 = rB0 + 16 * 64;

  f32x4 acc[2][8];
  #pragma unroll
  for (int tf = 0; tf < 2; ++tf)
    #pragma unroll
    for (int af = 0; af < 8; ++af) { f32x4 z = {0.f,0.f,0.f,0.f}; acc[tf][af] = z; }

  for (int k0 = 0; k0 < 4096; k0 += 128) {
    __syncthreads();
    gl_lds16(gB[0] + k0,      lB[0]);
    gl_lds16(gB[0] + k0 + 64, lB[0] + 8192);
    gl_lds16(gB[1] + k0,      lB[1]);
    gl_lds16(gB[1] + k0 + 64, lB[1] + 8192);
    gl_lds16(gA[0] + k0,      lA[0]);
    gl_lds16(gA[0] + k0 + 64, lA[0] + 8192);
    gl_lds16(gA[1] + k0,      lA[1]);
    gl_lds16(gA[1] + k0 + 64, lA[1] + 8192);
    if (k0 == 0) {
      if (tid < 128) sRNJ[tid] = rn[J * 128 + tid];
      else           sRNI[tid - 128] = rn[I * 128 + (tid - 128)];
    }
    __syncthreads();
    #pragma unroll
    for (int ksub = 0; ksub < 2; ++ksub) {
      const u8* bBase = sB + ksub * 8192;
      const u8* aBase = sA + ksub * 8192;
      #pragma unroll
      for (int ks = 0; ks < 2; ++ks) {
        const int sw = (((ks * 2 + q2) ^ s_n) << 4) + q8;
        long long b0 = *(const long long*)(bBase + rB0 + sw);
        long long b1 = *(const long long*)(bBase + rB1 + sw);
        #pragma unroll
        for (int af = 0; af < 8; ++af) {
          long long a = *(const long long*)(aBase + (af * 16 + n15) * 64 + sw);
          acc[0][af] = __builtin_amdgcn_mfma_f32_16x16x32_fp8_fp8(a, b0, acc[0][af], 0, 0, 0);
          acc[1][af] = __builtin_amdgcn_mfma_f32_16x16x32_fp8_fp8(a, b1, acc[1][af], 0, 0, 0);
        }
      }
    }
  }

  // ---- I-side: target rows in I, cands in J ----
  int bk[2][10];
  #pragma unroll
  for (int tf = 0; tf < 2; ++tf)
    #pragma unroll
    for (int j = 0; j < 10; ++j) bk[tf][j] = 0;

  #pragma unroll
  for (int af = 0; af < 8; ++af) {
    const float4 rn4 = *(const float4*)(sRNJ + af * 16 + quad * 4);
    const float rna[4] = {rn4.x, rn4.y, rn4.z, rn4.w};
    #pragma unroll
    for (int r = 0; r < 4; ++r) {
      const int ci = J * 128 + af * 16 + quad * 4 + r;
      #pragma unroll
      for (int tf = 0; tf < 2; ++tf) {
        float v = acc[tf][af][r] * rna[r];
        int key = (int)((__float_as_uint(v) & 0xFFFFE000u) | (u32)ci);
        if (ci < NI_C && key > bk[tf][9]) {
          bk[tf][9] = key;
          #pragma unroll
          for (int j = 9; j > 0; --j)
            if (bk[tf][j] > bk[tf][j-1]) { int t = bk[tf][j]; bk[tf][j] = bk[tf][j-1]; bk[tf][j-1] = t; }
        }
      }
    }
  }
  __syncthreads();
  #pragma unroll
  for (int tf = 0; tf < 2; ++tf) {
    int rl = wv * 32 + tf * 16 + n15;
    #pragma unroll
    for (int j = 0; j < 10; ++j) mk[rl * 40 + quad * 10 + j] = bk[tf][j];
  }
  __syncthreads();
  if (tid < 128) {                            // 4-way sorted-list tournament
    int* m = mk + tid * 40;
    int h0 = 0, h1 = 10, h2 = 20, h3 = 30;
    int v0 = m[0], v1 = m[10], v2 = m[20], v3 = m[30];
    #pragma unroll
    for (int s = 0; s < 10; ++s) {
      int m01 = v0 > v1 ? v0 : v1, m23 = v2 > v3 ? v2 : v3;
      int mx = m01 > m23 ? m01 : m23;
      mk2[tid * 10 + s] = mx;
      if      (mx == v0) { ++h0; v0 = (h0 < 10) ? m[h0] : (int)0x80000000; }
      else if (mx == v1) { ++h1; v1 = (h1 < 20) ? m[h1] : (int)0x80000000; }
      else if (mx == v2) { ++h2; v2 = (h2 < 30) ? m[h2] : (int)0x80000000; }
      else               { ++h3; v3 = (h3 < 40) ? m[h3] : (int)0x80000000; }
    }
  }
  __syncthreads();
  { u32* o = tv + ((size_t)J * NPAD_C + I * 128) * 10;
    for (int g = tid; g < 1280; g += 256) o[g] = (u32)mk2[g]; }

  if (I == J) return;

  // ---- J-side: target rows in J, cands in I (via transpose) ----
  int bj[2][10];
  #pragma unroll
  for (int s = 0; s < 2; ++s)
    #pragma unroll
    for (int j = 0; j < 10; ++j) bj[s][j] = 0;

  #pragma unroll
  for (int tf = 0; tf < 2; ++tf) {
    __syncthreads();
    #pragma unroll
    for (int af = 0; af < 8; ++af)
      #pragma unroll
      for (int r = 0; r < 4; ++r)
        T[(af * 16 + quad * 4 + r) * 66 + wv * 16 + n15] = acc[tf][af][r];
    __syncthreads();
    #pragma unroll
    for (int s = 0; s < 2; ++s) {
      const int c_own = wv * 32 + s * 16 + n15;
      #pragma unroll
      for (int j = 0; j < 16; ++j) {
        const int t  = quad * 32 + tf * 16 + j;
        const int t64 = quad * 16 + j;
        float v = T[c_own * 66 + t64] * sRNI[t];
        const int ti = I * 128 + t;
        int key = (int)((__float_as_uint(v) & 0xFFFFE000u) | (u32)ti);
        if (ti < NI_C && key > bj[s][9]) {
          bj[s][9] = key;
          #pragma unroll
          for (int q = 9; q > 0; --q)
            if (bj[s][q] > bj[s][q-1]) { int tt = bj[s][q]; bj[s][q] = bj[s][q-1]; bj[s][q-1] = tt; }
        }
      }
    }
  }
  __syncthreads();
  #pragma unroll
  for (int s = 0; s < 2; ++s) {
    int rl = wv * 32 + s * 16 + n15;
    #pragma unroll
    for (int j = 0; j < 10; ++j) mk[rl * 40 + quad * 10 + j] = bj[s][j];
  }
  __syncthreads();
  if (tid < 128) {
    int* m = mk + tid * 40;
    int h0 = 0, h1 = 10, h2 = 20, h3 = 30;
    int v0 = m[0], v1 = m[10], v2 = m[20], v3 = m[30];
    #pragma unroll
    for (int s = 0; s < 10; ++s) {
      int m01 = v0 > v1 ? v0 : v1, m23 = v2 > v3 ? v2 : v3;
      int mx = m01 > m23 ? m01 : m23;
      mk2[tid * 10 + s] = mx;
      if      (mx == v0) { ++h0; v0 = (h0 < 10) ? m[h0] : (int)0x80000000; }
      else if (mx == v1) { ++h1; v1 = (h1 < 20) ? m[h1] : (int)0x80000000; }
      else if (mx == v2) { ++h2; v2 = (h2 < 30) ? m[h2] : (int)0x80000000; }
      else               { ++h3; v3 = (h3 < 40) ? m[h3] : (int)0x80000000; }
    }
  }
  __syncthreads();
  { u32* o = tv + ((size_t)I * NPAD_C + J * 128) * 10;
    for (int g = tid; g < 1280; g += 256) o[g] = (u32)mk2[g]; }
}

// ---------------- bf16 symmetric fused Gram + top-10 body (t-graph, D=768) ----------------
static __device__ __forceinline__ void simtopk_bf16_body(
    int bid, char* smem, const u16* __restrict__ F, const float* __restrict__ rn,
    u32* __restrict__ tv) {
  u16*   sB   = (u16*)smem;
  u16*   sA   = (u16*)(smem + 16384);
  float* T    = (float*)smem;
  int*   mk   = (int*)smem;
  int*   mk2  = (int*)(smem + 20480);
  float* sRNI = (float*)(smem + 34816);
  float* sRNJ = (float*)(smem + 35328);

  const int tid  = threadIdx.x;
  const int lane = tid & 63;
  const int wv   = tid >> 6;
  const int n15  = lane & 15;
  const int quad = lane >> 4;

  int I = 0, rem = xcd_swz(bid);
  { int rowlen = NCHUNK;
    while (rem >= rowlen) { rem -= rowlen; rowlen--; I++; } }
  const int J = I + rem;

  const int l8  = lane >> 3;
  const int sgu = ((lane & 7) ^ l8) << 3;
  const u16* gB[4]; const u16* gA[4]; u16* lB[4]; u16* lA[4];
  #pragma unroll
  for (int rep = 0; rep < 4; ++rep) {
    int row = wv * 32 + rep * 8 + l8;
    gB[rep] = F + (size_t)(I * 128 + row) * 768 + sgu;
    gA[rep] = F + (size_t)(J * 128 + row) * 768 + sgu;
    lB[rep] = sB + wv * 2048 + rep * 512;
    lA[rep] = sA + wv * 2048 + rep * 512;
  }
  const int swu0 = ((quad    ) ^ (n15 & 7)) << 3;
  const int swu1 = ((quad + 4) ^ (n15 & 7)) << 3;
  const int rowB0 = (wv * 32 + n15) * 64;
  const int rowB1 = rowB0 + 16 * 64;

  f32x4 acc[2][8];
  #pragma unroll
  for (int tf = 0; tf < 2; ++tf)
    #pragma unroll
    for (int af = 0; af < 8; ++af) { f32x4 z = {0.f,0.f,0.f,0.f}; acc[tf][af] = z; }

  for (int k0 = 0; k0 < 768; k0 += 64) {
    __syncthreads();
    #pragma unroll
    for (int rep = 0; rep < 4; ++rep) gl_lds16(gB[rep] + k0, lB[rep]);
    #pragma unroll
    for (int rep = 0; rep < 4; ++rep) gl_lds16(gA[rep] + k0, lA[rep]);
    if (k0 == 0) {
      if (tid < 128) sRNJ[tid] = rn[J * 128 + tid];
      else           sRNI[tid - 128] = rn[I * 128 + (tid - 128)];
    }
    __syncthreads();
    #pragma unroll
    for (int ks = 0; ks < 2; ++ks) {
      const int swu = ks ? swu1 : swu0;
      bf16x8 b0 = *(const bf16x8*)(sB + rowB0 + swu);
      bf16x8 b1 = *(const bf16x8*)(sB + rowB1 + swu);
      #pragma unroll
      for (int af = 0; af < 8; ++af) {
        bf16x8 a = *(const bf16x8*)(sA + (af * 16 + n15) * 64 + swu);
        acc[0][af] = __builtin_amdgcn_mfma_f32_16x16x32_bf16(a, b0, acc[0][af], 0, 0, 0);
        acc[1][af] = __builtin_amdgcn_mfma_f32_16x16x32_bf16(a, b1, acc[1][af], 0, 0, 0);
      }
    }
  }

  int bk[2][10];
  #pragma unroll
  for (int tf = 0; tf < 2; ++tf)
    #pragma unroll
    for (int j = 0; j < 10; ++j) bk[tf][j] = 0;

  #pragma unroll
  for (int af = 0; af < 8; ++af) {
    const float4 rn4 = *(const float4*)(sRNJ + af * 16 + quad * 4);
    const float rna[4] = {rn4.x, rn4.y, rn4.z, rn4.w};
    #pragma unroll
    for (int r = 0; r < 4; ++r) {
      const int ci = J * 128 + af * 16 + quad * 4 + r;
      #pragma unroll
      for (int tf = 0; tf < 2; ++tf) {
        float v = acc[tf][af][r] * rna[r];
        int key = (int)((__float_as_uint(v) & 0xFFFFE000u) | (u32)ci);
        if (ci < NI_C && key > bk[tf][9]) {
          bk[tf][9] = key;
          #pragma unroll
          for (int j = 9; j > 0; --j)
            if (bk[tf][j] > bk[tf][j-1]) { int t = bk[tf][j]; bk[tf][j] = bk[tf][j-1]; bk[tf][j-1] = t; }
        }
      }
    }
  }
  __syncthreads();
  #pragma unroll
  for (int tf = 0; tf < 2; ++tf) {
    int rl = wv * 32 + tf * 16 + n15;
    #pragma unroll
    for (int j = 0; j < 10; ++j) mk[rl * 40 + quad * 10 + j] = bk[tf][j];
  }
  __syncthreads();
  if (tid < 128) {
    int* m = mk + tid * 40;
    int h0 = 0, h1 = 10, h2 = 20, h3 = 30;
    int v0 = m[0], v1 = m[10], v2 = m[20], v3 = m[30];
    #pragma unroll
    for (int s = 0; s < 10; ++s) {
      int m01 = v0 > v1 ? v0 : v1, m23 = v2 > v3 ? v2 : v3;
      int mx = m01 > m23 ? m01 : m23;
      mk2[tid * 10 + s] = mx;
      if      (mx == v0) { ++h0; v0 = (h0 < 10) ? m[h0] : (int)0x80000000; }
      else if (mx == v1) { ++h1; v1 = (h1 < 20) ? m[h1] : (int)0x80000000; }
      else if (mx == v2) { ++h2; v2 = (h2 < 30) ? m[h2] : (int)0x80000000; }
      else               { ++h3; v3 = (h3 < 40) ? m[h3] : (int)0x80000000; }
    }
  }
  __syncthreads();
  { u32* o = tv + ((size_t)J * NPAD_C + I * 128) * 10;
    for (int g = tid; g < 1280; g += 256) o[g] = (u32)mk2[g]; }

  if (I == J) return;

  int bj[2][10];
  #pragma unroll
  for (int s = 0; s < 2; ++s)
    #pragma unroll
    for (int j = 0; j < 10; ++j) bj[s][j] = 0;

  #pragma unroll
  for (int tf = 0; tf < 2; ++tf) {
    __syncthreads();
    #pragma unroll
    for (int af = 0; af < 8; ++af)
      #pragma unroll
      for (int r = 0; r < 4; ++r)
        T[(af * 16 + quad * 4 + r) * 66 + wv * 16 + n15] = acc[tf][af][r];
    __syncthreads();
    #pragma unroll
    for (int s = 0; s < 2; ++s) {
      const int c_own = wv * 32 + s * 16 + n15;
      #pragma unroll
      for (int j = 0; j < 16; ++j) {
        const int t  = quad * 32 + tf * 16 + j;
        const int t64 = quad * 16 + j;
        float v = T[c_own * 66 + t64] * sRNI[t];
        const int ti = I * 128 + t;
        int key = (int)((__float_as_uint(v) & 0xFFFFE000u) | (u32)ti);
        if (ti < NI_C && key > bj[s][9]) {
          bj[s][9] = key;
          #pragma unroll
          for (int q = 9; q > 0; --q)
            if (bj[s][q] > bj[s][q-1]) { int tt = bj[s][q]; bj[s][q] = bj[s][q-1]; bj[s][q-1] = tt; }
        }
      }
    }
  }
  __syncthreads();
  #pragma unroll
  for (int s = 0; s < 2; ++s) {
    int rl = wv * 32 + s * 16 + n15;
    #pragma unroll
    for (int j = 0; j < 10; ++j) mk[rl * 40 + quad * 10 + j] = bj[s][j];
  }
  __syncthreads();
  if (tid < 128) {
    int* m = mk + tid * 40;
    int h0 = 0, h1 = 10, h2 = 20, h3 = 30;
    int v0 = m[0], v1 = m[10], v2 = m[20], v3 = m[30];
    #pragma unroll
    for (int s = 0; s < 10; ++s) {
      int m01 = v0 > v1 ? v0 : v1, m23 = v2 > v3 ? v2 : v3;
      int mx = m01 > m23 ? m01 : m23;
      mk2[tid * 10 + s] = mx;
      if      (mx == v0) { ++h0; v0 = (h0 < 10) ? m[h0] : (int)0x80000000; }
      else if (mx == v1) { ++h1; v1 = (h1 < 20) ? m[h1] : (int)0x80000000; }
      else if (mx == v2) { ++h2; v2 = (h2 < 30) ? m[h2] : (int)0x80000000; }
      else               { ++h3; v3 = (h3 < 40) ? m[h3] : (int)0x80000000; }
    }
  }
  __syncthreads();
  { u32* o = tv + ((size_t)I * NPAD_C + J * 128) * 10;
    for (int g = tid; g < 1280; g += 256) o[g] = (u32)mk2[g]; }
}

// ---------------- merge: 63 sorted lists x 10 -> top-10, 4 rows per 256-thr block ----
static __device__ __forceinline__ void merge4_body(int mb, int* fkbase,
                                                   const u32* __restrict__ tv,
                                                   int* __restrict__ idx) {
  const int w    = threadIdx.x >> 6;
  const int lane = threadIdx.x & 63;
  const int row  = mb * 4 + w;
  int* fk = fkbase + w * 640;
  for (int g = lane; g < 630; g += 64)
    fk[g] = (int)tv[((size_t)(g / 10) * NPAD_C + row) * 10 + (g % 10)];
  if (lane < 10) fk[630 + lane] = (int)0x80000000;
  __syncthreads();
  int v[10];
  #pragma unroll
  for (int j = 0; j < 10; ++j) v[j] = fk[lane + j * 64];
  #pragma unroll 1
  for (int s = 0; s < 10; ++s) {
    int loc = v[0];
    #pragma unroll
    for (int j = 1; j < 10; ++j) loc = v[j] > loc ? v[j] : loc;
    #pragma unroll
    for (int off = 32; off; off >>= 1) {
      int o = __shfl_xor(loc, off); loc = o > loc ? o : loc;
    }
    if (lane == 0) idx[row * 10 + s] = loc & 0x1FFF;
    #pragma unroll
    for (int j = 0; j < 10; ++j) if (v[j] == loc) v[j] = (int)0x80000000;
  }
}

__launch_bounds__(256)
__global__ void merge4_kernel(const u32* __restrict__ tv, int* __restrict__ idx) {
  __shared__ int fk[4 * 640];
  merge4_body(blockIdx.x, fk, tv, idx);
}

// ---------------- feat @ W via bf16 MFMA body, M=64 tiles ----------------
template<int D>
static __device__ __forceinline__ void gemm_xw_body(
    int bid, char* smem, const u16* __restrict__ F, const u16* __restrict__ Wt,
    float* __restrict__ x2, int modeoff) {
  u16* sF = (u16*)smem;                      // 8192 B
  const int tid  = threadIdx.x;
  const int lane = tid & 63;
  const int wv   = tid >> 6;
  const int n15  = lane & 15;
  const int quad = lane >> 4;
  const int l8   = lane >> 3;
  const int sgu  = ((lane & 7) ^ l8) << 3;
  const u16* gF[2]; u16* lF[2];
  #pragma unroll
  for (int rep = 0; rep < 2; ++rep) {
    int row = rep * 32 + wv * 8 + l8;
    gF[rep] = F + (size_t)(bid * 64 + row) * D + sgu;
    lF[rep] = sF + (rep * 32 + wv * 8) * 64;
  }
  const int swu0 = ((quad    ) ^ (n15 & 7)) << 3;
  const int swu1 = ((quad + 4) ^ (n15 & 7)) << 3;

  f32x4 acc[4];
  #pragma unroll
  for (int nf = 0; nf < 4; ++nf) { f32x4 z = {0.f,0.f,0.f,0.f}; acc[nf] = z; }

  for (int k0 = 0; k0 < D; k0 += 64) {
    __syncthreads();
    gl_lds16(gF[0] + k0, lF[0]);
    gl_lds16(gF[1] + k0, lF[1]);
    __syncthreads();
    #pragma unroll
    for (int ks = 0; ks < 2; ++ks) {
      const int swu = ks ? swu1 : swu0;
      bf16x8 a = *(const bf16x8*)(sF + (wv * 16 + n15) * 64 + swu);
      #pragma unroll
      for (int nf = 0; nf < 4; ++nf) {
        bf16x8 b = *(const bf16x8*)(Wt + (size_t)(nf * 16 + n15) * D + k0 + ks * 32 + quad * 8);
        acc[nf] = __builtin_amdgcn_mfma_f32_16x16x32_bf16(a, b, acc[nf], 0, 0, 0);
      }
    }
  }
  #pragma unroll
  for (int nf = 0; nf < 4; ++nf)
    #pragma unroll
    for (int r = 0; r < 4; ++r) {
      int row = bid * 64 + wv * 16 + quad * 4 + r;
      if (row < NI_C)
        x2[(size_t)(NU_C + row) * 128 + modeoff + nf * 16 + n15] = acc[nf][r];
    }
}

// ---------------- gather bodies ----------------
static __device__ __forceinline__ void gather2_body(
    int bid, const int* __restrict__ row_start, const int* __restrict__ esrc,
    const float* __restrict__ ew, const float* __restrict__ x2, float* __restrict__ h1) {
  const int node = bid * 2 + (threadIdx.x >> 7);
  const int ch   = threadIdx.x & 127;
  if (node >= NTOT_C) return;
  const int b = row_start[node], e = row_start[node + 1];
  float acc = 0.f;
  for (int i = b; i < e; ++i)
    acc += ew[i] * x2[(size_t)esrc[i] * 128 + ch];
  h1[(size_t)node * 128 + ch] = acc;
}

static __device__ __forceinline__ void gather_comb2_body(
    int bid, const int* __restrict__ row_start, const int* __restrict__ esrc,
    const float* __restrict__ ew, const float* __restrict__ x2,
    const float* __restrict__ h1, const float* __restrict__ alpha,
    float* __restrict__ uf, float* __restrict__ ifb) {
  const int node = bid * 2 + (threadIdx.x >> 7);
  const int ch   = threadIdx.x & 127;
  if (node >= NTOT_C) return;
  const int b = row_start[node], e = row_start[node + 1];
  float acc = 0.f;
  for (int i = b; i < e; ++i)
    acc += ew[i] * h1[(size_t)esrc[i] * 128 + ch];
  float val = x2[(size_t)node * 128 + ch] + h1[(size_t)node * 128 + ch] + acc;
  if (node < NU_C) {
    float av = 1.f / (1.f + expf(-alpha[0]));
    float coef = (ch < 64) ? av : (1.f - av);
    uf[(size_t)node * 128 + ch] = coef * val;
  } else {
    ifb[(size_t)(node - NU_C) * 128 + ch] = val;
  }
}

// ---------------- fused launches (horizontal concurrency on one stream) -------------
// F1: simtopk_fp8 (long pole, blocks 0..2015 so XCD swizzle/dispatch matches the
//     standalone launch) ++ gemm_xw<4096> ++ gemm_xw<768> ++ fill_pref.
__launch_bounds__(256)
__global__ void fusedA_kernel(const u8* __restrict__ F8, const float* __restrict__ rnv,
                              u32* __restrict__ tv,
                              const u16* __restrict__ Fvb, const u16* __restrict__ Wtv,
                              const u16* __restrict__ Ftb, const u16* __restrict__ Wtt,
                              float* __restrict__ x2,
                              const float* __restrict__ pv, const float* __restrict__ pt) {
  __shared__ __align__(16) char smem[34816];
  int b = blockIdx.x;
  if (b < NPAIR) { simtopk_fp8_body(b, smem, F8, rnv, tv); return; }
  b -= NPAIR;
  if (b < 125) { gemm_xw_body<4096>(b, smem, Fvb, Wtv, x2, 0); return; }
  b -= 125;
  if (b < 125) { gemm_xw_body<768>(b, smem, Ftb, Wtt, x2, 64); return; }
  b -= 125;
  { // fill_pref: x2 user rows = pref_v | pref_t
    int gid = b * 256 + threadIdx.x;
    int u = gid >> 7, c = gid & 127;
    x2[gid] = (c < 64) ? pv[(size_t)u * 64 + c] : pt[(size_t)u * 64 + (c - 64)];
  }
}

// F2: gather2 (h1 = A @ x2) ++ merge_v (consumes tvb from F1).
__launch_bounds__(256)
__global__ void fusedB_kernel(const int* __restrict__ row_start, const int* __restrict__ esrc,
                              const float* __restrict__ ew, const float* __restrict__ x2,
                              float* __restrict__ h1,
                              const u32* __restrict__ tv, int* __restrict__ idx) {
  __shared__ int fk[4 * 640];
  int b = blockIdx.x;
  if (b < 14000) { gather2_body(b, row_start, esrc, ew, x2, h1); return; }
  merge4_body(b - 14000, fk, tv, idx);
}

// F3: simtopk_t (blocks 0..2015, tvb relocated to dead fvbf buffer) ++ gather_comb2.
__launch_bounds__(256)
__global__ void fusedC_kernel(const u16* __restrict__ Ftb, const float* __restrict__ rnt,
                              u32* __restrict__ tv2,
                              const int* __restrict__ row_start, const int* __restrict__ esrc,
                              const float* __restrict__ ew, const float* __restrict__ x2,
                              const float* __restrict__ h1, const float* __restrict__ alpha,
                              float* __restrict__ uf, float* __restrict__ ifb) {
  __shared__ __align__(16) char smem[40960];
  int b = blockIdx.x;
  if (b < NPAIR) { simtopk_bf16_body(b, smem, Ftb, rnt, tv2); return; }
  gather_comb2_body(b - NPAIR, row_start, esrc, ew, x2, h1, alpha, uf, ifb);
}

// ---------------- CSR build ----------------
__global__ void deg_count_kernel(const int* __restrict__ eu, const int* __restrict__ ei,
                                 float* deg) {
  int e = blockIdx.x * 256 + threadIdx.x;
  if (e < NE_C) {
    atomicAdd(&deg[eu[e]], 1.f);
    atomicAdd(&deg[NU_C + ei[e]], 1.f);
  }
}

__global__ void scan_kernel(float* __restrict__ deg, int* __restrict__ row_start,
                            int* __restrict__ cursor) {
  __shared__ int part[1024];
  const int tid = threadIdx.x;
  const int base = tid * 28;
  float dl[28];
  int local[28];
  int s = 0;
  #pragma unroll
  for (int j = 0; j < 28; ++j) {
    int n = base + j;
    float df = (n < NTOT_C) ? deg[n] : 0.f;
    dl[j] = df;
    local[j] = s; s += (int)df;
  }
  part[tid] = s;
  __syncthreads();
  for (int off = 1; off < 1024; off <<= 1) {
    int v = (tid >= off) ? part[tid - off] : 0;
    __syncthreads();
    part[tid] += v;
    __syncthreads();
  }
  int pre = (tid > 0) ? part[tid - 1] : 0;
  #pragma unroll
  for (int j = 0; j < 28; ++j) {
    int n = base + j;
    if (n < NTOT_C) {
      row_start[n] = pre + local[j];
      cursor[n]    = pre + local[j];
      deg[n]       = rsqrtf(fmaxf(dl[j], 1.f));
    }
  }
  if (tid == 1023) row_start[NTOT_C] = part[1023];
}

__global__ void place_kernel(const int* __restrict__ eu, const int* __restrict__ ei,
                             const float* __restrict__ dinv, int* __restrict__ cursor,
                             int* __restrict__ esrc, float* __restrict__ ew) {
  int e = blockIdx.x * 256 + threadIdx.x;
  if (e >= NE_C) return;
  int u = eu[e], v = NU_C + ei[e];
  float w = dinv[u] * dinv[v];
  int p1 = atomicAdd(&cursor[v], 1);  esrc[p1] = u; ew[p1] = w;
  int p2 = atomicAdd(&cursor[u], 1);  esrc[p2] = v; ew[p2] = w;
}

// ---------------- W transpose to bf16, tiled ----------------
__global__ void wtrans_kernel(const float* __restrict__ Wv, const float* __restrict__ Wti,
                              u16* __restrict__ Ov, u16* __restrict__ Ot) {
  __shared__ u16 sT[64][72];
  int b = blockIdx.x;
  const float* W; u16* O; int D;
  if (b < 64) { W = Wv; O = Ov; D = 4096; }
  else        { b -= 64; W = Wti; O = Ot; D = 768; }
  const int k0 = b * 64;
  const int r = threadIdx.x >> 6;
  const int c = threadIdx.x & 63;
  for (int rr = r; rr < 64; rr += 4)
    sT[c][rr] = f2bf(W[(size_t)(k0 + rr) * 64 + c]);
  __syncthreads();
  const int n = threadIdx.x >> 2, seg = threadIdx.x & 3;
  uint4 a0 = *(const uint4*)&sT[n][seg * 16];
  uint4 a1 = *(const uint4*)&sT[n][seg * 16 + 8];
  *(uint4*)(O + (size_t)n * D + k0 + seg * 16)     = a0;
  *(uint4*)(O + (size_t)n * D + k0 + seg * 16 + 8) = a1;
}

// ---------------- homo layers fused (zu | zi) ----------------
__global__ void zuzi_kernel(const float* __restrict__ uf, const float* __restrict__ w,
                            const int* __restrict__ nb, const float* __restrict__ ifb,
                            const int* __restrict__ iv, const int* __restrict__ it,
                            float* __restrict__ zu, float* __restrict__ zi) {
  const int c = threadIdx.x;
  if (blockIdx.x < NU_C) {
    const int u = blockIdx.x;
    __shared__ float at[20];
    if (c < 20) at[c] = w[u * 20 + c];
    __syncthreads();
    float e[20]; float m = -1e30f;
    #pragma unroll
    for (int k = 0; k < 20; ++k) { e[k] = at[k]; m = fmaxf(m, e[k]); }
    float ssum = 0.f;
    #pragma unroll
    for (int k = 0; k < 20; ++k) { e[k] = expf(e[k] - m); ssum += e[k]; }
    float inv = 1.f / ssum;
    float acc = 0.f;
    #pragma unroll
    for (int k = 0; k < 20; ++k) {
      int j = nb[u * 20 + k];
      acc += e[k] * inv * uf[(size_t)j * 128 + c];
    }
    zu[(size_t)u * 128 + c] = uf[(size_t)u * 128 + c] + acc;
  } else {
    const int i = blockIdx.x - NU_C;
    float sv = 0.f, st = 0.f;
    #pragma unroll
    for (int k = 0; k < 10; ++k) sv += ifb[(size_t)iv[i * 10 + k] * 128 + c];
    #pragma unroll
    for (int k = 0; k < 10; ++k) st += ifb[(size_t)it[i * 10 + k] * 128 + c];
    zi[(size_t)i * 128 + c] = ifb[(size_t)i * 128 + c] + 0.01f * sv + 0.09f * st;
  }
}

// ---------------- bpr + reg fused ----------------
__global__ void loss_kernel(const float* __restrict__ zu, const float* __restrict__ zi,
                            const int* __restrict__ uid, const int* __restrict__ pid,
                            const int* __restrict__ nid, const float* __restrict__ pv,
                            const float* __restrict__ pt, const float* __restrict__ alpha,
                            float* __restrict__ out) {
  if (blockIdx.x < 1024) {
    int wv = threadIdx.x >> 6, lane = threadIdx.x & 63;
    int b = blockIdx.x * 4 + wv;
    int u = uid[b], p = pid[b], n = nid[b];
    float2 a  = *(const float2*)(zu + (size_t)u * 128 + lane * 2);
    float2 xp = *(const float2*)(zi + (size_t)p * 128 + lane * 2);
    float2 xn = *(const float2*)(zi + (size_t)n * 128 + lane * 2);
    float d = a.x * (xp.x - xn.x) + a.y * (xp.y - xn.y);
    #pragma unroll
    for (int off = 32; off; off >>= 1) d += __shfl_xor(d, off);
    if (lane == 0) {
      float xv = -d;
      float sp = fmaxf(xv, 0.f) + log1pf(expf(-fabsf(xv)));
      atomicAdd(out, sp * (1.f / (float)B_C));
    }
  } else {
    const size_t N1 = (size_t)NU_C * 64;
    float acc = 0.f;
    for (size_t i = (size_t)(blockIdx.x - 1024) * 256 + threadIdx.x; i < 2 * N1;
         i += (size_t)512 * 256) {
      float x = (i < N1) ? pv[i] : pt[i - N1];
      acc += x * x;
    }
    #pragma unroll
    for (int off = 32; off; off >>= 1) acc += __shfl_xor(acc, off);
    __shared__ float red[4];
    if ((threadIdx.x & 63) == 0) red[threadIdx.x >> 6] = acc;
    __syncthreads();
    if (threadIdx.x == 0) {
      float s = red[0] + red[1] + red[2] + red[3];
      atomicAdd(out, 0.5e-4f * s);
    }
    if (blockIdx.x == 1024 && threadIdx.x == 0) {
      float a = alpha[0];
      atomicAdd(out, 0.5e-4f * a * a);
    }
  }
}

// ---------------- launcher ----------------
extern "C" void kernel_launch(void* const* d_in, const int* in_sizes, int n_in,
                              void* d_out, int out_size, void* d_ws, size_t ws_size,
                              hipStream_t stream) {
  const float* feat_v = (const float*)d_in[0];
  const float* feat_t = (const float*)d_in[1];
  const float* pref_v = (const float*)d_in[2];
  const float* pref_t = (const float*)d_in[3];
  const float* W_v    = (const float*)d_in[4];
  const float* W_t    = (const float*)d_in[5];
  const float* alpha  = (const float*)d_in[6];
  const float* unw    = (const float*)d_in[7];
  const int* eu       = (const int*)d_in[8];
  const int* ei       = (const int*)d_in[9];
  const int* u_ids    = (const int*)d_in[10];
  const int* pos_ids  = (const int*)d_in[11];
  const int* neg_ids  = (const int*)d_in[12];
  const int* user_nb  = (const int*)d_in[13];
  float* out = (float*)d_out;
  char* ws = (char*)d_ws;

  size_t off = 0;
  auto alloc = [&](size_t bytes) { char* p = ws + off; off += (bytes + 255) & ~(size_t)255; return p; };
  u16*   fvbf  = (u16*)alloc((size_t)NPAD_C * 4096 * 2);   // 66.06 MB (gemm; tvb2 after F1)
  u8*    fv8   = (u8*)alloc((size_t)NPAD_C * 4096);        // 33.03 MB (fp8 simtopk)
  u16*   ftbf  = (u16*)alloc((size_t)NPAD_C * 768 * 2);    // 12.39 MB
  u16*   wtv   = (u16*)alloc((size_t)64 * 4096 * 2);
  u16*   wtt   = (u16*)alloc((size_t)64 * 768 * 2);
  float* rn_v  = (float*)alloc(NPAD_C * 4);
  float* rn_t  = (float*)alloc(NPAD_C * 4);
  int*   idx_v = (int*)alloc(NI_C * 10 * 4);
  int*   idx_t = (int*)alloc(NI_C * 10 * 4);
  float* dinv  = (float*)alloc(NTOT_C * 4);
  int*   rowst = (int*)alloc((NTOT_C + 1) * 4);
  int*   curs  = (int*)alloc(NTOT_C * 4);
  int*   esrc  = (int*)alloc((size_t)2 * NE_C * 4);
  float* ew    = (float*)alloc((size_t)2 * NE_C * 4);
  float* x2    = (float*)alloc((size_t)NTOT_C * 128 * 4);  // 14.3 MB
  float* h1    = (float*)alloc((size_t)NTOT_C * 128 * 4);  // 14.3 MB
  char*  pC    = alloc((size_t)(NU_C + NI_C) * 128 * 4 * 2); // 28.7 MB
  u32*   tvb   = (u32*)pC;                                  // 20.3 MB (v-graph, dead before u_f write)
  u32*   tvb2  = (u32*)fvbf;                                // t-graph tv: fvbf dead after F1 gemm
  float* u_f   = (float*)pC;
  float* i_f   = (float*)(pC + (size_t)NU_C * 128 * 4);
  float* z_u   = (float*)(pC + (size_t)(NU_C + NI_C) * 128 * 4);
  float* z_i   = (float*)(pC + (size_t)(2 * NU_C + NI_C) * 128 * 4);

  hipMemsetAsync(out, 0, sizeof(float), stream);
  hipMemsetAsync(dinv, 0, NTOT_C * 4, stream);

  // --- CSR build + conversions (serial prologue) ---
  deg_count_kernel<<<(NE_C + 255) / 256, 256, 0, stream>>>(eu, ei, dinv);
  scan_kernel<<<1, 1024, 0, stream>>>(dinv, rowst, curs);
  place_kernel<<<(NE_C + 255) / 256, 256, 0, stream>>>(eu, ei, dinv, curs, esrc, ew);
  conv_kernel2<<<2 * NPAD_C, 256, 0, stream>>>(feat_v, feat_t, fvbf, ftbf, fv8, rn_v, rn_t);
  wtrans_kernel<<<76, 256, 0, stream>>>(W_v, W_t, wtv, wtt);

  // --- F1: simtopk_fp8 || gemm_xw x2 || fill_pref ---
  fusedA_kernel<<<NPAIR + 250 + 10000, 256, 0, stream>>>(
      fv8, rn_v, tvb, fvbf, wtv, ftbf, wtt, x2, pref_v, pref_t);

  // --- F2: gather2 || merge_v ---
  fusedB_kernel<<<14000 + 2000, 256, 0, stream>>>(rowst, esrc, ew, x2, h1, tvb, idx_v);

  // --- F3: simtopk_t (tv -> tvb2) || gather_comb2 ---
  fusedC_kernel<<<NPAIR + 14000, 256, 0, stream>>>(
      ftbf, rn_t, tvb2, rowst, esrc, ew, x2, h1, alpha, u_f, i_f);

  // --- merge_t, homo layers, loss ---
  merge4_kernel<<<2000, 256, 0, stream>>>(tvb2, idx_t);
  zuzi_kernel<<<NU_C + NI_C, 128, 0, stream>>>(u_f, unw, user_nb, i_f, idx_v, idx_t, z_u, z_i);
  loss_kernel<<<1536, 256, 0, stream>>>(z_u, z_i, u_ids, pos_ids, neg_ids,
                                        pref_v, pref_t, alpha, out);
}

// Round 6
// 1047.590 us; speedup vs baseline: 1.0453x; 1.0453x over previous
//
#include <hip/hip_runtime.h>
#include <cstdint>
#include <cstddef>

// ---------------- problem constants ----------------
#define NU_C   20000
#define NI_C   8000
#define NTOT_C 28000          // NU+NI
#define NE_C   200000
#define B_C    4096
#define NPAD_C 8064           // NI padded to 63*128 rows
#define NCHUNK 63
#define NPAIR  2016           // 63*64/2 upper-triangle chunk pairs

typedef unsigned short u16;
typedef unsigned int   u32;
typedef unsigned char  u8;
typedef __bf16 bf16x8 __attribute__((ext_vector_type(8)));
typedef float  f32x4  __attribute__((ext_vector_type(4)));

static __device__ __forceinline__ u16 f2bf(float f) {
  u32 u = __float_as_uint(f);
  return (u16)((u + 0x7fffu + ((u >> 16) & 1u)) >> 16);   // RNE
}

// async global->LDS, 16B per lane; LDS dest is wave-uniform base + lane*16
static __device__ __forceinline__ void gl_lds16(const void* g, void* l) {
  __builtin_amdgcn_global_load_lds(
      (const __attribute__((address_space(1))) void*)g,
      (__attribute__((address_space(3))) void*)l, 16, 0, 0);
}

// XCD-chunked block swizzle (T1). simtopk bodies receive a LOGICAL id in
// [0,NPAIR); the fused grids apply a uniform physical offset, which preserves
// the one-XCD-per-residue-class contiguity.
static __device__ __forceinline__ int xcd_swz(int b) {
  return (b & 7) * (NPAIR / 8) + (b >> 3);
}

// ---------------- bf16/fp8 convert + row 1/norm + fill_pref (absorbed) ----------------
__global__ void conv_kernel2(const float* __restrict__ Fv, const float* __restrict__ Ft,
                             u16* __restrict__ Fbv, u16* __restrict__ Fbt,
                             u8* __restrict__ Fv8,
                             float* __restrict__ rnv, float* __restrict__ rnt,
                             const float* __restrict__ pv, const float* __restrict__ pt,
                             float* __restrict__ x2) {
  int b = blockIdx.x;
  const int tid = threadIdx.x;
  float ss = 0.f;
  if (b < NPAD_C) {                                       // modality v, D=4096
    const int row = b;
    u16* dst  = Fbv + (size_t)row * 4096;
    u8*  dst8 = Fv8 + (size_t)row * 4096;
    if (row < NI_C) {
      const float* src = Fv + (size_t)row * 4096;
      for (int c = tid * 4; c < 4096; c += 1024) {
        float4 f = *(const float4*)(src + c);
        ss += f.x*f.x + f.y*f.y + f.z*f.z + f.w*f.w;
        ushort4 v; v.x = f2bf(f.x); v.y = f2bf(f.y); v.z = f2bf(f.z); v.w = f2bf(f.w);
        *(ushort4*)(dst + c) = v;
        int w8 = __builtin_amdgcn_cvt_pk_fp8_f32(f.x, f.y, 0, false);
        w8 = __builtin_amdgcn_cvt_pk_fp8_f32(f.z, f.w, w8, true);
        *(u32*)(dst8 + c) = (u32)w8;
      }
    } else {
      for (int c = tid * 4; c < 4096; c += 1024) {
        ushort4 v; v.x = v.y = v.z = v.w = 0;
        *(ushort4*)(dst + c) = v;
        *(u32*)(dst8 + c) = 0u;
      }
    }
    #pragma unroll
    for (int off = 32; off; off >>= 1) ss += __shfl_xor(ss, off);
    __shared__ float red[4];
    if ((tid & 63) == 0) red[tid >> 6] = ss;
    __syncthreads();
    if (tid == 0) {
      float s = red[0] + red[1] + red[2] + red[3];
      rnv[row] = (row < NI_C) ? rsqrtf(s) : 0.f;
    }
  } else if (b < 2 * NPAD_C) {                            // modality t, D=768
    const int row = b - NPAD_C;
    u16* dst = Fbt + (size_t)row * 768;
    if (row < NI_C) {
      const float* src = Ft + (size_t)row * 768;
      for (int c = tid * 4; c < 768; c += 1024) {
        float4 f = *(const float4*)(src + c);
        ss += f.x*f.x + f.y*f.y + f.z*f.z + f.w*f.w;
        ushort4 v; v.x = f2bf(f.x); v.y = f2bf(f.y); v.z = f2bf(f.z); v.w = f2bf(f.w);
        *(ushort4*)(dst + c) = v;
      }
    } else {
      for (int c = tid * 4; c < 768; c += 1024) {
        ushort4 v; v.x = v.y = v.z = v.w = 0;
        *(ushort4*)(dst + c) = v;
      }
    }
    #pragma unroll
    for (int off = 32; off; off >>= 1) ss += __shfl_xor(ss, off);
    __shared__ float red[4];
    if ((tid & 63) == 0) red[tid >> 6] = ss;
    __syncthreads();
    if (tid == 0) {
      float s = red[0] + red[1] + red[2] + red[3];
      rnt[row] = (row < NI_C) ? rsqrtf(s) : 0.f;
    }
  } else {                                                // fill_pref: x2 user rows
    const int b2 = b - 2 * NPAD_C;                        // [0,1250), 2048 elems each
    #pragma unroll
    for (int k = 0; k < 8; ++k) {
      int gid = b2 * 2048 + k * 256 + tid;
      int u = gid >> 7, c = gid & 127;
      x2[gid] = (c < 64) ? pv[(size_t)u * 64 + c] : pt[(size_t)u * 64 + (c - 64)];
    }
  }
}

// ---------------- fp8 symmetric fused Gram + top-10 body (v-graph, D=4096) ----------------
// r2/r4 structure: BK=128 single-buffer, 2 barriers per 128-K tile, seg-swizzled
// LDS, XCD-chunked pair map.
static __device__ __forceinline__ void simtopk_fp8_body(
    int bid, char* smem, const u8* __restrict__ F, const float* __restrict__ rn,
    u32* __restrict__ tv) {
  u8*    sB   = (u8*)smem;                   // I rows, cols [k0,k0+64)    [128][64B]
  u8*    sA   = (u8*)(smem + 16384);         // J rows, cols [k0,k0+64)    [128][64B]
  // region +8192 within each: cols [k0+64,k0+128), same layout
  float* T    = (float*)smem;                // transpose [128][66] = 33792 B (epilogue)
  int*   mk   = (int*)smem;                  // merge dump [128][40] (epilogue)
  int*   mk2  = (int*)(smem + 20480);        // repacked [128][10] (epilogue)
  float* sRNI = (float*)(smem + 33792);
  float* sRNJ = (float*)(smem + 34304);

  const int tid  = threadIdx.x;
  const int lane = tid & 63;
  const int wv   = tid >> 6;
  const int n15  = lane & 15;
  const int quad = lane >> 4;

  int I = 0, rem = xcd_swz(bid);
  { int rowlen = NCHUNK;
    while (rem >= rowlen) { rem -= rowlen; rowlen--; I++; } }
  const int J = I + rem;

  const int l2   = lane >> 2;
  const int lseg = (lane & 3) ^ (l2 & 3) ^ (lane >> 4);   // logical seg to fetch
  const u8* gB[2]; const u8* gA[2]; u8* lB[2]; u8* lA[2];
  #pragma unroll
  for (int rep = 0; rep < 2; ++rep) {
    int row = wv * 32 + rep * 16 + l2;
    gB[rep] = F + (size_t)(I * 128 + row) * 4096 + lseg * 16;
    gA[rep] = F + (size_t)(J * 128 + row) * 4096 + lseg * 16;
    lB[rep] = sB + (wv * 32 + rep * 16) * 64;
    lA[rep] = sA + (wv * 32 + rep * 16) * 64;
  }
  const int s_n = (n15 & 3) ^ (n15 >> 2);
  const int q2  = quad >> 1;
  const int q8  = (quad & 1) * 8;
  const int rB0 = (wv * 32 + n15) * 64;
  const int rB1 = rB0 + 16 * 64;

  f32x4 acc[2][8];
  #pragma unroll
  for (int tf = 0; tf < 2; ++tf)
    #pragma unroll
    for (int af = 0; af < 8; ++af) { f32x4 z = {0.f,0.f,0.f,0.f}; acc[tf][af] = z; }

  for (int k0 = 0; k0 < 4096; k0 += 128) {
    __syncthreads();
    gl_lds16(gB[0] + k0,      lB[0]);
    gl_lds16(gB[0] + k0 + 64, lB[0] + 8192);
    gl_lds16(gB[1] + k0,      lB[1]);
    gl_lds16(gB[1] + k0 + 64, lB[1] + 8192);
    gl_lds16(gA[0] + k0,      lA[0]);
    gl_lds16(gA[0] + k0 + 64, lA[0] + 8192);
    gl_lds16(gA[1] + k0,      lA[1]);
    gl_lds16(gA[1] + k0 + 64, lA[1] + 8192);
    if (k0 == 0) {
      if (tid < 128) sRNJ[tid] = rn[J * 128 + tid];
      else           sRNI[tid - 128] = rn[I * 128 + (tid - 128)];
    }
    __syncthreads();
    #pragma unroll
    for (int ksub = 0; ksub < 2; ++ksub) {
      const u8* bBase = sB + ksub * 8192;
      const u8* aBase = sA + ksub * 8192;
      #pragma unroll
      for (int ks = 0; ks < 2; ++ks) {
        const int sw = (((ks * 2 + q2) ^ s_n) << 4) + q8;
        long long b0 = *(const long long*)(bBase + rB0 + sw);
        long long b1 = *(const long long*)(bBase + rB1 + sw);
        #pragma unroll
        for (int af = 0; af < 8; ++af) {
          long long a = *(const long long*)(aBase + (af * 16 + n15) * 64 + sw);
          acc[0][af] = __builtin_amdgcn_mfma_f32_16x16x32_fp8_fp8(a, b0, acc[0][af], 0, 0, 0);
          acc[1][af] = __builtin_amdgcn_mfma_f32_16x16x32_fp8_fp8(a, b1, acc[1][af], 0, 0, 0);
        }
      }
    }
  }

  // ---- I-side: target rows in I, cands in J ----
  int bk[2][10];
  #pragma unroll
  for (int tf = 0; tf < 2; ++tf)
    #pragma unroll
    for (int j = 0; j < 10; ++j) bk[tf][j] = 0;

  #pragma unroll
  for (int af = 0; af < 8; ++af) {
    const float4 rn4 = *(const float4*)(sRNJ + af * 16 + quad * 4);
    const float rna[4] = {rn4.x, rn4.y, rn4.z, rn4.w};
    #pragma unroll
    for (int r = 0; r < 4; ++r) {
      const int ci = J * 128 + af * 16 + quad * 4 + r;
      #pragma unroll
      for (int tf = 0; tf < 2; ++tf) {
        float v = acc[tf][af][r] * rna[r];
        int key = (int)((__float_as_uint(v) & 0xFFFFE000u) | (u32)ci);
        if (ci < NI_C && key > bk[tf][9]) {
          bk[tf][9] = key;
          #pragma unroll
          for (int j = 9; j > 0; --j)
            if (bk[tf][j] > bk[tf][j-1]) { int t = bk[tf][j]; bk[tf][j] = bk[tf][j-1]; bk[tf][j-1] = t; }
        }
      }
    }
  }
  __syncthreads();
  #pragma unroll
  for (int tf = 0; tf < 2; ++tf) {
    int rl = wv * 32 + tf * 16 + n15;
    #pragma unroll
    for (int j = 0; j < 10; ++j) mk[rl * 40 + quad * 10 + j] = bk[tf][j];
  }
  __syncthreads();
  if (tid < 128) {                            // 4-way sorted-list tournament
    int* m = mk + tid * 40;
    int h0 = 0, h1 = 10, h2 = 20, h3 = 30;
    int v0 = m[0], v1 = m[10], v2 = m[20], v3 = m[30];
    #pragma unroll
    for (int s = 0; s < 10; ++s) {
      int m01 = v0 > v1 ? v0 : v1, m23 = v2 > v3 ? v2 : v3;
      int mx = m01 > m23 ? m01 : m23;
      mk2[tid * 10 + s] = mx;
      if      (mx == v0) { ++h0; v0 = (h0 < 10) ? m[h0] : (int)0x80000000; }
      else if (mx == v1) { ++h1; v1 = (h1 < 20) ? m[h1] : (int)0x80000000; }
      else if (mx == v2) { ++h2; v2 = (h2 < 30) ? m[h2] : (int)0x80000000; }
      else               { ++h3; v3 = (h3 < 40) ? m[h3] : (int)0x80000000; }
    }
  }
  __syncthreads();
  { u32* o = tv + ((size_t)J * NPAD_C + I * 128) * 10;
    for (int g = tid; g < 1280; g += 256) o[g] = (u32)mk2[g]; }

  if (I == J) return;

  // ---- J-side: target rows in J, cands in I (via transpose) ----
  int bj[2][10];
  #pragma unroll
  for (int s = 0; s < 2; ++s)
    #pragma unroll
    for (int j = 0; j < 10; ++j) bj[s][j] = 0;

  #pragma unroll
  for (int tf = 0; tf < 2; ++tf) {
    __syncthreads();
    #pragma unroll
    for (int af = 0; af < 8; ++af)
      #pragma unroll
      for (int r = 0; r < 4; ++r)
        T[(af * 16 + quad * 4 + r) * 66 + wv * 16 + n15] = acc[tf][af][r];
    __syncthreads();
    #pragma unroll
    for (int s = 0; s < 2; ++s) {
      const int c_own = wv * 32 + s * 16 + n15;
      #pragma unroll
      for (int j = 0; j < 16; ++j) {
        const int t  = quad * 32 + tf * 16 + j;
        const int t64 = quad * 16 + j;
        float v = T[c_own * 66 + t64] * sRNI[t];
        const int ti = I * 128 + t;
        int key = (int)((__float_as_uint(v) & 0xFFFFE000u) | (u32)ti);
        if (ti < NI_C && key > bj[s][9]) {
          bj[s][9] = key;
          #pragma unroll
          for (int q = 9; q > 0; --q)
            if (bj[s][q] > bj[s][q-1]) { int tt = bj[s][q]; bj[s][q] = bj[s][q-1]; bj[s][q-1] = tt; }
        }
      }
    }
  }
  __syncthreads();
  #pragma unroll
  for (int s = 0; s < 2; ++s) {
    int rl = wv * 32 + s * 16 + n15;
    #pragma unroll
    for (int j = 0; j < 10; ++j) mk[rl * 40 + quad * 10 + j] = bj[s][j];
  }
  __syncthreads();
  if (tid < 128) {
    int* m = mk + tid * 40;
    int h0 = 0, h1 = 10, h2 = 20, h3 = 30;
    int v0 = m[0], v1 = m[10], v2 = m[20], v3 = m[30];
    #pragma unroll
    for (int s = 0; s < 10; ++s) {
      int m01 = v0 > v1 ? v0 : v1, m23 = v2 > v3 ? v2 : v3;
      int mx = m01 > m23 ? m01 : m23;
      mk2[tid * 10 + s] = mx;
      if      (mx == v0) { ++h0; v0 = (h0 < 10) ? m[h0] : (int)0x80000000; }
      else if (mx == v1) { ++h1; v1 = (h1 < 20) ? m[h1] : (int)0x80000000; }
      else if (mx == v2) { ++h2; v2 = (h2 < 30) ? m[h2] : (int)0x80000000; }
      else               { ++h3; v3 = (h3 < 40) ? m[h3] : (int)0x80000000; }
    }
  }
  __syncthreads();
  { u32* o = tv + ((size_t)I * NPAD_C + J * 128) * 10;
    for (int g = tid; g < 1280; g += 256) o[g] = (u32)mk2[g]; }
}

// ---------------- bf16 symmetric fused Gram + top-10 body (t-graph, D=768) ----------------
static __device__ __forceinline__ void simtopk_bf16_body(
    int bid, char* smem, const u16* __restrict__ F, const float* __restrict__ rn,
    u32* __restrict__ tv) {
  u16*   sB   = (u16*)smem;
  u16*   sA   = (u16*)(smem + 16384);
  float* T    = (float*)smem;
  int*   mk   = (int*)smem;
  int*   mk2  = (int*)(smem + 20480);
  float* sRNI = (float*)(smem + 34816);
  float* sRNJ = (float*)(smem + 35328);

  const int tid  = threadIdx.x;
  const int lane = tid & 63;
  const int wv   = tid >> 6;
  const int n15  = lane & 15;
  const int quad = lane >> 4;

  int I = 0, rem = xcd_swz(bid);
  { int rowlen = NCHUNK;
    while (rem >= rowlen) { rem -= rowlen; rowlen--; I++; } }
  const int J = I + rem;

  const int l8  = lane >> 3;
  const int sgu = ((lane & 7) ^ l8) << 3;
  const u16* gB[4]; const u16* gA[4]; u16* lB[4]; u16* lA[4];
  #pragma unroll
  for (int rep = 0; rep < 4; ++rep) {
    int row = wv * 32 + rep * 8 + l8;
    gB[rep] = F + (size_t)(I * 128 + row) * 768 + sgu;
    gA[rep] = F + (size_t)(J * 128 + row) * 768 + sgu;
    lB[rep] = sB + wv * 2048 + rep * 512;
    lA[rep] = sA + wv * 2048 + rep * 512;
  }
  const int swu0 = ((quad    ) ^ (n15 & 7)) << 3;
  const int swu1 = ((quad + 4) ^ (n15 & 7)) << 3;
  const int rowB0 = (wv * 32 + n15) * 64;
  const int rowB1 = rowB0 + 16 * 64;

  f32x4 acc[2][8];
  #pragma unroll
  for (int tf = 0; tf < 2; ++tf)
    #pragma unroll
    for (int af = 0; af < 8; ++af) { f32x4 z = {0.f,0.f,0.f,0.f}; acc[tf][af] = z; }

  for (int k0 = 0; k0 < 768; k0 += 64) {
    __syncthreads();
    #pragma unroll
    for (int rep = 0; rep < 4; ++rep) gl_lds16(gB[rep] + k0, lB[rep]);
    #pragma unroll
    for (int rep = 0; rep < 4; ++rep) gl_lds16(gA[rep] + k0, lA[rep]);
    if (k0 == 0) {
      if (tid < 128) sRNJ[tid] = rn[J * 128 + tid];
      else           sRNI[tid - 128] = rn[I * 128 + (tid - 128)];
    }
    __syncthreads();
    #pragma unroll
    for (int ks = 0; ks < 2; ++ks) {
      const int swu = ks ? swu1 : swu0;
      bf16x8 b0 = *(const bf16x8*)(sB + rowB0 + swu);
      bf16x8 b1 = *(const bf16x8*)(sB + rowB1 + swu);
      #pragma unroll
      for (int af = 0; af < 8; ++af) {
        bf16x8 a = *(const bf16x8*)(sA + (af * 16 + n15) * 64 + swu);
        acc[0][af] = __builtin_amdgcn_mfma_f32_16x16x32_bf16(a, b0, acc[0][af], 0, 0, 0);
        acc[1][af] = __builtin_amdgcn_mfma_f32_16x16x32_bf16(a, b1, acc[1][af], 0, 0, 0);
      }
    }
  }

  int bk[2][10];
  #pragma unroll
  for (int tf = 0; tf < 2; ++tf)
    #pragma unroll
    for (int j = 0; j < 10; ++j) bk[tf][j] = 0;

  #pragma unroll
  for (int af = 0; af < 8; ++af) {
    const float4 rn4 = *(const float4*)(sRNJ + af * 16 + quad * 4);
    const float rna[4] = {rn4.x, rn4.y, rn4.z, rn4.w};
    #pragma unroll
    for (int r = 0; r < 4; ++r) {
      const int ci = J * 128 + af * 16 + quad * 4 + r;
      #pragma unroll
      for (int tf = 0; tf < 2; ++tf) {
        float v = acc[tf][af][r] * rna[r];
        int key = (int)((__float_as_uint(v) & 0xFFFFE000u) | (u32)ci);
        if (ci < NI_C && key > bk[tf][9]) {
          bk[tf][9] = key;
          #pragma unroll
          for (int j = 9; j > 0; --j)
            if (bk[tf][j] > bk[tf][j-1]) { int t = bk[tf][j]; bk[tf][j] = bk[tf][j-1]; bk[tf][j-1] = t; }
        }
      }
    }
  }
  __syncthreads();
  #pragma unroll
  for (int tf = 0; tf < 2; ++tf) {
    int rl = wv * 32 + tf * 16 + n15;
    #pragma unroll
    for (int j = 0; j < 10; ++j) mk[rl * 40 + quad * 10 + j] = bk[tf][j];
  }
  __syncthreads();
  if (tid < 128) {
    int* m = mk + tid * 40;
    int h0 = 0, h1 = 10, h2 = 20, h3 = 30;
    int v0 = m[0], v1 = m[10], v2 = m[20], v3 = m[30];
    #pragma unroll
    for (int s = 0; s < 10; ++s) {
      int m01 = v0 > v1 ? v0 : v1, m23 = v2 > v3 ? v2 : v3;
      int mx = m01 > m23 ? m01 : m23;
      mk2[tid * 10 + s] = mx;
      if      (mx == v0) { ++h0; v0 = (h0 < 10) ? m[h0] : (int)0x80000000; }
      else if (mx == v1) { ++h1; v1 = (h1 < 20) ? m[h1] : (int)0x80000000; }
      else if (mx == v2) { ++h2; v2 = (h2 < 30) ? m[h2] : (int)0x80000000; }
      else               { ++h3; v3 = (h3 < 40) ? m[h3] : (int)0x80000000; }
    }
  }
  __syncthreads();
  { u32* o = tv + ((size_t)J * NPAD_C + I * 128) * 10;
    for (int g = tid; g < 1280; g += 256) o[g] = (u32)mk2[g]; }

  if (I == J) return;

  int bj[2][10];
  #pragma unroll
  for (int s = 0; s < 2; ++s)
    #pragma unroll
    for (int j = 0; j < 10; ++j) bj[s][j] = 0;

  #pragma unroll
  for (int tf = 0; tf < 2; ++tf) {
    __syncthreads();
    #pragma unroll
    for (int af = 0; af < 8; ++af)
      #pragma unroll
      for (int r = 0; r < 4; ++r)
        T[(af * 16 + quad * 4 + r) * 66 + wv * 16 + n15] = acc[tf][af][r];
    __syncthreads();
    #pragma unroll
    for (int s = 0; s < 2; ++s) {
      const int c_own = wv * 32 + s * 16 + n15;
      #pragma unroll
      for (int j = 0; j < 16; ++j) {
        const int t  = quad * 32 + tf * 16 + j;
        const int t64 = quad * 16 + j;
        float v = T[c_own * 66 + t64] * sRNI[t];
        const int ti = I * 128 + t;
        int key = (int)((__float_as_uint(v) & 0xFFFFE000u) | (u32)ti);
        if (ti < NI_C && key > bj[s][9]) {
          bj[s][9] = key;
          #pragma unroll
          for (int q = 9; q > 0; --q)
            if (bj[s][q] > bj[s][q-1]) { int tt = bj[s][q]; bj[s][q] = bj[s][q-1]; bj[s][q-1] = tt; }
        }
      }
    }
  }
  __syncthreads();
  #pragma unroll
  for (int s = 0; s < 2; ++s) {
    int rl = wv * 32 + s * 16 + n15;
    #pragma unroll
    for (int j = 0; j < 10; ++j) mk[rl * 40 + quad * 10 + j] = bj[s][j];
  }
  __syncthreads();
  if (tid < 128) {
    int* m = mk + tid * 40;
    int h0 = 0, h1 = 10, h2 = 20, h3 = 30;
    int v0 = m[0], v1 = m[10], v2 = m[20], v3 = m[30];
    #pragma unroll
    for (int s = 0; s < 10; ++s) {
      int m01 = v0 > v1 ? v0 : v1, m23 = v2 > v3 ? v2 : v3;
      int mx = m01 > m23 ? m01 : m23;
      mk2[tid * 10 + s] = mx;
      if      (mx == v0) { ++h0; v0 = (h0 < 10) ? m[h0] : (int)0x80000000; }
      else if (mx == v1) { ++h1; v1 = (h1 < 20) ? m[h1] : (int)0x80000000; }
      else if (mx == v2) { ++h2; v2 = (h2 < 30) ? m[h2] : (int)0x80000000; }
      else               { ++h3; v3 = (h3 < 40) ? m[h3] : (int)0x80000000; }
    }
  }
  __syncthreads();
  { u32* o = tv + ((size_t)I * NPAD_C + J * 128) * 10;
    for (int g = tid; g < 1280; g += 256) o[g] = (u32)mk2[g]; }
}

// ---------------- merge: 63 sorted lists x 10 -> top-10, 4 rows per 256-thr block ----
static __device__ __forceinline__ void merge4_body(int mb, int* fkbase,
                                                   const u32* __restrict__ tv,
                                                   int* __restrict__ idx) {
  const int w    = threadIdx.x >> 6;
  const int lane = threadIdx.x & 63;
  const int row  = mb * 4 + w;
  int* fk = fkbase + w * 640;
  for (int g = lane; g < 630; g += 64)
    fk[g] = (int)tv[((size_t)(g / 10) * NPAD_C + row) * 10 + (g % 10)];
  if (lane < 10) fk[630 + lane] = (int)0x80000000;
  __syncthreads();
  int v[10];
  #pragma unroll
  for (int j = 0; j < 10; ++j) v[j] = fk[lane + j * 64];
  #pragma unroll 1
  for (int s = 0; s < 10; ++s) {
    int loc = v[0];
    #pragma unroll
    for (int j = 1; j < 10; ++j) loc = v[j] > loc ? v[j] : loc;
    #pragma unroll
    for (int off = 32; off; off >>= 1) {
      int o = __shfl_xor(loc, off); loc = o > loc ? o : loc;
    }
    if (lane == 0) idx[row * 10 + s] = loc & 0x1FFF;
    #pragma unroll
    for (int j = 0; j < 10; ++j) if (v[j] == loc) v[j] = (int)0x80000000;
  }
}

__launch_bounds__(256)
__global__ void merge4_kernel(const u32* __restrict__ tv, int* __restrict__ idx) {
  __shared__ int fk[4 * 640];
  merge4_body(blockIdx.x, fk, tv, idx);
}

// ---------------- feat @ W via bf16 MFMA body, M=64 tiles ----------------
template<int D>
static __device__ __forceinline__ void gemm_xw_body(
    int bid, char* smem, const u16* __restrict__ F, const u16* __restrict__ Wt,
    float* __restrict__ x2, int modeoff) {
  u16* sF = (u16*)smem;                      // 8192 B
  const int tid  = threadIdx.x;
  const int lane = tid & 63;
  const int wv   = tid >> 6;
  const int n15  = lane & 15;
  const int quad = lane >> 4;
  const int l8   = lane >> 3;
  const int sgu  = ((lane & 7) ^ l8) << 3;
  const u16* gF[2]; u16* lF[2];
  #pragma unroll
  for (int rep = 0; rep < 2; ++rep) {
    int row = rep * 32 + wv * 8 + l8;
    gF[rep] = F + (size_t)(bid * 64 + row) * D + sgu;
    lF[rep] = sF + (rep * 32 + wv * 8) * 64;
  }
  const int swu0 = ((quad    ) ^ (n15 & 7)) << 3;
  const int swu1 = ((quad + 4) ^ (n15 & 7)) << 3;

  f32x4 acc[4];
  #pragma unroll
  for (int nf = 0; nf < 4; ++nf) { f32x4 z = {0.f,0.f,0.f,0.f}; acc[nf] = z; }

  for (int k0 = 0; k0 < D; k0 += 64) {
    __syncthreads();
    gl_lds16(gF[0] + k0, lF[0]);
    gl_lds16(gF[1] + k0, lF[1]);
    __syncthreads();
    #pragma unroll
    for (int ks = 0; ks < 2; ++ks) {
      const int swu = ks ? swu1 : swu0;
      bf16x8 a = *(const bf16x8*)(sF + (wv * 16 + n15) * 64 + swu);
      #pragma unroll
      for (int nf = 0; nf < 4; ++nf) {
        bf16x8 b = *(const bf16x8*)(Wt + (size_t)(nf * 16 + n15) * D + k0 + ks * 32 + quad * 8);
        acc[nf] = __builtin_amdgcn_mfma_f32_16x16x32_bf16(a, b, acc[nf], 0, 0, 0);
      }
    }
  }
  #pragma unroll
  for (int nf = 0; nf < 4; ++nf)
    #pragma unroll
    for (int r = 0; r < 4; ++r) {
      int row = bid * 64 + wv * 16 + quad * 4 + r;
      if (row < NI_C)
        x2[(size_t)(NU_C + row) * 128 + modeoff + nf * 16 + n15] = acc[nf][r];
    }
}

// ---------------- gather bodies ----------------
static __device__ __forceinline__ void gather2_body(
    int bid, const int* __restrict__ row_start, const int* __restrict__ esrc,
    const float* __restrict__ ew, const float* __restrict__ x2, float* __restrict__ h1) {
  const int node = bid * 2 + (threadIdx.x >> 7);
  const int ch   = threadIdx.x & 127;
  if (node >= NTOT_C) return;
  const int b = row_start[node], e = row_start[node + 1];
  float acc = 0.f;
  for (int i = b; i < e; ++i)
    acc += ew[i] * x2[(size_t)esrc[i] * 128 + ch];
  h1[(size_t)node * 128 + ch] = acc;
}

static __device__ __forceinline__ void gather_comb2_body(
    int bid, const int* __restrict__ row_start, const int* __restrict__ esrc,
    const float* __restrict__ ew, const float* __restrict__ x2,
    const float* __restrict__ h1, const float* __restrict__ alpha,
    float* __restrict__ uf, float* __restrict__ ifb) {
  const int node = bid * 2 + (threadIdx.x >> 7);
  const int ch   = threadIdx.x & 127;
  if (node >= NTOT_C) return;
  const int b = row_start[node], e = row_start[node + 1];
  float acc = 0.f;
  for (int i = b; i < e; ++i)
    acc += ew[i] * h1[(size_t)esrc[i] * 128 + ch];
  float val = x2[(size_t)node * 128 + ch] + h1[(size_t)node * 128 + ch] + acc;
  if (node < NU_C) {
    float av = 1.f / (1.f + expf(-alpha[0]));
    float coef = (ch < 64) ? av : (1.f - av);
    uf[(size_t)node * 128 + ch] = coef * val;
  } else {
    ifb[(size_t)(node - NU_C) * 128 + ch] = val;
  }
}

// ---------------- fused launches (LPT ordering: long/latency-bound blocks FIRST) ----
// F1: gemm_xw<4096> (125 latency-bound blocks) ++ gemm_xw<768> (125) ++
//     simtopk_fp8 (2016, the throughput pole). Short work first = its latency
//     hides under the simtopk waves instead of forming an exposed tail.
__launch_bounds__(256)
__global__ void fusedA_kernel(const u8* __restrict__ F8, const float* __restrict__ rnv,
                              u32* __restrict__ tv,
                              const u16* __restrict__ Fvb, const u16* __restrict__ Wtv,
                              const u16* __restrict__ Ftb, const u16* __restrict__ Wtt,
                              float* __restrict__ x2) {
  __shared__ __align__(16) char smem[34816];
  int b = blockIdx.x;
  if (b < 125) { gemm_xw_body<4096>(b, smem, Fvb, Wtv, x2, 0); return; }
  b -= 125;
  if (b < 125) { gemm_xw_body<768>(b, smem, Ftb, Wtt, x2, 64); return; }
  simtopk_fp8_body(b - 125, smem, F8, rnv, tv);
}

// F2: merge_v (2000 short blocks) first, gather2 (14000) after.
__launch_bounds__(256)
__global__ void fusedB_kernel(const int* __restrict__ row_start, const int* __restrict__ esrc,
                              const float* __restrict__ ew, const float* __restrict__ x2,
                              float* __restrict__ h1,
                              const u32* __restrict__ tv, int* __restrict__ idx) {
  __shared__ int fk[4 * 640];
  int b = blockIdx.x;
  if (b < 2000) { merge4_body(b, fk, tv, idx); return; }
  gather2_body(b - 2000, row_start, esrc, ew, x2, h1);
}

// F3: simtopk_t (blocks 0..2015, long pole first) ++ gather_comb2.
__launch_bounds__(256)
__global__ void fusedC_kernel(const u16* __restrict__ Ftb, const float* __restrict__ rnt,
                              u32* __restrict__ tv2,
                              const int* __restrict__ row_start, const int* __restrict__ esrc,
                              const float* __restrict__ ew, const float* __restrict__ x2,
                              const float* __restrict__ h1, const float* __restrict__ alpha,
                              float* __restrict__ uf, float* __restrict__ ifb) {
  __shared__ __align__(16) char smem[40960];
  int b = blockIdx.x;
  if (b < NPAIR) { simtopk_bf16_body(b, smem, Ftb, rnt, tv2); return; }
  gather_comb2_body(b - NPAIR, row_start, esrc, ew, x2, h1, alpha, uf, ifb);
}

// ---------------- CSR build ----------------
__global__ void deg_count_kernel(const int* __restrict__ eu, const int* __restrict__ ei,
                                 float* deg) {
  int e = blockIdx.x * 256 + threadIdx.x;
  if (e < NE_C) {
    atomicAdd(&deg[eu[e]], 1.f);
    atomicAdd(&deg[NU_C + ei[e]], 1.f);
  }
}

__global__ void scan_kernel(float* __restrict__ deg, int* __restrict__ row_start,
                            int* __restrict__ cursor) {
  __shared__ int part[1024];
  const int tid = threadIdx.x;
  const int base = tid * 28;
  float dl[28];
  int local[28];
  int s = 0;
  #pragma unroll
  for (int j = 0; j < 28; ++j) {
    int n = base + j;
    float df = (n < NTOT_C) ? deg[n] : 0.f;
    dl[j] = df;
    local[j] = s; s += (int)df;
  }
  part[tid] = s;
  __syncthreads();
  for (int off = 1; off < 1024; off <<= 1) {
    int v = (tid >= off) ? part[tid - off] : 0;
    __syncthreads();
    part[tid] += v;
    __syncthreads();
  }
  int pre = (tid > 0) ? part[tid - 1] : 0;
  #pragma unroll
  for (int j = 0; j < 28; ++j) {
    int n = base + j;
    if (n < NTOT_C) {
      row_start[n] = pre + local[j];
      cursor[n]    = pre + local[j];
      deg[n]       = rsqrtf(fmaxf(dl[j], 1.f));
    }
  }
  if (tid == 1023) row_start[NTOT_C] = part[1023];
}

__global__ void place_kernel(const int* __restrict__ eu, const int* __restrict__ ei,
                             const float* __restrict__ dinv, int* __restrict__ cursor,
                             int* __restrict__ esrc, float* __restrict__ ew) {
  int e = blockIdx.x * 256 + threadIdx.x;
  if (e >= NE_C) return;
  int u = eu[e], v = NU_C + ei[e];
  float w = dinv[u] * dinv[v];
  int p1 = atomicAdd(&cursor[v], 1);  esrc[p1] = u; ew[p1] = w;
  int p2 = atomicAdd(&cursor[u], 1);  esrc[p2] = v; ew[p2] = w;
}

// ---------------- W transpose to bf16, tiled ----------------
__global__ void wtrans_kernel(const float* __restrict__ Wv, const float* __restrict__ Wti,
                              u16* __restrict__ Ov, u16* __restrict__ Ot) {
  __shared__ u16 sT[64][72];
  int b = blockIdx.x;
  const float* W; u16* O; int D;
  if (b < 64) { W = Wv; O = Ov; D = 4096; }
  else        { b -= 64; W = Wti; O = Ot; D = 768; }
  const int k0 = b * 64;
  const int r = threadIdx.x >> 6;
  const int c = threadIdx.x & 63;
  for (int rr = r; rr < 64; rr += 4)
    sT[c][rr] = f2bf(W[(size_t)(k0 + rr) * 64 + c]);
  __syncthreads();
  const int n = threadIdx.x >> 2, seg = threadIdx.x & 3;
  uint4 a0 = *(const uint4*)&sT[n][seg * 16];
  uint4 a1 = *(const uint4*)&sT[n][seg * 16 + 8];
  *(uint4*)(O + (size_t)n * D + k0 + seg * 16)     = a0;
  *(uint4*)(O + (size_t)n * D + k0 + seg * 16 + 8) = a1;
}

// ---------------- homo layers fused (zu | zi) ----------------
__global__ void zuzi_kernel(const float* __restrict__ uf, const float* __restrict__ w,
                            const int* __restrict__ nb, const float* __restrict__ ifb,
                            const int* __restrict__ iv, const int* __restrict__ it,
                            float* __restrict__ zu, float* __restrict__ zi) {
  const int c = threadIdx.x;
  if (blockIdx.x < NU_C) {
    const int u = blockIdx.x;
    __shared__ float at[20];
    if (c < 20) at[c] = w[u * 20 + c];
    __syncthreads();
    float e[20]; float m = -1e30f;
    #pragma unroll
    for (int k = 0; k < 20; ++k) { e[k] = at[k]; m = fmaxf(m, e[k]); }
    float ssum = 0.f;
    #pragma unroll
    for (int k = 0; k < 20; ++k) { e[k] = expf(e[k] - m); ssum += e[k]; }
    float inv = 1.f / ssum;
    float acc = 0.f;
    #pragma unroll
    for (int k = 0; k < 20; ++k) {
      int j = nb[u * 20 + k];
      acc += e[k] * inv * uf[(size_t)j * 128 + c];
    }
    zu[(size_t)u * 128 + c] = uf[(size_t)u * 128 + c] + acc;
  } else {
    const int i = blockIdx.x - NU_C;
    float sv = 0.f, st = 0.f;
    #pragma unroll
    for (int k = 0; k < 10; ++k) sv += ifb[(size_t)iv[i * 10 + k] * 128 + c];
    #pragma unroll
    for (int k = 0; k < 10; ++k) st += ifb[(size_t)it[i * 10 + k] * 128 + c];
    zi[(size_t)i * 128 + c] = ifb[(size_t)i * 128 + c] + 0.01f * sv + 0.09f * st;
  }
}

// ---------------- bpr + reg fused ----------------
__global__ void loss_kernel(const float* __restrict__ zu, const float* __restrict__ zi,
                            const int* __restrict__ uid, const int* __restrict__ pid,
                            const int* __restrict__ nid, const float* __restrict__ pv,
                            const float* __restrict__ pt, const float* __restrict__ alpha,
                            float* __restrict__ out) {
  if (blockIdx.x < 1024) {
    int wv = threadIdx.x >> 6, lane = threadIdx.x & 63;
    int b = blockIdx.x * 4 + wv;
    int u = uid[b], p = pid[b], n = nid[b];
    float2 a  = *(const float2*)(zu + (size_t)u * 128 + lane * 2);
    float2 xp = *(const float2*)(zi + (size_t)p * 128 + lane * 2);
    float2 xn = *(const float2*)(zi + (size_t)n * 128 + lane * 2);
    float d = a.x * (xp.x - xn.x) + a.y * (xp.y - xn.y);
    #pragma unroll
    for (int off = 32; off; off >>= 1) d += __shfl_xor(d, off);
    if (lane == 0) {
      float xv = -d;
      float sp = fmaxf(xv, 0.f) + log1pf(expf(-fabsf(xv)));
      atomicAdd(out, sp * (1.f / (float)B_C));
    }
  } else {
    const size_t N1 = (size_t)NU_C * 64;
    float acc = 0.f;
    for (size_t i = (size_t)(blockIdx.x - 1024) * 256 + threadIdx.x; i < 2 * N1;
         i += (size_t)512 * 256) {
      float x = (i < N1) ? pv[i] : pt[i - N1];
      acc += x * x;
    }
    #pragma unroll
    for (int off = 32; off; off >>= 1) acc += __shfl_xor(acc, off);
    __shared__ float red[4];
    if ((threadIdx.x & 63) == 0) red[threadIdx.x >> 6] = acc;
    __syncthreads();
    if (threadIdx.x == 0) {
      float s = red[0] + red[1] + red[2] + red[3];
      atomicAdd(out, 0.5e-4f * s);
    }
    if (blockIdx.x == 1024 && threadIdx.x == 0) {
      float a = alpha[0];
      atomicAdd(out, 0.5e-4f * a * a);
    }
  }
}

// ---------------- launcher ----------------
extern "C" void kernel_launch(void* const* d_in, const int* in_sizes, int n_in,
                              void* d_out, int out_size, void* d_ws, size_t ws_size,
                              hipStream_t stream) {
  const float* feat_v = (const float*)d_in[0];
  const float* feat_t = (const float*)d_in[1];
  const float* pref_v = (const float*)d_in[2];
  const float* pref_t = (const float*)d_in[3];
  const float* W_v    = (const float*)d_in[4];
  const float* W_t    = (const float*)d_in[5];
  const float* alpha  = (const float*)d_in[6];
  const float* unw    = (const float*)d_in[7];
  const int* eu       = (const int*)d_in[8];
  const int* ei       = (const int*)d_in[9];
  const int* u_ids    = (const int*)d_in[10];
  const int* pos_ids  = (const int*)d_in[11];
  const int* neg_ids  = (const int*)d_in[12];
  const int* user_nb  = (const int*)d_in[13];
  float* out = (float*)d_out;
  char* ws = (char*)d_ws;

  size_t off = 0;
  auto alloc = [&](size_t bytes) { char* p = ws + off; off += (bytes + 255) & ~(size_t)255; return p; };
  u16*   fvbf  = (u16*)alloc((size_t)NPAD_C * 4096 * 2);   // 66.06 MB (gemm; tvb2 after F1)
  u8*    fv8   = (u8*)alloc((size_t)NPAD_C * 4096);        // 33.03 MB (fp8 simtopk)
  u16*   ftbf  = (u16*)alloc((size_t)NPAD_C * 768 * 2);    // 12.39 MB
  u16*   wtv   = (u16*)alloc((size_t)64 * 4096 * 2);
  u16*   wtt   = (u16*)alloc((size_t)64 * 768 * 2);
  float* rn_v  = (float*)alloc(NPAD_C * 4);
  float* rn_t  = (float*)alloc(NPAD_C * 4);
  int*   idx_v = (int*)alloc(NI_C * 10 * 4);
  int*   idx_t = (int*)alloc(NI_C * 10 * 4);
  float* dinv  = (float*)alloc(NTOT_C * 4);
  int*   rowst = (int*)alloc((NTOT_C + 1) * 4);
  int*   curs  = (int*)alloc(NTOT_C * 4);
  int*   esrc  = (int*)alloc((size_t)2 * NE_C * 4);
  float* ew    = (float*)alloc((size_t)2 * NE_C * 4);
  float* x2    = (float*)alloc((size_t)NTOT_C * 128 * 4);  // 14.3 MB
  float* h1    = (float*)alloc((size_t)NTOT_C * 128 * 4);  // 14.3 MB
  char*  pC    = alloc((size_t)(NU_C + NI_C) * 128 * 4 * 2); // 28.7 MB
  u32*   tvb   = (u32*)pC;                                  // 20.3 MB (v-graph, dead before u_f write)
  u32*   tvb2  = (u32*)fvbf;                                // t-graph tv: fvbf dead after F1 gemm
  float* u_f   = (float*)pC;
  float* i_f   = (float*)(pC + (size_t)NU_C * 128 * 4);
  float* z_u   = (float*)(pC + (size_t)(NU_C + NI_C) * 128 * 4);
  float* z_i   = (float*)(pC + (size_t)(2 * NU_C + NI_C) * 128 * 4);

  hipMemsetAsync(out, 0, sizeof(float), stream);
  hipMemsetAsync(dinv, 0, NTOT_C * 4, stream);

  // --- CSR build + conversions (serial prologue; conv also fills x2 user rows) ---
  deg_count_kernel<<<(NE_C + 255) / 256, 256, 0, stream>>>(eu, ei, dinv);
  scan_kernel<<<1, 1024, 0, stream>>>(dinv, rowst, curs);
  place_kernel<<<(NE_C + 255) / 256, 256, 0, stream>>>(eu, ei, dinv, curs, esrc, ew);
  conv_kernel2<<<2 * NPAD_C + 1250, 256, 0, stream>>>(feat_v, feat_t, fvbf, ftbf, fv8,
                                                      rn_v, rn_t, pref_v, pref_t, x2);
  wtrans_kernel<<<76, 256, 0, stream>>>(W_v, W_t, wtv, wtt);

  // --- F1: gemm_xw x2 (first, latency hides under simtopk) ++ simtopk_fp8 ---
  fusedA_kernel<<<250 + NPAIR, 256, 0, stream>>>(
      fv8, rn_v, tvb, fvbf, wtv, ftbf, wtt, x2);

  // --- F2: merge_v (first) ++ gather2 ---
  fusedB_kernel<<<2000 + 14000, 256, 0, stream>>>(rowst, esrc, ew, x2, h1, tvb, idx_v);

  // --- F3: simtopk_t (tv -> tvb2) ++ gather_comb2 ---
  fusedC_kernel<<<NPAIR + 14000, 256, 0, stream>>>(
      ftbf, rn_t, tvb2, rowst, esrc, ew, x2, h1, alpha, u_f, i_f);

  // --- merge_t, homo layers, loss ---
  merge4_kernel<<<2000, 256, 0, stream>>>(tvb2, idx_t);
  zuzi_kernel<<<NU_C + NI_C, 128, 0, stream>>>(u_f, unw, user_nb, i_f, idx_v, idx_t, z_u, z_i);
  loss_kernel<<<1536, 256, 0, stream>>>(z_u, z_i, u_ids, pos_ids, neg_ids,
                                        pref_v, pref_t, alpha, out);
}

// Round 7
// 1003.735 us; speedup vs baseline: 1.0910x; 1.0437x over previous
//
#include <hip/hip_runtime.h>
#include <cstdint>
#include <cstddef>

// ---------------- problem constants ----------------
#define NU_C   20000
#define NI_C   8000
#define NTOT_C 28000          // NU+NI
#define NE_C   200000
#define B_C    4096
#define NPAD_C 8064           // NI padded to 63*128 rows
#define NCHUNK 63
#define NPAIR  2016           // 63*64/2 upper-triangle chunk pairs

typedef unsigned short u16;
typedef unsigned int   u32;
typedef unsigned char  u8;
typedef __bf16 bf16x8 __attribute__((ext_vector_type(8)));
typedef float  f32x4  __attribute__((ext_vector_type(4)));

static __device__ __forceinline__ u16 f2bf(float f) {
  u32 u = __float_as_uint(f);
  return (u16)((u + 0x7fffu + ((u >> 16) & 1u)) >> 16);   // RNE
}

// async global->LDS, 16B per lane; LDS dest is wave-uniform base + lane*16
static __device__ __forceinline__ void gl_lds16(const void* g, void* l) {
  __builtin_amdgcn_global_load_lds(
      (const __attribute__((address_space(1))) void*)g,
      (__attribute__((address_space(3))) void*)l, 16, 0, 0);
}

// XCD-chunked block swizzle (T1). simtopk bodies receive a LOGICAL id in
// [0,NPAIR); the fused grids apply a uniform physical offset, which preserves
// the one-XCD-per-residue-class contiguity.
static __device__ __forceinline__ int xcd_swz(int b) {
  return (b & 7) * (NPAIR / 8) + (b >> 3);
}

// ---------------- W transpose body (64x64 fp32 tile -> bf16 transposed) ----------------
static __device__ __forceinline__ void wtrans_body(int b, const float* __restrict__ Wv,
                                                   const float* __restrict__ Wti,
                                                   u16* __restrict__ Ov, u16* __restrict__ Ot) {
  __shared__ u16 sT[64][72];
  const float* W; u16* O; int D;
  if (b < 64) { W = Wv; O = Ov; D = 4096; }
  else        { b -= 64; W = Wti; O = Ot; D = 768; }
  const int k0 = b * 64;
  const int r = threadIdx.x >> 6;
  const int c = threadIdx.x & 63;
  for (int rr = r; rr < 64; rr += 4)
    sT[c][rr] = f2bf(W[(size_t)(k0 + rr) * 64 + c]);
  __syncthreads();
  const int n = threadIdx.x >> 2, seg = threadIdx.x & 3;
  uint4 a0 = *(const uint4*)&sT[n][seg * 16];
  uint4 a1 = *(const uint4*)&sT[n][seg * 16 + 8];
  *(uint4*)(O + (size_t)n * D + k0 + seg * 16)     = a0;
  *(uint4*)(O + (size_t)n * D + k0 + seg * 16 + 8) = a1;
}

// ---------------- K1: convert + rownorm + wtrans + fill_pref + deg_count ----------------
__global__ void conv_kernel2(const float* __restrict__ Fv, const float* __restrict__ Ft,
                             u16* __restrict__ Fbv, u16* __restrict__ Fbt,
                             u8* __restrict__ Fv8,
                             float* __restrict__ rnv, float* __restrict__ rnt,
                             const float* __restrict__ pv, const float* __restrict__ pt,
                             float* __restrict__ x2,
                             const float* __restrict__ Wv, const float* __restrict__ Wti,
                             u16* __restrict__ wtv, u16* __restrict__ wtt,
                             const int* __restrict__ eu, const int* __restrict__ ei,
                             float* __restrict__ deg) {
  int b = blockIdx.x;
  const int tid = threadIdx.x;
  float ss = 0.f;
  if (b < NPAD_C) {                                       // modality v, D=4096
    const int row = b;
    u16* dst  = Fbv + (size_t)row * 4096;
    u8*  dst8 = Fv8 + (size_t)row * 4096;
    if (row < NI_C) {
      const float* src = Fv + (size_t)row * 4096;
      for (int c = tid * 4; c < 4096; c += 1024) {
        float4 f = *(const float4*)(src + c);
        ss += f.x*f.x + f.y*f.y + f.z*f.z + f.w*f.w;
        ushort4 v; v.x = f2bf(f.x); v.y = f2bf(f.y); v.z = f2bf(f.z); v.w = f2bf(f.w);
        *(ushort4*)(dst + c) = v;
        int w8 = __builtin_amdgcn_cvt_pk_fp8_f32(f.x, f.y, 0, false);
        w8 = __builtin_amdgcn_cvt_pk_fp8_f32(f.z, f.w, w8, true);
        *(u32*)(dst8 + c) = (u32)w8;
      }
    } else {
      for (int c = tid * 4; c < 4096; c += 1024) {
        ushort4 v; v.x = v.y = v.z = v.w = 0;
        *(ushort4*)(dst + c) = v;
        *(u32*)(dst8 + c) = 0u;
      }
    }
    #pragma unroll
    for (int off = 32; off; off >>= 1) ss += __shfl_xor(ss, off);
    __shared__ float red[4];
    if ((tid & 63) == 0) red[tid >> 6] = ss;
    __syncthreads();
    if (tid == 0) {
      float s = red[0] + red[1] + red[2] + red[3];
      rnv[row] = (row < NI_C) ? rsqrtf(s) : 0.f;
    }
  } else if (b < 2 * NPAD_C) {                            // modality t, D=768
    const int row = b - NPAD_C;
    u16* dst = Fbt + (size_t)row * 768;
    if (row < NI_C) {
      const float* src = Ft + (size_t)row * 768;
      for (int c = tid * 4; c < 768; c += 1024) {
        float4 f = *(const float4*)(src + c);
        ss += f.x*f.x + f.y*f.y + f.z*f.z + f.w*f.w;
        ushort4 v; v.x = f2bf(f.x); v.y = f2bf(f.y); v.z = f2bf(f.z); v.w = f2bf(f.w);
        *(ushort4*)(dst + c) = v;
      }
    } else {
      for (int c = tid * 4; c < 768; c += 1024) {
        ushort4 v; v.x = v.y = v.z = v.w = 0;
        *(ushort4*)(dst + c) = v;
      }
    }
    #pragma unroll
    for (int off = 32; off; off >>= 1) ss += __shfl_xor(ss, off);
    __shared__ float red[4];
    if ((tid & 63) == 0) red[tid >> 6] = ss;
    __syncthreads();
    if (tid == 0) {
      float s = red[0] + red[1] + red[2] + red[3];
      rnt[row] = (row < NI_C) ? rsqrtf(s) : 0.f;
    }
  } else if (b < 2 * NPAD_C + 76) {                       // W transpose
    wtrans_body(b - 2 * NPAD_C, Wv, Wti, wtv, wtt);
  } else if (b < 2 * NPAD_C + 76 + 1250) {                // fill_pref: x2 user rows
    const int b2 = b - (2 * NPAD_C + 76);                 // [0,1250), 2048 elems each
    #pragma unroll
    for (int k = 0; k < 8; ++k) {
      int gid = b2 * 2048 + k * 256 + tid;
      int u = gid >> 7, c = gid & 127;
      x2[gid] = (c < 64) ? pv[(size_t)u * 64 + c] : pt[(size_t)u * 64 + (c - 64)];
    }
  } else {                                                // deg_count
    const int b2 = b - (2 * NPAD_C + 76 + 1250);
    int e = b2 * 256 + tid;
    if (e < NE_C) {
      atomicAdd(&deg[eu[e]], 1.f);
      atomicAdd(&deg[NU_C + ei[e]], 1.f);
    }
  }
}

// ---------------- fp8 symmetric fused Gram + top-10 body (v-graph, D=4096) ----------------
// r2/r4 structure: BK=128 single-buffer, 2 barriers per 128-K tile, seg-swizzled
// LDS, XCD-chunked pair map.
static __device__ __forceinline__ void simtopk_fp8_body(
    int bid, char* smem, const u8* __restrict__ F, const float* __restrict__ rn,
    u32* __restrict__ tv) {
  u8*    sB   = (u8*)smem;                   // I rows, cols [k0,k0+64)    [128][64B]
  u8*    sA   = (u8*)(smem + 16384);         // J rows, cols [k0,k0+64)    [128][64B]
  // region +8192 within each: cols [k0+64,k0+128), same layout
  float* T    = (float*)smem;                // transpose [128][66] = 33792 B (epilogue)
  int*   mk   = (int*)smem;                  // merge dump [128][40] (epilogue)
  int*   mk2  = (int*)(smem + 20480);        // repacked [128][10] (epilogue)
  float* sRNI = (float*)(smem + 33792);
  float* sRNJ = (float*)(smem + 34304);

  const int tid  = threadIdx.x;
  const int lane = tid & 63;
  const int wv   = tid >> 6;
  const int n15  = lane & 15;
  const int quad = lane >> 4;

  int I = 0, rem = xcd_swz(bid);
  { int rowlen = NCHUNK;
    while (rem >= rowlen) { rem -= rowlen; rowlen--; I++; } }
  const int J = I + rem;

  const int l2   = lane >> 2;
  const int lseg = (lane & 3) ^ (l2 & 3) ^ (lane >> 4);   // logical seg to fetch
  const u8* gB[2]; const u8* gA[2]; u8* lB[2]; u8* lA[2];
  #pragma unroll
  for (int rep = 0; rep < 2; ++rep) {
    int row = wv * 32 + rep * 16 + l2;
    gB[rep] = F + (size_t)(I * 128 + row) * 4096 + lseg * 16;
    gA[rep] = F + (size_t)(J * 128 + row) * 4096 + lseg * 16;
    lB[rep] = sB + (wv * 32 + rep * 16) * 64;
    lA[rep] = sA + (wv * 32 + rep * 16) * 64;
  }
  const int s_n = (n15 & 3) ^ (n15 >> 2);
  const int q2  = quad >> 1;
  const int q8  = (quad & 1) * 8;
  const int rB0 = (wv * 32 + n15) * 64;
  const int rB1 = rB0 + 16 * 64;

  f32x4 acc[2][8];
  #pragma unroll
  for (int tf = 0; tf < 2; ++tf)
    #pragma unroll
    for (int af = 0; af < 8; ++af) { f32x4 z = {0.f,0.f,0.f,0.f}; acc[tf][af] = z; }

  for (int k0 = 0; k0 < 4096; k0 += 128) {
    __syncthreads();
    gl_lds16(gB[0] + k0,      lB[0]);
    gl_lds16(gB[0] + k0 + 64, lB[0] + 8192);
    gl_lds16(gB[1] + k0,      lB[1]);
    gl_lds16(gB[1] + k0 + 64, lB[1] + 8192);
    gl_lds16(gA[0] + k0,      lA[0]);
    gl_lds16(gA[0] + k0 + 64, lA[0] + 8192);
    gl_lds16(gA[1] + k0,      lA[1]);
    gl_lds16(gA[1] + k0 + 64, lA[1] + 8192);
    if (k0 == 0) {
      if (tid < 128) sRNJ[tid] = rn[J * 128 + tid];
      else           sRNI[tid - 128] = rn[I * 128 + (tid - 128)];
    }
    __syncthreads();
    #pragma unroll
    for (int ksub = 0; ksub < 2; ++ksub) {
      const u8* bBase = sB + ksub * 8192;
      const u8* aBase = sA + ksub * 8192;
      #pragma unroll
      for (int ks = 0; ks < 2; ++ks) {
        const int sw = (((ks * 2 + q2) ^ s_n) << 4) + q8;
        long long b0 = *(const long long*)(bBase + rB0 + sw);
        long long b1 = *(const long long*)(bBase + rB1 + sw);
        #pragma unroll
        for (int af = 0; af < 8; ++af) {
          long long a = *(const long long*)(aBase + (af * 16 + n15) * 64 + sw);
          acc[0][af] = __builtin_amdgcn_mfma_f32_16x16x32_fp8_fp8(a, b0, acc[0][af], 0, 0, 0);
          acc[1][af] = __builtin_amdgcn_mfma_f32_16x16x32_fp8_fp8(a, b1, acc[1][af], 0, 0, 0);
        }
      }
    }
  }

  // ---- I-side: target rows in I, cands in J ----
  int bk[2][10];
  #pragma unroll
  for (int tf = 0; tf < 2; ++tf)
    #pragma unroll
    for (int j = 0; j < 10; ++j) bk[tf][j] = 0;

  #pragma unroll
  for (int af = 0; af < 8; ++af) {
    const float4 rn4 = *(const float4*)(sRNJ + af * 16 + quad * 4);
    const float rna[4] = {rn4.x, rn4.y, rn4.z, rn4.w};
    #pragma unroll
    for (int r = 0; r < 4; ++r) {
      const int ci = J * 128 + af * 16 + quad * 4 + r;
      #pragma unroll
      for (int tf = 0; tf < 2; ++tf) {
        float v = acc[tf][af][r] * rna[r];
        int key = (int)((__float_as_uint(v) & 0xFFFFE000u) | (u32)ci);
        if (ci < NI_C && key > bk[tf][9]) {
          bk[tf][9] = key;
          #pragma unroll
          for (int j = 9; j > 0; --j)
            if (bk[tf][j] > bk[tf][j-1]) { int t = bk[tf][j]; bk[tf][j] = bk[tf][j-1]; bk[tf][j-1] = t; }
        }
      }
    }
  }
  __syncthreads();
  #pragma unroll
  for (int tf = 0; tf < 2; ++tf) {
    int rl = wv * 32 + tf * 16 + n15;
    #pragma unroll
    for (int j = 0; j < 10; ++j) mk[rl * 40 + quad * 10 + j] = bk[tf][j];
  }
  __syncthreads();
  if (tid < 128) {                            // 4-way sorted-list tournament
    int* m = mk + tid * 40;
    int h0 = 0, h1 = 10, h2 = 20, h3 = 30;
    int v0 = m[0], v1 = m[10], v2 = m[20], v3 = m[30];
    #pragma unroll
    for (int s = 0; s < 10; ++s) {
      int m01 = v0 > v1 ? v0 : v1, m23 = v2 > v3 ? v2 : v3;
      int mx = m01 > m23 ? m01 : m23;
      mk2[tid * 10 + s] = mx;
      if      (mx == v0) { ++h0; v0 = (h0 < 10) ? m[h0] : (int)0x80000000; }
      else if (mx == v1) { ++h1; v1 = (h1 < 20) ? m[h1] : (int)0x80000000; }
      else if (mx == v2) { ++h2; v2 = (h2 < 30) ? m[h2] : (int)0x80000000; }
      else               { ++h3; v3 = (h3 < 40) ? m[h3] : (int)0x80000000; }
    }
  }
  __syncthreads();
  { u32* o = tv + ((size_t)J * NPAD_C + I * 128) * 10;
    for (int g = tid; g < 1280; g += 256) o[g] = (u32)mk2[g]; }

  if (I == J) return;

  // ---- J-side: target rows in J, cands in I (via transpose) ----
  int bj[2][10];
  #pragma unroll
  for (int s = 0; s < 2; ++s)
    #pragma unroll
    for (int j = 0; j < 10; ++j) bj[s][j] = 0;

  #pragma unroll
  for (int tf = 0; tf < 2; ++tf) {
    __syncthreads();
    #pragma unroll
    for (int af = 0; af < 8; ++af)
      #pragma unroll
      for (int r = 0; r < 4; ++r)
        T[(af * 16 + quad * 4 + r) * 66 + wv * 16 + n15] = acc[tf][af][r];
    __syncthreads();
    #pragma unroll
    for (int s = 0; s < 2; ++s) {
      const int c_own = wv * 32 + s * 16 + n15;
      #pragma unroll
      for (int j = 0; j < 16; ++j) {
        const int t  = quad * 32 + tf * 16 + j;
        const int t64 = quad * 16 + j;
        float v = T[c_own * 66 + t64] * sRNI[t];
        const int ti = I * 128 + t;
        int key = (int)((__float_as_uint(v) & 0xFFFFE000u) | (u32)ti);
        if (ti < NI_C && key > bj[s][9]) {
          bj[s][9] = key;
          #pragma unroll
          for (int q = 9; q > 0; --q)
            if (bj[s][q] > bj[s][q-1]) { int tt = bj[s][q]; bj[s][q] = bj[s][q-1]; bj[s][q-1] = tt; }
        }
      }
    }
  }
  __syncthreads();
  #pragma unroll
  for (int s = 0; s < 2; ++s) {
    int rl = wv * 32 + s * 16 + n15;
    #pragma unroll
    for (int j = 0; j < 10; ++j) mk[rl * 40 + quad * 10 + j] = bj[s][j];
  }
  __syncthreads();
  if (tid < 128) {
    int* m = mk + tid * 40;
    int h0 = 0, h1 = 10, h2 = 20, h3 = 30;
    int v0 = m[0], v1 = m[10], v2 = m[20], v3 = m[30];
    #pragma unroll
    for (int s = 0; s < 10; ++s) {
      int m01 = v0 > v1 ? v0 : v1, m23 = v2 > v3 ? v2 : v3;
      int mx = m01 > m23 ? m01 : m23;
      mk2[tid * 10 + s] = mx;
      if      (mx == v0) { ++h0; v0 = (h0 < 10) ? m[h0] : (int)0x80000000; }
      else if (mx == v1) { ++h1; v1 = (h1 < 20) ? m[h1] : (int)0x80000000; }
      else if (mx == v2) { ++h2; v2 = (h2 < 30) ? m[h2] : (int)0x80000000; }
      else               { ++h3; v3 = (h3 < 40) ? m[h3] : (int)0x80000000; }
    }
  }
  __syncthreads();
  { u32* o = tv + ((size_t)I * NPAD_C + J * 128) * 10;
    for (int g = tid; g < 1280; g += 256) o[g] = (u32)mk2[g]; }
}

// ---------------- bf16 symmetric fused Gram + top-10 body (t-graph, D=768) ----------------
static __device__ __forceinline__ void simtopk_bf16_body(
    int bid, char* smem, const u16* __restrict__ F, const float* __restrict__ rn,
    u32* __restrict__ tv) {
  u16*   sB   = (u16*)smem;
  u16*   sA   = (u16*)(smem + 16384);
  float* T    = (float*)smem;
  int*   mk   = (int*)smem;
  int*   mk2  = (int*)(smem + 20480);
  float* sRNI = (float*)(smem + 34816);
  float* sRNJ = (float*)(smem + 35328);

  const int tid  = threadIdx.x;
  const int lane = tid & 63;
  const int wv   = tid >> 6;
  const int n15  = lane & 15;
  const int quad = lane >> 4;

  int I = 0, rem = xcd_swz(bid);
  { int rowlen = NCHUNK;
    while (rem >= rowlen) { rem -= rowlen; rowlen--; I++; } }
  const int J = I + rem;

  const int l8  = lane >> 3;
  const int sgu = ((lane & 7) ^ l8) << 3;
  const u16* gB[4]; const u16* gA[4]; u16* lB[4]; u16* lA[4];
  #pragma unroll
  for (int rep = 0; rep < 4; ++rep) {
    int row = wv * 32 + rep * 8 + l8;
    gB[rep] = F + (size_t)(I * 128 + row) * 768 + sgu;
    gA[rep] = F + (size_t)(J * 128 + row) * 768 + sgu;
    lB[rep] = sB + wv * 2048 + rep * 512;
    lA[rep] = sA + wv * 2048 + rep * 512;
  }
  const int swu0 = ((quad    ) ^ (n15 & 7)) << 3;
  const int swu1 = ((quad + 4) ^ (n15 & 7)) << 3;
  const int rowB0 = (wv * 32 + n15) * 64;
  const int rowB1 = rowB0 + 16 * 64;

  f32x4 acc[2][8];
  #pragma unroll
  for (int tf = 0; tf < 2; ++tf)
    #pragma unroll
    for (int af = 0; af < 8; ++af) { f32x4 z = {0.f,0.f,0.f,0.f}; acc[tf][af] = z; }

  for (int k0 = 0; k0 < 768; k0 += 64) {
    __syncthreads();
    #pragma unroll
    for (int rep = 0; rep < 4; ++rep) gl_lds16(gB[rep] + k0, lB[rep]);
    #pragma unroll
    for (int rep = 0; rep < 4; ++rep) gl_lds16(gA[rep] + k0, lA[rep]);
    if (k0 == 0) {
      if (tid < 128) sRNJ[tid] = rn[J * 128 + tid];
      else           sRNI[tid - 128] = rn[I * 128 + (tid - 128)];
    }
    __syncthreads();
    #pragma unroll
    for (int ks = 0; ks < 2; ++ks) {
      const int swu = ks ? swu1 : swu0;
      bf16x8 b0 = *(const bf16x8*)(sB + rowB0 + swu);
      bf16x8 b1 = *(const bf16x8*)(sB + rowB1 + swu);
      #pragma unroll
      for (int af = 0; af < 8; ++af) {
        bf16x8 a = *(const bf16x8*)(sA + (af * 16 + n15) * 64 + swu);
        acc[0][af] = __builtin_amdgcn_mfma_f32_16x16x32_bf16(a, b0, acc[0][af], 0, 0, 0);
        acc[1][af] = __builtin_amdgcn_mfma_f32_16x16x32_bf16(a, b1, acc[1][af], 0, 0, 0);
      }
    }
  }

  int bk[2][10];
  #pragma unroll
  for (int tf = 0; tf < 2; ++tf)
    #pragma unroll
    for (int j = 0; j < 10; ++j) bk[tf][j] = 0;

  #pragma unroll
  for (int af = 0; af < 8; ++af) {
    const float4 rn4 = *(const float4*)(sRNJ + af * 16 + quad * 4);
    const float rna[4] = {rn4.x, rn4.y, rn4.z, rn4.w};
    #pragma unroll
    for (int r = 0; r < 4; ++r) {
      const int ci = J * 128 + af * 16 + quad * 4 + r;
      #pragma unroll
      for (int tf = 0; tf < 2; ++tf) {
        float v = acc[tf][af][r] * rna[r];
        int key = (int)((__float_as_uint(v) & 0xFFFFE000u) | (u32)ci);
        if (ci < NI_C && key > bk[tf][9]) {
          bk[tf][9] = key;
          #pragma unroll
          for (int j = 9; j > 0; --j)
            if (bk[tf][j] > bk[tf][j-1]) { int t = bk[tf][j]; bk[tf][j] = bk[tf][j-1]; bk[tf][j-1] = t; }
        }
      }
    }
  }
  __syncthreads();
  #pragma unroll
  for (int tf = 0; tf < 2; ++tf) {
    int rl = wv * 32 + tf * 16 + n15;
    #pragma unroll
    for (int j = 0; j < 10; ++j) mk[rl * 40 + quad * 10 + j] = bk[tf][j];
  }
  __syncthreads();
  if (tid < 128) {
    int* m = mk + tid * 40;
    int h0 = 0, h1 = 10, h2 = 20, h3 = 30;
    int v0 = m[0], v1 = m[10], v2 = m[20], v3 = m[30];
    #pragma unroll
    for (int s = 0; s < 10; ++s) {
      int m01 = v0 > v1 ? v0 : v1, m23 = v2 > v3 ? v2 : v3;
      int mx = m01 > m23 ? m01 : m23;
      mk2[tid * 10 + s] = mx;
      if      (mx == v0) { ++h0; v0 = (h0 < 10) ? m[h0] : (int)0x80000000; }
      else if (mx == v1) { ++h1; v1 = (h1 < 20) ? m[h1] : (int)0x80000000; }
      else if (mx == v2) { ++h2; v2 = (h2 < 30) ? m[h2] : (int)0x80000000; }
      else               { ++h3; v3 = (h3 < 40) ? m[h3] : (int)0x80000000; }
    }
  }
  __syncthreads();
  { u32* o = tv + ((size_t)J * NPAD_C + I * 128) * 10;
    for (int g = tid; g < 1280; g += 256) o[g] = (u32)mk2[g]; }

  if (I == J) return;

  int bj[2][10];
  #pragma unroll
  for (int s = 0; s < 2; ++s)
    #pragma unroll
    for (int j = 0; j < 10; ++j) bj[s][j] = 0;

  #pragma unroll
  for (int tf = 0; tf < 2; ++tf) {
    __syncthreads();
    #pragma unroll
    for (int af = 0; af < 8; ++af)
      #pragma unroll
      for (int r = 0; r < 4; ++r)
        T[(af * 16 + quad * 4 + r) * 66 + wv * 16 + n15] = acc[tf][af][r];
    __syncthreads();
    #pragma unroll
    for (int s = 0; s < 2; ++s) {
      const int c_own = wv * 32 + s * 16 + n15;
      #pragma unroll
      for (int j = 0; j < 16; ++j) {
        const int t  = quad * 32 + tf * 16 + j;
        const int t64 = quad * 16 + j;
        float v = T[c_own * 66 + t64] * sRNI[t];
        const int ti = I * 128 + t;
        int key = (int)((__float_as_uint(v) & 0xFFFFE000u) | (u32)ti);
        if (ti < NI_C && key > bj[s][9]) {
          bj[s][9] = key;
          #pragma unroll
          for (int q = 9; q > 0; --q)
            if (bj[s][q] > bj[s][q-1]) { int tt = bj[s][q]; bj[s][q] = bj[s][q-1]; bj[s][q-1] = tt; }
        }
      }
    }
  }
  __syncthreads();
  #pragma unroll
  for (int s = 0; s < 2; ++s) {
    int rl = wv * 32 + s * 16 + n15;
    #pragma unroll
    for (int j = 0; j < 10; ++j) mk[rl * 40 + quad * 10 + j] = bj[s][j];
  }
  __syncthreads();
  if (tid < 128) {
    int* m = mk + tid * 40;
    int h0 = 0, h1 = 10, h2 = 20, h3 = 30;
    int v0 = m[0], v1 = m[10], v2 = m[20], v3 = m[30];
    #pragma unroll
    for (int s = 0; s < 10; ++s) {
      int m01 = v0 > v1 ? v0 : v1, m23 = v2 > v3 ? v2 : v3;
      int mx = m01 > m23 ? m01 : m23;
      mk2[tid * 10 + s] = mx;
      if      (mx == v0) { ++h0; v0 = (h0 < 10) ? m[h0] : (int)0x80000000; }
      else if (mx == v1) { ++h1; v1 = (h1 < 20) ? m[h1] : (int)0x80000000; }
      else if (mx == v2) { ++h2; v2 = (h2 < 30) ? m[h2] : (int)0x80000000; }
      else               { ++h3; v3 = (h3 < 40) ? m[h3] : (int)0x80000000; }
    }
  }
  __syncthreads();
  { u32* o = tv + ((size_t)I * NPAD_C + J * 128) * 10;
    for (int g = tid; g < 1280; g += 256) o[g] = (u32)mk2[g]; }
}

// ---------------- merge: 63 sorted lists x 10 -> top-10, 4 rows per 256-thr block ----
static __device__ __forceinline__ void merge4_body(int mb, int* fkbase,
                                                   const u32* __restrict__ tv,
                                                   int* __restrict__ idx) {
  const int w    = threadIdx.x >> 6;
  const int lane = threadIdx.x & 63;
  const int row  = mb * 4 + w;
  int* fk = fkbase + w * 640;
  for (int g = lane; g < 630; g += 64)
    fk[g] = (int)tv[((size_t)(g / 10) * NPAD_C + row) * 10 + (g % 10)];
  if (lane < 10) fk[630 + lane] = (int)0x80000000;
  __syncthreads();
  int v[10];
  #pragma unroll
  for (int j = 0; j < 10; ++j) v[j] = fk[lane + j * 64];
  #pragma unroll 1
  for (int s = 0; s < 10; ++s) {
    int loc = v[0];
    #pragma unroll
    for (int j = 1; j < 10; ++j) loc = v[j] > loc ? v[j] : loc;
    #pragma unroll
    for (int off = 32; off; off >>= 1) {
      int o = __shfl_xor(loc, off); loc = o > loc ? o : loc;
    }
    if (lane == 0) idx[row * 10 + s] = loc & 0x1FFF;
    #pragma unroll
    for (int j = 0; j < 10; ++j) if (v[j] == loc) v[j] = (int)0x80000000;
  }
}

// ---------------- feat @ W via bf16 MFMA body, M=64 tiles ----------------
template<int D>
static __device__ __forceinline__ void gemm_xw_body(
    int bid, char* smem, const u16* __restrict__ F, const u16* __restrict__ Wt,
    float* __restrict__ x2, int modeoff) {
  u16* sF = (u16*)smem;                      // 8192 B
  const int tid  = threadIdx.x;
  const int lane = tid & 63;
  const int wv   = tid >> 6;
  const int n15  = lane & 15;
  const int quad = lane >> 4;
  const int l8   = lane >> 3;
  const int sgu  = ((lane & 7) ^ l8) << 3;
  const u16* gF[2]; u16* lF[2];
  #pragma unroll
  for (int rep = 0; rep < 2; ++rep) {
    int row = rep * 32 + wv * 8 + l8;
    gF[rep] = F + (size_t)(bid * 64 + row) * D + sgu;
    lF[rep] = sF + (rep * 32 + wv * 8) * 64;
  }
  const int swu0 = ((quad    ) ^ (n15 & 7)) << 3;
  const int swu1 = ((quad + 4) ^ (n15 & 7)) << 3;

  f32x4 acc[4];
  #pragma unroll
  for (int nf = 0; nf < 4; ++nf) { f32x4 z = {0.f,0.f,0.f,0.f}; acc[nf] = z; }

  for (int k0 = 0; k0 < D; k0 += 64) {
    __syncthreads();
    gl_lds16(gF[0] + k0, lF[0]);
    gl_lds16(gF[1] + k0, lF[1]);
    __syncthreads();
    #pragma unroll
    for (int ks = 0; ks < 2; ++ks) {
      const int swu = ks ? swu1 : swu0;
      bf16x8 a = *(const bf16x8*)(sF + (wv * 16 + n15) * 64 + swu);
      #pragma unroll
      for (int nf = 0; nf < 4; ++nf) {
        bf16x8 b = *(const bf16x8*)(Wt + (size_t)(nf * 16 + n15) * D + k0 + ks * 32 + quad * 8);
        acc[nf] = __builtin_amdgcn_mfma_f32_16x16x32_bf16(a, b, acc[nf], 0, 0, 0);
      }
    }
  }
  #pragma unroll
  for (int nf = 0; nf < 4; ++nf)
    #pragma unroll
    for (int r = 0; r < 4; ++r) {
      int row = bid * 64 + wv * 16 + quad * 4 + r;
      if (row < NI_C)
        x2[(size_t)(NU_C + row) * 128 + modeoff + nf * 16 + n15] = acc[nf][r];
    }
}

// ---------------- gather bodies ----------------
static __device__ __forceinline__ void gather2_body(
    int bid, const int* __restrict__ row_start, const int* __restrict__ esrc,
    const float* __restrict__ ew, const float* __restrict__ x2, float* __restrict__ h1) {
  const int node = bid * 2 + (threadIdx.x >> 7);
  const int ch   = threadIdx.x & 127;
  if (node >= NTOT_C) return;
  const int b = row_start[node], e = row_start[node + 1];
  float acc = 0.f;
  for (int i = b; i < e; ++i)
    acc += ew[i] * x2[(size_t)esrc[i] * 128 + ch];
  h1[(size_t)node * 128 + ch] = acc;
}

static __device__ __forceinline__ void gather_comb2_body(
    int bid, const int* __restrict__ row_start, const int* __restrict__ esrc,
    const float* __restrict__ ew, const float* __restrict__ x2,
    const float* __restrict__ h1, const float* __restrict__ alpha,
    float* __restrict__ uf, float* __restrict__ ifb) {
  const int node = bid * 2 + (threadIdx.x >> 7);
  const int ch   = threadIdx.x & 127;
  if (node >= NTOT_C) return;
  const int b = row_start[node], e = row_start[node + 1];
  float acc = 0.f;
  for (int i = b; i < e; ++i)
    acc += ew[i] * h1[(size_t)esrc[i] * 128 + ch];
  float val = x2[(size_t)node * 128 + ch] + h1[(size_t)node * 128 + ch] + acc;
  if (node < NU_C) {
    float av = 1.f / (1.f + expf(-alpha[0]));
    float coef = (ch < 64) ? av : (1.f - av);
    uf[(size_t)node * 128 + ch] = coef * val;
  } else {
    ifb[(size_t)(node - NU_C) * 128 + ch] = val;
  }
}

// ---------------- place body (CSR fill) ----------------
static __device__ __forceinline__ void place_body(
    int bid, const int* __restrict__ eu, const int* __restrict__ ei,
    const float* __restrict__ dinv, int* __restrict__ cursor,
    int* __restrict__ esrc, float* __restrict__ ew) {
  int e = bid * 256 + threadIdx.x;
  if (e >= NE_C) return;
  int u = eu[e], v = NU_C + ei[e];
  float w = dinv[u] * dinv[v];
  int p1 = atomicAdd(&cursor[v], 1);  esrc[p1] = u; ew[p1] = w;
  int p2 = atomicAdd(&cursor[u], 1);  esrc[p2] = v; ew[p2] = w;
}

// ---------------- fused launches (LPT ordering: long/latency-bound blocks FIRST) ----
// F1: gemm_xw<4096> (125) ++ gemm_xw<768> (125) ++ simtopk_fp8 (2016, pole) ++
//     place (782 trivial blocks, slot into the drain tail; feeds F2 only).
__launch_bounds__(256)
__global__ void fusedA_kernel(const u8* __restrict__ F8, const float* __restrict__ rnv,
                              u32* __restrict__ tv,
                              const u16* __restrict__ Fvb, const u16* __restrict__ Wtv,
                              const u16* __restrict__ Ftb, const u16* __restrict__ Wtt,
                              float* __restrict__ x2,
                              const int* __restrict__ eu, const int* __restrict__ ei,
                              const float* __restrict__ dinv, int* __restrict__ cursor,
                              int* __restrict__ esrc, float* __restrict__ ew) {
  __shared__ __align__(16) char smem[34816];
  int b = blockIdx.x;
  if (b < 125) { gemm_xw_body<4096>(b, smem, Fvb, Wtv, x2, 0); return; }
  b -= 125;
  if (b < 125) { gemm_xw_body<768>(b, smem, Ftb, Wtt, x2, 64); return; }
  b -= 125;
  if (b < NPAIR) { simtopk_fp8_body(b, smem, F8, rnv, tv); return; }
  place_body(b - NPAIR, eu, ei, dinv, cursor, esrc, ew);
}

// F2: simtopk_t (2016, pole, first; tvb2 = dead fvbf) ++ merge_v (2000) ++ gather2 (14000).
__launch_bounds__(256)
__global__ void fusedB_kernel(const u16* __restrict__ Ftb, const float* __restrict__ rnt,
                              u32* __restrict__ tv2,
                              const u32* __restrict__ tv, int* __restrict__ idx,
                              const int* __restrict__ row_start, const int* __restrict__ esrc,
                              const float* __restrict__ ew, const float* __restrict__ x2,
                              float* __restrict__ h1) {
  __shared__ __align__(16) char smem[40960];
  int b = blockIdx.x;
  if (b < NPAIR) { simtopk_bf16_body(b, smem, Ftb, rnt, tv2); return; }
  b -= NPAIR;
  if (b < 2000) { merge4_body(b, (int*)smem, tv, idx); return; }
  gather2_body(b - 2000, row_start, esrc, ew, x2, h1);
}

// F3: merge_t (2000, first; consumes tvb2 from F2) ++ gather_comb2 (14000).
// Safe: tvb (pC) was consumed by merge_v in F2, so u_f/i_f writes over pC are race-free.
__launch_bounds__(256)
__global__ void fusedC_kernel(const u32* __restrict__ tv2, int* __restrict__ idxt,
                              const int* __restrict__ row_start, const int* __restrict__ esrc,
                              const float* __restrict__ ew, const float* __restrict__ x2,
                              const float* __restrict__ h1, const float* __restrict__ alpha,
                              float* __restrict__ uf, float* __restrict__ ifb) {
  __shared__ __align__(16) int fk[4 * 640];
  int b = blockIdx.x;
  if (b < 2000) { merge4_body(b, fk, tv2, idxt); return; }
  gather_comb2_body(b - 2000, row_start, esrc, ew, x2, h1, alpha, uf, ifb);
}

// ---------------- scan (CSR prefix) ----------------
__global__ void scan_kernel(float* __restrict__ deg, int* __restrict__ row_start,
                            int* __restrict__ cursor) {
  __shared__ int part[1024];
  const int tid = threadIdx.x;
  const int base = tid * 28;
  float dl[28];
  int local[28];
  int s = 0;
  #pragma unroll
  for (int j = 0; j < 28; ++j) {
    int n = base + j;
    float df = (n < NTOT_C) ? deg[n] : 0.f;
    dl[j] = df;
    local[j] = s; s += (int)df;
  }
  part[tid] = s;
  __syncthreads();
  for (int off = 1; off < 1024; off <<= 1) {
    int v = (tid >= off) ? part[tid - off] : 0;
    __syncthreads();
    part[tid] += v;
    __syncthreads();
  }
  int pre = (tid > 0) ? part[tid - 1] : 0;
  #pragma unroll
  for (int j = 0; j < 28; ++j) {
    int n = base + j;
    if (n < NTOT_C) {
      row_start[n] = pre + local[j];
      cursor[n]    = pre + local[j];
      deg[n]       = rsqrtf(fmaxf(dl[j], 1.f));
    }
  }
  if (tid == 1023) row_start[NTOT_C] = part[1023];
}

// ---------------- homo layers fused (zu | zi) ----------------
__global__ void zuzi_kernel(const float* __restrict__ uf, const float* __restrict__ w,
                            const int* __restrict__ nb, const float* __restrict__ ifb,
                            const int* __restrict__ iv, const int* __restrict__ it,
                            float* __restrict__ zu, float* __restrict__ zi) {
  const int c = threadIdx.x;
  if (blockIdx.x < NU_C) {
    const int u = blockIdx.x;
    __shared__ float at[20];
    if (c < 20) at[c] = w[u * 20 + c];
    __syncthreads();
    float e[20]; float m = -1e30f;
    #pragma unroll
    for (int k = 0; k < 20; ++k) { e[k] = at[k]; m = fmaxf(m, e[k]); }
    float ssum = 0.f;
    #pragma unroll
    for (int k = 0; k < 20; ++k) { e[k] = expf(e[k] - m); ssum += e[k]; }
    float inv = 1.f / ssum;
    float acc = 0.f;
    #pragma unroll
    for (int k = 0; k < 20; ++k) {
      int j = nb[u * 20 + k];
      acc += e[k] * inv * uf[(size_t)j * 128 + c];
    }
    zu[(size_t)u * 128 + c] = uf[(size_t)u * 128 + c] + acc;
  } else {
    const int i = blockIdx.x - NU_C;
    float sv = 0.f, st = 0.f;
    #pragma unroll
    for (int k = 0; k < 10; ++k) sv += ifb[(size_t)iv[i * 10 + k] * 128 + c];
    #pragma unroll
    for (int k = 0; k < 10; ++k) st += ifb[(size_t)it[i * 10 + k] * 128 + c];
    zi[(size_t)i * 128 + c] = ifb[(size_t)i * 128 + c] + 0.01f * sv + 0.09f * st;
  }
}

// ---------------- bpr + reg fused ----------------
__global__ void loss_kernel(const float* __restrict__ zu, const float* __restrict__ zi,
                            const int* __restrict__ uid, const int* __restrict__ pid,
                            const int* __restrict__ nid, const float* __restrict__ pv,
                            const float* __restrict__ pt, const float* __restrict__ alpha,
                            float* __restrict__ out) {
  if (blockIdx.x < 1024) {
    int wv = threadIdx.x >> 6, lane = threadIdx.x & 63;
    int b = blockIdx.x * 4 + wv;
    int u = uid[b], p = pid[b], n = nid[b];
    float2 a  = *(const float2*)(zu + (size_t)u * 128 + lane * 2);
    float2 xp = *(const float2*)(zi + (size_t)p * 128 + lane * 2);
    float2 xn = *(const float2*)(zi + (size_t)n * 128 + lane * 2);
    float d = a.x * (xp.x - xn.x) + a.y * (xp.y - xn.y);
    #pragma unroll
    for (int off = 32; off; off >>= 1) d += __shfl_xor(d, off);
    if (lane == 0) {
      float xv = -d;
      float sp = fmaxf(xv, 0.f) + log1pf(expf(-fabsf(xv)));
      atomicAdd(out, sp * (1.f / (float)B_C));
    }
  } else {
    const size_t N1 = (size_t)NU_C * 64;
    float acc = 0.f;
    for (size_t i = (size_t)(blockIdx.x - 1024) * 256 + threadIdx.x; i < 2 * N1;
         i += (size_t)512 * 256) {
      float x = (i < N1) ? pv[i] : pt[i - N1];
      acc += x * x;
    }
    #pragma unroll
    for (int off = 32; off; off >>= 1) acc += __shfl_xor(acc, off);
    __shared__ float red[4];
    if ((threadIdx.x & 63) == 0) red[threadIdx.x >> 6] = acc;
    __syncthreads();
    if (threadIdx.x == 0) {
      float s = red[0] + red[1] + red[2] + red[3];
      atomicAdd(out, 0.5e-4f * s);
    }
    if (blockIdx.x == 1024 && threadIdx.x == 0) {
      float a = alpha[0];
      atomicAdd(out, 0.5e-4f * a * a);
    }
  }
}

// ---------------- launcher ----------------
extern "C" void kernel_launch(void* const* d_in, const int* in_sizes, int n_in,
                              void* d_out, int out_size, void* d_ws, size_t ws_size,
                              hipStream_t stream) {
  const float* feat_v = (const float*)d_in[0];
  const float* feat_t = (const float*)d_in[1];
  const float* pref_v = (const float*)d_in[2];
  const float* pref_t = (const float*)d_in[3];
  const float* W_v    = (const float*)d_in[4];
  const float* W_t    = (const float*)d_in[5];
  const float* alpha  = (const float*)d_in[6];
  const float* unw    = (const float*)d_in[7];
  const int* eu       = (const int*)d_in[8];
  const int* ei       = (const int*)d_in[9];
  const int* u_ids    = (const int*)d_in[10];
  const int* pos_ids  = (const int*)d_in[11];
  const int* neg_ids  = (const int*)d_in[12];
  const int* user_nb  = (const int*)d_in[13];
  float* out = (float*)d_out;
  char* ws = (char*)d_ws;

  size_t off = 0;
  auto alloc = [&](size_t bytes) { char* p = ws + off; off += (bytes + 255) & ~(size_t)255; return p; };
  u16*   fvbf  = (u16*)alloc((size_t)NPAD_C * 4096 * 2);   // 66.06 MB (gemm; tvb2 after F1)
  u8*    fv8   = (u8*)alloc((size_t)NPAD_C * 4096);        // 33.03 MB (fp8 simtopk)
  u16*   ftbf  = (u16*)alloc((size_t)NPAD_C * 768 * 2);    // 12.39 MB
  u16*   wtv   = (u16*)alloc((size_t)64 * 4096 * 2);
  u16*   wtt   = (u16*)alloc((size_t)64 * 768 * 2);
  float* rn_v  = (float*)alloc(NPAD_C * 4);
  float* rn_t  = (float*)alloc(NPAD_C * 4);
  int*   idx_v = (int*)alloc(NI_C * 10 * 4);
  int*   idx_t = (int*)alloc(NI_C * 10 * 4);
  float* dinv  = (float*)alloc(NTOT_C * 4);
  int*   rowst = (int*)alloc((NTOT_C + 1) * 4);
  int*   curs  = (int*)alloc(NTOT_C * 4);
  int*   esrc  = (int*)alloc((size_t)2 * NE_C * 4);
  float* ew    = (float*)alloc((size_t)2 * NE_C * 4);
  float* x2    = (float*)alloc((size_t)NTOT_C * 128 * 4);  // 14.3 MB
  float* h1    = (float*)alloc((size_t)NTOT_C * 128 * 4);  // 14.3 MB
  char*  pC    = alloc((size_t)(NU_C + NI_C) * 128 * 4 * 2); // 28.7 MB
  u32*   tvb   = (u32*)pC;                                  // 20.3 MB (v-graph, consumed in F2)
  u32*   tvb2  = (u32*)fvbf;                                // t-graph tv: fvbf dead after F1 gemm
  float* u_f   = (float*)pC;
  float* i_f   = (float*)(pC + (size_t)NU_C * 128 * 4);
  float* z_u   = (float*)(pC + (size_t)(NU_C + NI_C) * 128 * 4);
  float* z_i   = (float*)(pC + (size_t)(2 * NU_C + NI_C) * 128 * 4);

  hipMemsetAsync(out, 0, sizeof(float), stream);
  hipMemsetAsync(dinv, 0, NTOT_C * 4, stream);

  // --- K1: conv + wtrans + fill_pref + deg_count ---
  conv_kernel2<<<2 * NPAD_C + 76 + 1250 + (NE_C + 255) / 256, 256, 0, stream>>>(
      feat_v, feat_t, fvbf, ftbf, fv8, rn_v, rn_t, pref_v, pref_t, x2,
      W_v, W_t, wtv, wtt, eu, ei, dinv);

  // --- scan (single block; rowst/curs + dinv finalize) ---
  scan_kernel<<<1, 1024, 0, stream>>>(dinv, rowst, curs);

  // --- F1: gemm_xw x2 ++ simtopk_fp8 ++ place ---
  fusedA_kernel<<<250 + NPAIR + (NE_C + 255) / 256, 256, 0, stream>>>(
      fv8, rn_v, tvb, fvbf, wtv, ftbf, wtt, x2, eu, ei, dinv, curs, esrc, ew);

  // --- F2: simtopk_t (tv -> tvb2) ++ merge_v ++ gather2 ---
  fusedB_kernel<<<NPAIR + 2000 + 14000, 256, 0, stream>>>(
      ftbf, rn_t, tvb2, tvb, idx_v, rowst, esrc, ew, x2, h1);

  // --- F3: merge_t ++ gather_comb2 ---
  fusedC_kernel<<<2000 + 14000, 256, 0, stream>>>(
      tvb2, idx_t, rowst, esrc, ew, x2, h1, alpha, u_f, i_f);

  // --- homo layers, loss ---
  zuzi_kernel<<<NU_C + NI_C, 128, 0, stream>>>(u_f, unw, user_nb, i_f, idx_v, idx_t, z_u, z_i);
  loss_kernel<<<1536, 256, 0, stream>>>(z_u, z_i, u_ids, pos_ids, neg_ids,
                                        pref_v, pref_t, alpha, out);
}

// Round 8
// 986.018 us; speedup vs baseline: 1.1106x; 1.0180x over previous
//
#include <hip/hip_runtime.h>
#include <cstdint>
#include <cstddef>

// ---------------- problem constants ----------------
#define NU_C   20000
#define NI_C   8000
#define NTOT_C 28000          // NU+NI
#define NE_C   200000
#define B_C    4096
#define NPAD_C 8064           // NI padded to 63*128 rows
#define NCHUNK 63
#define NPAIR  2016           // 63*64/2 upper-triangle chunk pairs
#define NEB    782            // (NE_C+255)/256

typedef unsigned short u16;
typedef unsigned int   u32;
typedef unsigned char  u8;
typedef __bf16 bf16x8 __attribute__((ext_vector_type(8)));
typedef float  f32x4  __attribute__((ext_vector_type(4)));

static __device__ __forceinline__ u16 f2bf(float f) {
  u32 u = __float_as_uint(f);
  return (u16)((u + 0x7fffu + ((u >> 16) & 1u)) >> 16);   // RNE
}

// async global->LDS, 16B per lane; LDS dest is wave-uniform base + lane*16
static __device__ __forceinline__ void gl_lds16(const void* g, void* l) {
  __builtin_amdgcn_global_load_lds(
      (const __attribute__((address_space(1))) void*)g,
      (__attribute__((address_space(3))) void*)l, 16, 0, 0);
}

// XCD-chunked block swizzle (T1). simtopk bodies receive a LOGICAL id in
// [0,NPAIR); the fused grids apply a uniform physical offset, which preserves
// the one-XCD-per-residue-class contiguity.
static __device__ __forceinline__ int xcd_swz(int b) {
  return (b & 7) * (NPAIR / 8) + (b >> 3);
}

// ---------------- W transpose body (64x64 fp32 tile -> bf16 transposed) ----------------
static __device__ __forceinline__ void wtrans_body(int b, const float* __restrict__ Wv,
                                                   const float* __restrict__ Wti,
                                                   u16* __restrict__ Ov, u16* __restrict__ Ot) {
  __shared__ u16 sT[64][72];
  const float* W; u16* O; int D;
  if (b < 64) { W = Wv; O = Ov; D = 4096; }
  else        { b -= 64; W = Wti; O = Ot; D = 768; }
  const int k0 = b * 64;
  const int r = threadIdx.x >> 6;
  const int c = threadIdx.x & 63;
  for (int rr = r; rr < 64; rr += 4)
    sT[c][rr] = f2bf(W[(size_t)(k0 + rr) * 64 + c]);
  __syncthreads();
  const int n = threadIdx.x >> 2, seg = threadIdx.x & 3;
  uint4 a0 = *(const uint4*)&sT[n][seg * 16];
  uint4 a1 = *(const uint4*)&sT[n][seg * 16 + 8];
  *(uint4*)(O + (size_t)n * D + k0 + seg * 16)     = a0;
  *(uint4*)(O + (size_t)n * D + k0 + seg * 16 + 8) = a1;
}

// ---------------- K1: convert + rownorm + wtrans + fill_pref + deg_count + reg-sum ----
__global__ void conv_kernel2(const float* __restrict__ Fv, const float* __restrict__ Ft,
                             u16* __restrict__ Fbv, u16* __restrict__ Fbt,
                             u8* __restrict__ Fv8,
                             float* __restrict__ rnv, float* __restrict__ rnt,
                             const float* __restrict__ pv, const float* __restrict__ pt,
                             float* __restrict__ x2,
                             const float* __restrict__ Wv, const float* __restrict__ Wti,
                             u16* __restrict__ wtv, u16* __restrict__ wtt,
                             const int* __restrict__ eu, const int* __restrict__ ei,
                             float* __restrict__ deg,
                             const float* __restrict__ alpha, float* __restrict__ out) {
  int b = blockIdx.x;
  const int tid = threadIdx.x;
  float ss = 0.f;
  if (b < NPAD_C) {                                       // modality v, D=4096
    const int row = b;
    u16* dst  = Fbv + (size_t)row * 4096;
    u8*  dst8 = Fv8 + (size_t)row * 4096;
    if (row < NI_C) {
      const float* src = Fv + (size_t)row * 4096;
      for (int c = tid * 4; c < 4096; c += 1024) {
        float4 f = *(const float4*)(src + c);
        ss += f.x*f.x + f.y*f.y + f.z*f.z + f.w*f.w;
        ushort4 v; v.x = f2bf(f.x); v.y = f2bf(f.y); v.z = f2bf(f.z); v.w = f2bf(f.w);
        *(ushort4*)(dst + c) = v;
        int w8 = __builtin_amdgcn_cvt_pk_fp8_f32(f.x, f.y, 0, false);
        w8 = __builtin_amdgcn_cvt_pk_fp8_f32(f.z, f.w, w8, true);
        *(u32*)(dst8 + c) = (u32)w8;
      }
    } else {
      for (int c = tid * 4; c < 4096; c += 1024) {
        ushort4 v; v.x = v.y = v.z = v.w = 0;
        *(ushort4*)(dst + c) = v;
        *(u32*)(dst8 + c) = 0u;
      }
    }
    #pragma unroll
    for (int off = 32; off; off >>= 1) ss += __shfl_xor(ss, off);
    __shared__ float red[4];
    if ((tid & 63) == 0) red[tid >> 6] = ss;
    __syncthreads();
    if (tid == 0) {
      float s = red[0] + red[1] + red[2] + red[3];
      rnv[row] = (row < NI_C) ? rsqrtf(s) : 0.f;
    }
  } else if (b < 2 * NPAD_C) {                            // modality t, D=768
    const int row = b - NPAD_C;
    u16* dst = Fbt + (size_t)row * 768;
    if (row < NI_C) {
      const float* src = Ft + (size_t)row * 768;
      for (int c = tid * 4; c < 768; c += 1024) {
        float4 f = *(const float4*)(src + c);
        ss += f.x*f.x + f.y*f.y + f.z*f.z + f.w*f.w;
        ushort4 v; v.x = f2bf(f.x); v.y = f2bf(f.y); v.z = f2bf(f.z); v.w = f2bf(f.w);
        *(ushort4*)(dst + c) = v;
      }
    } else {
      for (int c = tid * 4; c < 768; c += 1024) {
        ushort4 v; v.x = v.y = v.z = v.w = 0;
        *(ushort4*)(dst + c) = v;
      }
    }
    #pragma unroll
    for (int off = 32; off; off >>= 1) ss += __shfl_xor(ss, off);
    __shared__ float red[4];
    if ((tid & 63) == 0) red[tid >> 6] = ss;
    __syncthreads();
    if (tid == 0) {
      float s = red[0] + red[1] + red[2] + red[3];
      rnt[row] = (row < NI_C) ? rsqrtf(s) : 0.f;
    }
  } else if (b < 2 * NPAD_C + 76) {                       // W transpose
    wtrans_body(b - 2 * NPAD_C, Wv, Wti, wtv, wtt);
  } else if (b < 2 * NPAD_C + 76 + 1250) {                // fill_pref: x2 user rows
    const int b2 = b - (2 * NPAD_C + 76);                 // [0,1250), 2048 elems each
    #pragma unroll
    for (int k = 0; k < 8; ++k) {
      int gid = b2 * 2048 + k * 256 + tid;
      int u = gid >> 7, c = gid & 127;
      x2[gid] = (c < 64) ? pv[(size_t)u * 64 + c] : pt[(size_t)u * 64 + (c - 64)];
    }
  } else if (b < 2 * NPAD_C + 76 + 1250 + NEB) {          // deg_count
    const int b2 = b - (2 * NPAD_C + 76 + 1250);
    int e = b2 * 256 + tid;
    if (e < NE_C) {
      atomicAdd(&deg[eu[e]], 1.f);
      atomicAdd(&deg[NU_C + ei[e]], 1.f);
    }
  } else {                                                // reg-sum (was loss blocks >=1024)
    const int b2 = b - (2 * NPAD_C + 76 + 1250 + NEB);    // [0,512)
    const size_t N1 = (size_t)NU_C * 64;
    float acc = 0.f;
    for (size_t i = (size_t)b2 * 256 + tid; i < 2 * N1; i += (size_t)512 * 256) {
      float x = (i < N1) ? pv[i] : pt[i - N1];
      acc += x * x;
    }
    #pragma unroll
    for (int off = 32; off; off >>= 1) acc += __shfl_xor(acc, off);
    __shared__ float red2[4];
    if ((tid & 63) == 0) red2[tid >> 6] = acc;
    __syncthreads();
    if (tid == 0) {
      float s = red2[0] + red2[1] + red2[2] + red2[3];
      atomicAdd(out, 0.5e-4f * s);
    }
    if (b2 == 0 && tid == 0) {
      float a = alpha[0];
      atomicAdd(out, 0.5e-4f * a * a);
    }
  }
}

// ---------------- fp8 symmetric fused Gram + top-10 body (v-graph, D=4096) ----------------
// r2/r4 structure: BK=128 single-buffer, 2 barriers per 128-K tile, seg-swizzled
// LDS, XCD-chunked pair map.
static __device__ __forceinline__ void simtopk_fp8_body(
    int bid, char* smem, const u8* __restrict__ F, const float* __restrict__ rn,
    u32* __restrict__ tv) {
  u8*    sB   = (u8*)smem;                   // I rows, cols [k0,k0+64)    [128][64B]
  u8*    sA   = (u8*)(smem + 16384);         // J rows, cols [k0,k0+64)    [128][64B]
  // region +8192 within each: cols [k0+64,k0+128), same layout
  float* T    = (float*)smem;                // transpose [128][66] = 33792 B (epilogue)
  int*   mk   = (int*)smem;                  // merge dump [128][40] (epilogue)
  int*   mk2  = (int*)(smem + 20480);        // repacked [128][10] (epilogue)
  float* sRNI = (float*)(smem + 33792);
  float* sRNJ = (float*)(smem + 34304);

  const int tid  = threadIdx.x;
  const int lane = tid & 63;
  const int wv   = tid >> 6;
  const int n15  = lane & 15;
  const int quad = lane >> 4;

  int I = 0, rem = xcd_swz(bid);
  { int rowlen = NCHUNK;
    while (rem >= rowlen) { rem -= rowlen; rowlen--; I++; } }
  const int J = I + rem;

  const int l2   = lane >> 2;
  const int lseg = (lane & 3) ^ (l2 & 3) ^ (lane >> 4);   // logical seg to fetch
  const u8* gB[2]; const u8* gA[2]; u8* lB[2]; u8* lA[2];
  #pragma unroll
  for (int rep = 0; rep < 2; ++rep) {
    int row = wv * 32 + rep * 16 + l2;
    gB[rep] = F + (size_t)(I * 128 + row) * 4096 + lseg * 16;
    gA[rep] = F + (size_t)(J * 128 + row) * 4096 + lseg * 16;
    lB[rep] = sB + (wv * 32 + rep * 16) * 64;
    lA[rep] = sA + (wv * 32 + rep * 16) * 64;
  }
  const int s_n = (n15 & 3) ^ (n15 >> 2);
  const int q2  = quad >> 1;
  const int q8  = (quad & 1) * 8;
  const int rB0 = (wv * 32 + n15) * 64;
  const int rB1 = rB0 + 16 * 64;

  f32x4 acc[2][8];
  #pragma unroll
  for (int tf = 0; tf < 2; ++tf)
    #pragma unroll
    for (int af = 0; af < 8; ++af) { f32x4 z = {0.f,0.f,0.f,0.f}; acc[tf][af] = z; }

  for (int k0 = 0; k0 < 4096; k0 += 128) {
    __syncthreads();
    gl_lds16(gB[0] + k0,      lB[0]);
    gl_lds16(gB[0] + k0 + 64, lB[0] + 8192);
    gl_lds16(gB[1] + k0,      lB[1]);
    gl_lds16(gB[1] + k0 + 64, lB[1] + 8192);
    gl_lds16(gA[0] + k0,      lA[0]);
    gl_lds16(gA[0] + k0 + 64, lA[0] + 8192);
    gl_lds16(gA[1] + k0,      lA[1]);
    gl_lds16(gA[1] + k0 + 64, lA[1] + 8192);
    if (k0 == 0) {
      if (tid < 128) sRNJ[tid] = rn[J * 128 + tid];
      else           sRNI[tid - 128] = rn[I * 128 + (tid - 128)];
    }
    __syncthreads();
    #pragma unroll
    for (int ksub = 0; ksub < 2; ++ksub) {
      const u8* bBase = sB + ksub * 8192;
      const u8* aBase = sA + ksub * 8192;
      #pragma unroll
      for (int ks = 0; ks < 2; ++ks) {
        const int sw = (((ks * 2 + q2) ^ s_n) << 4) + q8;
        long long b0 = *(const long long*)(bBase + rB0 + sw);
        long long b1 = *(const long long*)(bBase + rB1 + sw);
        #pragma unroll
        for (int af = 0; af < 8; ++af) {
          long long a = *(const long long*)(aBase + (af * 16 + n15) * 64 + sw);
          acc[0][af] = __builtin_amdgcn_mfma_f32_16x16x32_fp8_fp8(a, b0, acc[0][af], 0, 0, 0);
          acc[1][af] = __builtin_amdgcn_mfma_f32_16x16x32_fp8_fp8(a, b1, acc[1][af], 0, 0, 0);
        }
      }
    }
  }

  // ---- I-side: target rows in I, cands in J ----
  int bk[2][10];
  #pragma unroll
  for (int tf = 0; tf < 2; ++tf)
    #pragma unroll
    for (int j = 0; j < 10; ++j) bk[tf][j] = 0;

  #pragma unroll
  for (int af = 0; af < 8; ++af) {
    const float4 rn4 = *(const float4*)(sRNJ + af * 16 + quad * 4);
    const float rna[4] = {rn4.x, rn4.y, rn4.z, rn4.w};
    #pragma unroll
    for (int r = 0; r < 4; ++r) {
      const int ci = J * 128 + af * 16 + quad * 4 + r;
      #pragma unroll
      for (int tf = 0; tf < 2; ++tf) {
        float v = acc[tf][af][r] * rna[r];
        int key = (int)((__float_as_uint(v) & 0xFFFFE000u) | (u32)ci);
        if (ci < NI_C && key > bk[tf][9]) {
          bk[tf][9] = key;
          #pragma unroll
          for (int j = 9; j > 0; --j)
            if (bk[tf][j] > bk[tf][j-1]) { int t = bk[tf][j]; bk[tf][j] = bk[tf][j-1]; bk[tf][j-1] = t; }
        }
      }
    }
  }
  __syncthreads();
  #pragma unroll
  for (int tf = 0; tf < 2; ++tf) {
    int rl = wv * 32 + tf * 16 + n15;
    #pragma unroll
    for (int j = 0; j < 10; ++j) mk[rl * 40 + quad * 10 + j] = bk[tf][j];
  }
  __syncthreads();
  if (tid < 128) {                            // 4-way sorted-list tournament
    int* m = mk + tid * 40;
    int h0 = 0, h1 = 10, h2 = 20, h3 = 30;
    int v0 = m[0], v1 = m[10], v2 = m[20], v3 = m[30];
    #pragma unroll
    for (int s = 0; s < 10; ++s) {
      int m01 = v0 > v1 ? v0 : v1, m23 = v2 > v3 ? v2 : v3;
      int mx = m01 > m23 ? m01 : m23;
      mk2[tid * 10 + s] = mx;
      if      (mx == v0) { ++h0; v0 = (h0 < 10) ? m[h0] : (int)0x80000000; }
      else if (mx == v1) { ++h1; v1 = (h1 < 20) ? m[h1] : (int)0x80000000; }
      else if (mx == v2) { ++h2; v2 = (h2 < 30) ? m[h2] : (int)0x80000000; }
      else               { ++h3; v3 = (h3 < 40) ? m[h3] : (int)0x80000000; }
    }
  }
  __syncthreads();
  { u32* o = tv + ((size_t)J * NPAD_C + I * 128) * 10;
    for (int g = tid; g < 1280; g += 256) o[g] = (u32)mk2[g]; }

  if (I == J) return;

  // ---- J-side: target rows in J, cands in I (via transpose) ----
  int bj[2][10];
  #pragma unroll
  for (int s = 0; s < 2; ++s)
    #pragma unroll
    for (int j = 0; j < 10; ++j) bj[s][j] = 0;

  #pragma unroll
  for (int tf = 0; tf < 2; ++tf) {
    __syncthreads();
    #pragma unroll
    for (int af = 0; af < 8; ++af)
      #pragma unroll
      for (int r = 0; r < 4; ++r)
        T[(af * 16 + quad * 4 + r) * 66 + wv * 16 + n15] = acc[tf][af][r];
    __syncthreads();
    #pragma unroll
    for (int s = 0; s < 2; ++s) {
      const int c_own = wv * 32 + s * 16 + n15;
      #pragma unroll
      for (int j = 0; j < 16; ++j) {
        const int t  = quad * 32 + tf * 16 + j;
        const int t64 = quad * 16 + j;
        float v = T[c_own * 66 + t64] * sRNI[t];
        const int ti = I * 128 + t;
        int key = (int)((__float_as_uint(v) & 0xFFFFE000u) | (u32)ti);
        if (ti < NI_C && key > bj[s][9]) {
          bj[s][9] = key;
          #pragma unroll
          for (int q = 9; q > 0; --q)
            if (bj[s][q] > bj[s][q-1]) { int tt = bj[s][q]; bj[s][q] = bj[s][q-1]; bj[s][q-1] = tt; }
        }
      }
    }
  }
  __syncthreads();
  #pragma unroll
  for (int s = 0; s < 2; ++s) {
    int rl = wv * 32 + s * 16 + n15;
    #pragma unroll
    for (int j = 0; j < 10; ++j) mk[rl * 40 + quad * 10 + j] = bj[s][j];
  }
  __syncthreads();
  if (tid < 128) {
    int* m = mk + tid * 40;
    int h0 = 0, h1 = 10, h2 = 20, h3 = 30;
    int v0 = m[0], v1 = m[10], v2 = m[20], v3 = m[30];
    #pragma unroll
    for (int s = 0; s < 10; ++s) {
      int m01 = v0 > v1 ? v0 : v1, m23 = v2 > v3 ? v2 : v3;
      int mx = m01 > m23 ? m01 : m23;
      mk2[tid * 10 + s] = mx;
      if      (mx == v0) { ++h0; v0 = (h0 < 10) ? m[h0] : (int)0x80000000; }
      else if (mx == v1) { ++h1; v1 = (h1 < 20) ? m[h1] : (int)0x80000000; }
      else if (mx == v2) { ++h2; v2 = (h2 < 30) ? m[h2] : (int)0x80000000; }
      else               { ++h3; v3 = (h3 < 40) ? m[h3] : (int)0x80000000; }
    }
  }
  __syncthreads();
  { u32* o = tv + ((size_t)I * NPAD_C + J * 128) * 10;
    for (int g = tid; g < 1280; g += 256) o[g] = (u32)mk2[g]; }
}

// ---------------- bf16 symmetric fused Gram + top-10 body (t-graph, D=768) ----------------
static __device__ __forceinline__ void simtopk_bf16_body(
    int bid, char* smem, const u16* __restrict__ F, const float* __restrict__ rn,
    u32* __restrict__ tv) {
  u16*   sB   = (u16*)smem;
  u16*   sA   = (u16*)(smem + 16384);
  float* T    = (float*)smem;
  int*   mk   = (int*)smem;
  int*   mk2  = (int*)(smem + 20480);
  float* sRNI = (float*)(smem + 34816);
  float* sRNJ = (float*)(smem + 35328);

  const int tid  = threadIdx.x;
  const int lane = tid & 63;
  const int wv   = tid >> 6;
  const int n15  = lane & 15;
  const int quad = lane >> 4;

  int I = 0, rem = xcd_swz(bid);
  { int rowlen = NCHUNK;
    while (rem >= rowlen) { rem -= rowlen; rowlen--; I++; } }
  const int J = I + rem;

  const int l8  = lane >> 3;
  const int sgu = ((lane & 7) ^ l8) << 3;
  const u16* gB[4]; const u16* gA[4]; u16* lB[4]; u16* lA[4];
  #pragma unroll
  for (int rep = 0; rep < 4; ++rep) {
    int row = wv * 32 + rep * 8 + l8;
    gB[rep] = F + (size_t)(I * 128 + row) * 768 + sgu;
    gA[rep] = F + (size_t)(J * 128 + row) * 768 + sgu;
    lB[rep] = sB + wv * 2048 + rep * 512;
    lA[rep] = sA + wv * 2048 + rep * 512;
  }
  const int swu0 = ((quad    ) ^ (n15 & 7)) << 3;
  const int swu1 = ((quad + 4) ^ (n15 & 7)) << 3;
  const int rowB0 = (wv * 32 + n15) * 64;
  const int rowB1 = rowB0 + 16 * 64;

  f32x4 acc[2][8];
  #pragma unroll
  for (int tf = 0; tf < 2; ++tf)
    #pragma unroll
    for (int af = 0; af < 8; ++af) { f32x4 z = {0.f,0.f,0.f,0.f}; acc[tf][af] = z; }

  for (int k0 = 0; k0 < 768; k0 += 64) {
    __syncthreads();
    #pragma unroll
    for (int rep = 0; rep < 4; ++rep) gl_lds16(gB[rep] + k0, lB[rep]);
    #pragma unroll
    for (int rep = 0; rep < 4; ++rep) gl_lds16(gA[rep] + k0, lA[rep]);
    if (k0 == 0) {
      if (tid < 128) sRNJ[tid] = rn[J * 128 + tid];
      else           sRNI[tid - 128] = rn[I * 128 + (tid - 128)];
    }
    __syncthreads();
    #pragma unroll
    for (int ks = 0; ks < 2; ++ks) {
      const int swu = ks ? swu1 : swu0;
      bf16x8 b0 = *(const bf16x8*)(sB + rowB0 + swu);
      bf16x8 b1 = *(const bf16x8*)(sB + rowB1 + swu);
      #pragma unroll
      for (int af = 0; af < 8; ++af) {
        bf16x8 a = *(const bf16x8*)(sA + (af * 16 + n15) * 64 + swu);
        acc[0][af] = __builtin_amdgcn_mfma_f32_16x16x32_bf16(a, b0, acc[0][af], 0, 0, 0);
        acc[1][af] = __builtin_amdgcn_mfma_f32_16x16x32_bf16(a, b1, acc[1][af], 0, 0, 0);
      }
    }
  }

  int bk[2][10];
  #pragma unroll
  for (int tf = 0; tf < 2; ++tf)
    #pragma unroll
    for (int j = 0; j < 10; ++j) bk[tf][j] = 0;

  #pragma unroll
  for (int af = 0; af < 8; ++af) {
    const float4 rn4 = *(const float4*)(sRNJ + af * 16 + quad * 4);
    const float rna[4] = {rn4.x, rn4.y, rn4.z, rn4.w};
    #pragma unroll
    for (int r = 0; r < 4; ++r) {
      const int ci = J * 128 + af * 16 + quad * 4 + r;
      #pragma unroll
      for (int tf = 0; tf < 2; ++tf) {
        float v = acc[tf][af][r] * rna[r];
        int key = (int)((__float_as_uint(v) & 0xFFFFE000u) | (u32)ci);
        if (ci < NI_C && key > bk[tf][9]) {
          bk[tf][9] = key;
          #pragma unroll
          for (int j = 9; j > 0; --j)
            if (bk[tf][j] > bk[tf][j-1]) { int t = bk[tf][j]; bk[tf][j] = bk[tf][j-1]; bk[tf][j-1] = t; }
        }
      }
    }
  }
  __syncthreads();
  #pragma unroll
  for (int tf = 0; tf < 2; ++tf) {
    int rl = wv * 32 + tf * 16 + n15;
    #pragma unroll
    for (int j = 0; j < 10; ++j) mk[rl * 40 + quad * 10 + j] = bk[tf][j];
  }
  __syncthreads();
  if (tid < 128) {
    int* m = mk + tid * 40;
    int h0 = 0, h1 = 10, h2 = 20, h3 = 30;
    int v0 = m[0], v1 = m[10], v2 = m[20], v3 = m[30];
    #pragma unroll
    for (int s = 0; s < 10; ++s) {
      int m01 = v0 > v1 ? v0 : v1, m23 = v2 > v3 ? v2 : v3;
      int mx = m01 > m23 ? m01 : m23;
      mk2[tid * 10 + s] = mx;
      if      (mx == v0) { ++h0; v0 = (h0 < 10) ? m[h0] : (int)0x80000000; }
      else if (mx == v1) { ++h1; v1 = (h1 < 20) ? m[h1] : (int)0x80000000; }
      else if (mx == v2) { ++h2; v2 = (h2 < 30) ? m[h2] : (int)0x80000000; }
      else               { ++h3; v3 = (h3 < 40) ? m[h3] : (int)0x80000000; }
    }
  }
  __syncthreads();
  { u32* o = tv + ((size_t)J * NPAD_C + I * 128) * 10;
    for (int g = tid; g < 1280; g += 256) o[g] = (u32)mk2[g]; }

  if (I == J) return;

  int bj[2][10];
  #pragma unroll
  for (int s = 0; s < 2; ++s)
    #pragma unroll
    for (int j = 0; j < 10; ++j) bj[s][j] = 0;

  #pragma unroll
  for (int tf = 0; tf < 2; ++tf) {
    __syncthreads();
    #pragma unroll
    for (int af = 0; af < 8; ++af)
      #pragma unroll
      for (int r = 0; r < 4; ++r)
        T[(af * 16 + quad * 4 + r) * 66 + wv * 16 + n15] = acc[tf][af][r];
    __syncthreads();
    #pragma unroll
    for (int s = 0; s < 2; ++s) {
      const int c_own = wv * 32 + s * 16 + n15;
      #pragma unroll
      for (int j = 0; j < 16; ++j) {
        const int t  = quad * 32 + tf * 16 + j;
        const int t64 = quad * 16 + j;
        float v = T[c_own * 66 + t64] * sRNI[t];
        const int ti = I * 128 + t;
        int key = (int)((__float_as_uint(v) & 0xFFFFE000u) | (u32)ti);
        if (ti < NI_C && key > bj[s][9]) {
          bj[s][9] = key;
          #pragma unroll
          for (int q = 9; q > 0; --q)
            if (bj[s][q] > bj[s][q-1]) { int tt = bj[s][q]; bj[s][q] = bj[s][q-1]; bj[s][q-1] = tt; }
        }
      }
    }
  }
  __syncthreads();
  #pragma unroll
  for (int s = 0; s < 2; ++s) {
    int rl = wv * 32 + s * 16 + n15;
    #pragma unroll
    for (int j = 0; j < 10; ++j) mk[rl * 40 + quad * 10 + j] = bj[s][j];
  }
  __syncthreads();
  if (tid < 128) {
    int* m = mk + tid * 40;
    int h0 = 0, h1 = 10, h2 = 20, h3 = 30;
    int v0 = m[0], v1 = m[10], v2 = m[20], v3 = m[30];
    #pragma unroll
    for (int s = 0; s < 10; ++s) {
      int m01 = v0 > v1 ? v0 : v1, m23 = v2 > v3 ? v2 : v3;
      int mx = m01 > m23 ? m01 : m23;
      mk2[tid * 10 + s] = mx;
      if      (mx == v0) { ++h0; v0 = (h0 < 10) ? m[h0] : (int)0x80000000; }
      else if (mx == v1) { ++h1; v1 = (h1 < 20) ? m[h1] : (int)0x80000000; }
      else if (mx == v2) { ++h2; v2 = (h2 < 30) ? m[h2] : (int)0x80000000; }
      else               { ++h3; v3 = (h3 < 40) ? m[h3] : (int)0x80000000; }
    }
  }
  __syncthreads();
  { u32* o = tv + ((size_t)I * NPAD_C + J * 128) * 10;
    for (int g = tid; g < 1280; g += 256) o[g] = (u32)mk2[g]; }
}

// ---------------- merge: 63 sorted lists x 10 -> top-10, 4 rows per 256-thr block ----
static __device__ __forceinline__ void merge4_body(int mb, int* fkbase,
                                                   const u32* __restrict__ tv,
                                                   int* __restrict__ idx) {
  const int w    = threadIdx.x >> 6;
  const int lane = threadIdx.x & 63;
  const int row  = mb * 4 + w;
  int* fk = fkbase + w * 640;
  for (int g = lane; g < 630; g += 64)
    fk[g] = (int)tv[((size_t)(g / 10) * NPAD_C + row) * 10 + (g % 10)];
  if (lane < 10) fk[630 + lane] = (int)0x80000000;
  __syncthreads();
  int v[10];
  #pragma unroll
  for (int j = 0; j < 10; ++j) v[j] = fk[lane + j * 64];
  #pragma unroll 1
  for (int s = 0; s < 10; ++s) {
    int loc = v[0];
    #pragma unroll
    for (int j = 1; j < 10; ++j) loc = v[j] > loc ? v[j] : loc;
    #pragma unroll
    for (int off = 32; off; off >>= 1) {
      int o = __shfl_xor(loc, off); loc = o > loc ? o : loc;
    }
    if (lane == 0) idx[row * 10 + s] = loc & 0x1FFF;
    #pragma unroll
    for (int j = 0; j < 10; ++j) if (v[j] == loc) v[j] = (int)0x80000000;
  }
}

// ---------------- feat @ W via bf16 MFMA body, M=64 tiles ----------------
template<int D>
static __device__ __forceinline__ void gemm_xw_body(
    int bid, char* smem, const u16* __restrict__ F, const u16* __restrict__ Wt,
    float* __restrict__ x2, int modeoff) {
  u16* sF = (u16*)smem;                      // 8192 B
  const int tid  = threadIdx.x;
  const int lane = tid & 63;
  const int wv   = tid >> 6;
  const int n15  = lane & 15;
  const int quad = lane >> 4;
  const int l8   = lane >> 3;
  const int sgu  = ((lane & 7) ^ l8) << 3;
  const u16* gF[2]; u16* lF[2];
  #pragma unroll
  for (int rep = 0; rep < 2; ++rep) {
    int row = rep * 32 + wv * 8 + l8;
    gF[rep] = F + (size_t)(bid * 64 + row) * D + sgu;
    lF[rep] = sF + (rep * 32 + wv * 8) * 64;
  }
  const int swu0 = ((quad    ) ^ (n15 & 7)) << 3;
  const int swu1 = ((quad + 4) ^ (n15 & 7)) << 3;

  f32x4 acc[4];
  #pragma unroll
  for (int nf = 0; nf < 4; ++nf) { f32x4 z = {0.f,0.f,0.f,0.f}; acc[nf] = z; }

  for (int k0 = 0; k0 < D; k0 += 64) {
    __syncthreads();
    gl_lds16(gF[0] + k0, lF[0]);
    gl_lds16(gF[1] + k0, lF[1]);
    __syncthreads();
    #pragma unroll
    for (int ks = 0; ks < 2; ++ks) {
      const int swu = ks ? swu1 : swu0;
      bf16x8 a = *(const bf16x8*)(sF + (wv * 16 + n15) * 64 + swu);
      #pragma unroll
      for (int nf = 0; nf < 4; ++nf) {
        bf16x8 b = *(const bf16x8*)(Wt + (size_t)(nf * 16 + n15) * D + k0 + ks * 32 + quad * 8);
        acc[nf] = __builtin_amdgcn_mfma_f32_16x16x32_bf16(a, b, acc[nf], 0, 0, 0);
      }
    }
  }
  #pragma unroll
  for (int nf = 0; nf < 4; ++nf)
    #pragma unroll
    for (int r = 0; r < 4; ++r) {
      int row = bid * 64 + wv * 16 + quad * 4 + r;
      if (row < NI_C)
        x2[(size_t)(NU_C + row) * 128 + modeoff + nf * 16 + n15] = acc[nf][r];
    }
}

// ---------------- gather bodies ----------------
static __device__ __forceinline__ void gather2_body(
    int bid, const int* __restrict__ row_start, const int* __restrict__ esrc,
    const float* __restrict__ ew, const float* __restrict__ x2, float* __restrict__ h1) {
  const int node = bid * 2 + (threadIdx.x >> 7);
  const int ch   = threadIdx.x & 127;
  if (node >= NTOT_C) return;
  const int b = row_start[node], e = row_start[node + 1];
  float acc = 0.f;
  for (int i = b; i < e; ++i)
    acc += ew[i] * x2[(size_t)esrc[i] * 128 + ch];
  h1[(size_t)node * 128 + ch] = acc;
}

static __device__ __forceinline__ void gather_comb2_body(
    int bid, const int* __restrict__ row_start, const int* __restrict__ esrc,
    const float* __restrict__ ew, const float* __restrict__ x2,
    const float* __restrict__ h1, const float* __restrict__ alpha,
    float* __restrict__ uf, float* __restrict__ ifb) {
  const int node = bid * 2 + (threadIdx.x >> 7);
  const int ch   = threadIdx.x & 127;
  if (node >= NTOT_C) return;
  const int b = row_start[node], e = row_start[node + 1];
  float acc = 0.f;
  for (int i = b; i < e; ++i)
    acc += ew[i] * h1[(size_t)esrc[i] * 128 + ch];
  float val = x2[(size_t)node * 128 + ch] + h1[(size_t)node * 128 + ch] + acc;
  if (node < NU_C) {
    float av = 1.f / (1.f + expf(-alpha[0]));
    float coef = (ch < 64) ? av : (1.f - av);
    uf[(size_t)node * 128 + ch] = coef * val;
  } else {
    ifb[(size_t)(node - NU_C) * 128 + ch] = val;
  }
}

// ---------------- place body (CSR fill) ----------------
static __device__ __forceinline__ void place_body(
    int bid, const int* __restrict__ eu, const int* __restrict__ ei,
    const float* __restrict__ dinv, int* __restrict__ cursor,
    int* __restrict__ esrc, float* __restrict__ ew) {
  int e = bid * 256 + threadIdx.x;
  if (e >= NE_C) return;
  int u = eu[e], v = NU_C + ei[e];
  float w = dinv[u] * dinv[v];
  int p1 = atomicAdd(&cursor[v], 1);  esrc[p1] = u; ew[p1] = w;
  int p2 = atomicAdd(&cursor[u], 1);  esrc[p2] = v; ew[p2] = w;
}

// ---------------- fused launches (LPT ordering: long/latency-bound blocks FIRST) ----
// F1: gemm_xw<4096> (125) ++ gemm_xw<768> (125) ++ simtopk_fp8 (2016, pole) ++
//     place (782 trivial blocks, slot into the drain tail; feeds F2 only).
__launch_bounds__(256)
__global__ void fusedA_kernel(const u8* __restrict__ F8, const float* __restrict__ rnv,
                              u32* __restrict__ tv,
                              const u16* __restrict__ Fvb, const u16* __restrict__ Wtv,
                              const u16* __restrict__ Ftb, const u16* __restrict__ Wtt,
                              float* __restrict__ x2,
                              const int* __restrict__ eu, const int* __restrict__ ei,
                              const float* __restrict__ dinv, int* __restrict__ cursor,
                              int* __restrict__ esrc, float* __restrict__ ew) {
  __shared__ __align__(16) char smem[34816];
  int b = blockIdx.x;
  if (b < 125) { gemm_xw_body<4096>(b, smem, Fvb, Wtv, x2, 0); return; }
  b -= 125;
  if (b < 125) { gemm_xw_body<768>(b, smem, Ftb, Wtt, x2, 64); return; }
  b -= 125;
  if (b < NPAIR) { simtopk_fp8_body(b, smem, F8, rnv, tv); return; }
  place_body(b - NPAIR, eu, ei, dinv, cursor, esrc, ew);
}

// F2: simtopk_t (2016, pole, first; tvb2 = dead fvbf) ++ merge_v (2000) ++ gather2 (14000).
__launch_bounds__(256)
__global__ void fusedB_kernel(const u16* __restrict__ Ftb, const float* __restrict__ rnt,
                              u32* __restrict__ tv2,
                              const u32* __restrict__ tv, int* __restrict__ idx,
                              const int* __restrict__ row_start, const int* __restrict__ esrc,
                              const float* __restrict__ ew, const float* __restrict__ x2,
                              float* __restrict__ h1) {
  __shared__ __align__(16) char smem[40960];
  int b = blockIdx.x;
  if (b < NPAIR) { simtopk_bf16_body(b, smem, Ftb, rnt, tv2); return; }
  b -= NPAIR;
  if (b < 2000) { merge4_body(b, (int*)smem, tv, idx); return; }
  gather2_body(b - 2000, row_start, esrc, ew, x2, h1);
}

// F3: merge_t (2000, first; consumes tvb2 from F2) ++ gather_comb2 (14000).
// Safe: tvb (pC) was consumed by merge_v in F2, so u_f/i_f writes over pC are race-free.
__launch_bounds__(256)
__global__ void fusedC_kernel(const u32* __restrict__ tv2, int* __restrict__ idxt,
                              const int* __restrict__ row_start, const int* __restrict__ esrc,
                              const float* __restrict__ ew, const float* __restrict__ x2,
                              const float* __restrict__ h1, const float* __restrict__ alpha,
                              float* __restrict__ uf, float* __restrict__ ifb) {
  __shared__ __align__(16) int fk[4 * 640];
  int b = blockIdx.x;
  if (b < 2000) { merge4_body(b, fk, tv2, idxt); return; }
  gather_comb2_body(b - 2000, row_start, esrc, ew, x2, h1, alpha, uf, ifb);
}

// ---------------- scan (CSR prefix) ----------------
__global__ void scan_kernel(float* __restrict__ deg, int* __restrict__ row_start,
                            int* __restrict__ cursor) {
  __shared__ int part[1024];
  const int tid = threadIdx.x;
  const int base = tid * 28;
  float dl[28];
  int local[28];
  int s = 0;
  #pragma unroll
  for (int j = 0; j < 28; ++j) {
    int n = base + j;
    float df = (n < NTOT_C) ? deg[n] : 0.f;
    dl[j] = df;
    local[j] = s; s += (int)df;
  }
  part[tid] = s;
  __syncthreads();
  for (int off = 1; off < 1024; off <<= 1) {
    int v = (tid >= off) ? part[tid - off] : 0;
    __syncthreads();
    part[tid] += v;
    __syncthreads();
  }
  int pre = (tid > 0) ? part[tid - 1] : 0;
  #pragma unroll
  for (int j = 0; j < 28; ++j) {
    int n = base + j;
    if (n < NTOT_C) {
      row_start[n] = pre + local[j];
      cursor[n]    = pre + local[j];
      deg[n]       = rsqrtf(fmaxf(dl[j], 1.f));
    }
  }
  if (tid == 1023) row_start[NTOT_C] = part[1023];
}

// ---------------- fused zu/zi + bpr loss: one wave per batch element ----------------
// Computes z_u[u], z_i[p], z_i[n] on the fly (identical expressions/order to the
// old zuzi_kernel) and feeds the original dot+shfl+atomic BPR reduction. The
// reg-term blocks moved into K1.
__launch_bounds__(256)
__global__ void zuloss_kernel(const float* __restrict__ uf, const float* __restrict__ w,
                              const int* __restrict__ nb, const float* __restrict__ ifb,
                              const int* __restrict__ iv, const int* __restrict__ it,
                              const int* __restrict__ uid, const int* __restrict__ pid,
                              const int* __restrict__ nid, float* __restrict__ out) {
  const int wv = threadIdx.x >> 6, lane = threadIdx.x & 63;
  const int b = blockIdx.x * 4 + wv;
  const int u = uid[b], p = pid[b], n = nid[b];
  const int c = lane * 2;

  // softmax over the 20 user-attn weights (all lanes redundantly; broadcast loads)
  float e[20]; float m = -1e30f;
  #pragma unroll
  for (int k = 0; k < 20; ++k) { e[k] = w[u * 20 + k]; m = fmaxf(m, e[k]); }
  float ssum = 0.f;
  #pragma unroll
  for (int k = 0; k < 20; ++k) { e[k] = expf(e[k] - m); ssum += e[k]; }
  float inv = 1.f / ssum;

  // z_u = uf[u] + sum_k e[k]*inv*uf[nb[u,k]]   (same accumulation order as zuzi)
  float2 zu = *(const float2*)(uf + (size_t)u * 128 + c);
  float ax = 0.f, ay = 0.f;
  #pragma unroll
  for (int k = 0; k < 20; ++k) {
    int j = nb[u * 20 + k];
    float2 t = *(const float2*)(uf + (size_t)j * 128 + c);
    ax += e[k] * inv * t.x;
    ay += e[k] * inv * t.y;
  }
  zu.x += ax; zu.y += ay;

  // z_i = ifb[i] + 0.01*sum(iv rows) + 0.09*sum(it rows)   (same order as zuzi)
  float2 zp, zn;
  #pragma unroll
  for (int side = 0; side < 2; ++side) {
    const int i = side ? n : p;
    float svx = 0.f, svy = 0.f, stx = 0.f, sty = 0.f;
    #pragma unroll
    for (int k = 0; k < 10; ++k) {
      float2 t = *(const float2*)(ifb + (size_t)iv[i * 10 + k] * 128 + c);
      svx += t.x; svy += t.y;
    }
    #pragma unroll
    for (int k = 0; k < 10; ++k) {
      float2 t = *(const float2*)(ifb + (size_t)it[i * 10 + k] * 128 + c);
      stx += t.x; sty += t.y;
    }
    float2 base = *(const float2*)(ifb + (size_t)i * 128 + c);
    float2 r;
    r.x = base.x + 0.01f * svx + 0.09f * stx;
    r.y = base.y + 0.01f * svy + 0.09f * sty;
    if (side) zn = r; else zp = r;
  }

  float d = zu.x * (zp.x - zn.x) + zu.y * (zp.y - zn.y);
  #pragma unroll
  for (int off = 32; off; off >>= 1) d += __shfl_xor(d, off);
  if (lane == 0) {
    float xv = -d;
    float sp = fmaxf(xv, 0.f) + log1pf(expf(-fabsf(xv)));
    atomicAdd(out, sp * (1.f / (float)B_C));
  }
}

// ---------------- launcher ----------------
extern "C" void kernel_launch(void* const* d_in, const int* in_sizes, int n_in,
                              void* d_out, int out_size, void* d_ws, size_t ws_size,
                              hipStream_t stream) {
  const float* feat_v = (const float*)d_in[0];
  const float* feat_t = (const float*)d_in[1];
  const float* pref_v = (const float*)d_in[2];
  const float* pref_t = (const float*)d_in[3];
  const float* W_v    = (const float*)d_in[4];
  const float* W_t    = (const float*)d_in[5];
  const float* alpha  = (const float*)d_in[6];
  const float* unw    = (const float*)d_in[7];
  const int* eu       = (const int*)d_in[8];
  const int* ei       = (const int*)d_in[9];
  const int* u_ids    = (const int*)d_in[10];
  const int* pos_ids  = (const int*)d_in[11];
  const int* neg_ids  = (const int*)d_in[12];
  const int* user_nb  = (const int*)d_in[13];
  float* out = (float*)d_out;
  char* ws = (char*)d_ws;

  size_t off = 0;
  auto alloc = [&](size_t bytes) { char* p = ws + off; off += (bytes + 255) & ~(size_t)255; return p; };
  u16*   fvbf  = (u16*)alloc((size_t)NPAD_C * 4096 * 2);   // 66.06 MB (gemm; tvb2 after F1)
  u8*    fv8   = (u8*)alloc((size_t)NPAD_C * 4096);        // 33.03 MB (fp8 simtopk)
  u16*   ftbf  = (u16*)alloc((size_t)NPAD_C * 768 * 2);    // 12.39 MB
  u16*   wtv   = (u16*)alloc((size_t)64 * 4096 * 2);
  u16*   wtt   = (u16*)alloc((size_t)64 * 768 * 2);
  float* rn_v  = (float*)alloc(NPAD_C * 4);
  float* rn_t  = (float*)alloc(NPAD_C * 4);
  int*   idx_v = (int*)alloc(NI_C * 10 * 4);
  int*   idx_t = (int*)alloc(NI_C * 10 * 4);
  float* dinv  = (float*)alloc(NTOT_C * 4);
  int*   rowst = (int*)alloc((NTOT_C + 1) * 4);
  int*   curs  = (int*)alloc(NTOT_C * 4);
  int*   esrc  = (int*)alloc((size_t)2 * NE_C * 4);
  float* ew    = (float*)alloc((size_t)2 * NE_C * 4);
  float* x2    = (float*)alloc((size_t)NTOT_C * 128 * 4);  // 14.3 MB
  float* h1    = (float*)alloc((size_t)NTOT_C * 128 * 4);  // 14.3 MB
  char*  pC    = alloc((size_t)(NU_C + NI_C) * 128 * 4);   // 14.3 MB
  u32*   tvb   = (u32*)pC;                                  // 20.3 MB? no: v-graph tv needs 20.3MB
  // NOTE: tvb needs 63*NPAD_C*10*4 = 20.3 MB; pC is 14.3 MB -> extend:
  char*  pC2   = alloc((size_t)6 * 1024 * 1024 + 256);      // pad pC region to >20.3 MB total
  (void)pC2;
  u32*   tvb2  = (u32*)fvbf;                                // t-graph tv: fvbf dead after F1 gemm
  float* u_f   = (float*)pC;
  float* i_f   = (float*)(pC + (size_t)NU_C * 128 * 4);

  hipMemsetAsync(out, 0, sizeof(float), stream);
  hipMemsetAsync(dinv, 0, NTOT_C * 4, stream);

  // --- K1: conv + wtrans + fill_pref + deg_count + reg-sum ---
  conv_kernel2<<<2 * NPAD_C + 76 + 1250 + NEB + 512, 256, 0, stream>>>(
      feat_v, feat_t, fvbf, ftbf, fv8, rn_v, rn_t, pref_v, pref_t, x2,
      W_v, W_t, wtv, wtt, eu, ei, dinv, alpha, out);

  // --- scan (single block; rowst/curs + dinv finalize) ---
  scan_kernel<<<1, 1024, 0, stream>>>(dinv, rowst, curs);

  // --- F1: gemm_xw x2 ++ simtopk_fp8 ++ place ---
  fusedA_kernel<<<250 + NPAIR + NEB, 256, 0, stream>>>(
      fv8, rn_v, tvb, fvbf, wtv, ftbf, wtt, x2, eu, ei, dinv, curs, esrc, ew);

  // --- F2: simtopk_t (tv -> tvb2) ++ merge_v ++ gather2 ---
  fusedB_kernel<<<NPAIR + 2000 + 14000, 256, 0, stream>>>(
      ftbf, rn_t, tvb2, tvb, idx_v, rowst, esrc, ew, x2, h1);

  // --- F3: merge_t ++ gather_comb2 ---
  fusedC_kernel<<<2000 + 14000, 256, 0, stream>>>(
      tvb2, idx_t, rowst, esrc, ew, x2, h1, alpha, u_f, i_f);

  // --- fused zu/zi + loss ---
  zuloss_kernel<<<1024, 256, 0, stream>>>(u_f, unw, user_nb, i_f, idx_v, idx_t,
                                          u_ids, pos_ids, neg_ids, out);
}

// Round 9
// 906.874 us; speedup vs baseline: 1.2075x; 1.0873x over previous
//
#include <hip/hip_runtime.h>
#include <cstdint>
#include <cstddef>

// ---------------- problem constants ----------------
#define NU_C   20000
#define NI_C   8000
#define NTOT_C 28000          // NU+NI
#define NE_C   200000
#define B_C    4096
#define NPAD_C 8064           // NI padded to 63*128 rows
#define NCHUNK 63
#define NPAIR  2016           // 63*64/2 upper-triangle chunk pairs
#define NEB    782            // (NE_C+255)/256

typedef unsigned short u16;
typedef unsigned int   u32;
typedef unsigned char  u8;
typedef __bf16 bf16x8 __attribute__((ext_vector_type(8)));
typedef float  f32x4  __attribute__((ext_vector_type(4)));

static __device__ __forceinline__ u16 f2bf(float f) {
  u32 u = __float_as_uint(f);
  return (u16)((u + 0x7fffu + ((u >> 16) & 1u)) >> 16);   // RNE
}

// async global->LDS, 16B per lane; LDS dest is wave-uniform base + lane*16
static __device__ __forceinline__ void gl_lds16(const void* g, void* l) {
  __builtin_amdgcn_global_load_lds(
      (const __attribute__((address_space(1))) void*)g,
      (__attribute__((address_space(3))) void*)l, 16, 0, 0);
}

// XCD-chunked block swizzle (T1). simtopk bodies receive a LOGICAL id in
// [0,NPAIR); the fused grids apply a uniform physical offset, which preserves
// the one-XCD-per-residue-class contiguity.
static __device__ __forceinline__ int xcd_swz(int b) {
  return (b & 7) * (NPAIR / 8) + (b >> 3);
}

// ---------------- W transpose body (64x64 fp32 tile -> bf16 transposed) ----------------
static __device__ __forceinline__ void wtrans_body(int b, const float* __restrict__ Wv,
                                                   const float* __restrict__ Wti,
                                                   u16* __restrict__ Ov, u16* __restrict__ Ot) {
  __shared__ u16 sT[64][72];
  const float* W; u16* O; int D;
  if (b < 64) { W = Wv; O = Ov; D = 4096; }
  else        { b -= 64; W = Wti; O = Ot; D = 768; }
  const int k0 = b * 64;
  const int r = threadIdx.x >> 6;
  const int c = threadIdx.x & 63;
  for (int rr = r; rr < 64; rr += 4)
    sT[c][rr] = f2bf(W[(size_t)(k0 + rr) * 64 + c]);
  __syncthreads();
  const int n = threadIdx.x >> 2, seg = threadIdx.x & 3;
  uint4 a0 = *(const uint4*)&sT[n][seg * 16];
  uint4 a1 = *(const uint4*)&sT[n][seg * 16 + 8];
  *(uint4*)(O + (size_t)n * D + k0 + seg * 16)     = a0;
  *(uint4*)(O + (size_t)n * D + k0 + seg * 16 + 8) = a1;
}

// ---------------- K1: convert + rownorm + wtrans + fill_pref + deg_count + reg-sum ----
__global__ void conv_kernel2(const float* __restrict__ Fv, const float* __restrict__ Ft,
                             u16* __restrict__ Fbv, u16* __restrict__ Fbt,
                             u8* __restrict__ Fv8,
                             float* __restrict__ rnv, float* __restrict__ rnt,
                             const float* __restrict__ pv, const float* __restrict__ pt,
                             float* __restrict__ x2,
                             const float* __restrict__ Wv, const float* __restrict__ Wti,
                             u16* __restrict__ wtv, u16* __restrict__ wtt,
                             const int* __restrict__ eu, const int* __restrict__ ei,
                             float* __restrict__ deg,
                             const float* __restrict__ alpha, float* __restrict__ out) {
  int b = blockIdx.x;
  const int tid = threadIdx.x;
  float ss = 0.f;
  if (b < NPAD_C) {                                       // modality v, D=4096
    const int row = b;
    u16* dst  = Fbv + (size_t)row * 4096;
    u8*  dst8 = Fv8 + (size_t)row * 4096;
    if (row < NI_C) {
      const float* src = Fv + (size_t)row * 4096;
      for (int c = tid * 4; c < 4096; c += 1024) {
        float4 f = *(const float4*)(src + c);
        ss += f.x*f.x + f.y*f.y + f.z*f.z + f.w*f.w;
        ushort4 v; v.x = f2bf(f.x); v.y = f2bf(f.y); v.z = f2bf(f.z); v.w = f2bf(f.w);
        *(ushort4*)(dst + c) = v;
        int w8 = __builtin_amdgcn_cvt_pk_fp8_f32(f.x, f.y, 0, false);
        w8 = __builtin_amdgcn_cvt_pk_fp8_f32(f.z, f.w, w8, true);
        *(u32*)(dst8 + c) = (u32)w8;
      }
    } else {
      for (int c = tid * 4; c < 4096; c += 1024) {
        ushort4 v; v.x = v.y = v.z = v.w = 0;
        *(ushort4*)(dst + c) = v;
        *(u32*)(dst8 + c) = 0u;
      }
    }
    #pragma unroll
    for (int off = 32; off; off >>= 1) ss += __shfl_xor(ss, off);
    __shared__ float red[4];
    if ((tid & 63) == 0) red[tid >> 6] = ss;
    __syncthreads();
    if (tid == 0) {
      float s = red[0] + red[1] + red[2] + red[3];
      rnv[row] = (row < NI_C) ? rsqrtf(s) : 0.f;
    }
  } else if (b < 2 * NPAD_C) {                            // modality t, D=768
    const int row = b - NPAD_C;
    u16* dst = Fbt + (size_t)row * 768;
    if (row < NI_C) {
      const float* src = Ft + (size_t)row * 768;
      for (int c = tid * 4; c < 768; c += 1024) {
        float4 f = *(const float4*)(src + c);
        ss += f.x*f.x + f.y*f.y + f.z*f.z + f.w*f.w;
        ushort4 v; v.x = f2bf(f.x); v.y = f2bf(f.y); v.z = f2bf(f.z); v.w = f2bf(f.w);
        *(ushort4*)(dst + c) = v;
      }
    } else {
      for (int c = tid * 4; c < 768; c += 1024) {
        ushort4 v; v.x = v.y = v.z = v.w = 0;
        *(ushort4*)(dst + c) = v;
      }
    }
    #pragma unroll
    for (int off = 32; off; off >>= 1) ss += __shfl_xor(ss, off);
    __shared__ float red[4];
    if ((tid & 63) == 0) red[tid >> 6] = ss;
    __syncthreads();
    if (tid == 0) {
      float s = red[0] + red[1] + red[2] + red[3];
      rnt[row] = (row < NI_C) ? rsqrtf(s) : 0.f;
    }
  } else if (b < 2 * NPAD_C + 76) {                       // W transpose
    wtrans_body(b - 2 * NPAD_C, Wv, Wti, wtv, wtt);
  } else if (b < 2 * NPAD_C + 76 + 1250) {                // fill_pref: x2 user rows
    const int b2 = b - (2 * NPAD_C + 76);                 // [0,1250), 2048 elems each
    #pragma unroll
    for (int k = 0; k < 8; ++k) {
      int gid = b2 * 2048 + k * 256 + tid;
      int u = gid >> 7, c = gid & 127;
      x2[gid] = (c < 64) ? pv[(size_t)u * 64 + c] : pt[(size_t)u * 64 + (c - 64)];
    }
  } else if (b < 2 * NPAD_C + 76 + 1250 + NEB) {          // deg_count
    const int b2 = b - (2 * NPAD_C + 76 + 1250);
    int e = b2 * 256 + tid;
    if (e < NE_C) {
      atomicAdd(&deg[eu[e]], 1.f);
      atomicAdd(&deg[NU_C + ei[e]], 1.f);
    }
  } else {                                                // reg-sum (loss reg term)
    const int b2 = b - (2 * NPAD_C + 76 + 1250 + NEB);    // [0,512)
    const size_t N1 = (size_t)NU_C * 64;
    float acc = 0.f;
    for (size_t i = (size_t)b2 * 256 + tid; i < 2 * N1; i += (size_t)512 * 256) {
      float x = (i < N1) ? pv[i] : pt[i - N1];
      acc += x * x;
    }
    #pragma unroll
    for (int off = 32; off; off >>= 1) acc += __shfl_xor(acc, off);
    __shared__ float red2[4];
    if ((tid & 63) == 0) red2[tid >> 6] = acc;
    __syncthreads();
    if (tid == 0) {
      float s = red2[0] + red2[1] + red2[2] + red2[3];
      atomicAdd(out, 0.5e-4f * s);
    }
    if (b2 == 0 && tid == 0) {
      float a = alpha[0];
      atomicAdd(out, 0.5e-4f * a * a);
    }
  }
}

// ---------------- fp8 symmetric fused Gram + top-10 body (v-graph, D=4096) ----------------
// r2/r4 structure: BK=128 single-buffer, 2 barriers per 128-K tile, seg-swizzled
// LDS, XCD-chunked pair map.
static __device__ __forceinline__ void simtopk_fp8_body(
    int bid, char* smem, const u8* __restrict__ F, const float* __restrict__ rn,
    u32* __restrict__ tv) {
  u8*    sB   = (u8*)smem;                   // I rows, cols [k0,k0+64)    [128][64B]
  u8*    sA   = (u8*)(smem + 16384);         // J rows, cols [k0,k0+64)    [128][64B]
  // region +8192 within each: cols [k0+64,k0+128), same layout
  float* T    = (float*)smem;                // transpose [128][66] = 33792 B (epilogue)
  int*   mk   = (int*)smem;                  // merge dump [128][40] (epilogue)
  int*   mk2  = (int*)(smem + 20480);        // repacked [128][10] (epilogue)
  float* sRNI = (float*)(smem + 33792);
  float* sRNJ = (float*)(smem + 34304);

  const int tid  = threadIdx.x;
  const int lane = tid & 63;
  const int wv   = tid >> 6;
  const int n15  = lane & 15;
  const int quad = lane >> 4;

  int I = 0, rem = xcd_swz(bid);
  { int rowlen = NCHUNK;
    while (rem >= rowlen) { rem -= rowlen; rowlen--; I++; } }
  const int J = I + rem;

  const int l2   = lane >> 2;
  const int lseg = (lane & 3) ^ (l2 & 3) ^ (lane >> 4);   // logical seg to fetch
  const u8* gB[2]; const u8* gA[2]; u8* lB[2]; u8* lA[2];
  #pragma unroll
  for (int rep = 0; rep < 2; ++rep) {
    int row = wv * 32 + rep * 16 + l2;
    gB[rep] = F + (size_t)(I * 128 + row) * 4096 + lseg * 16;
    gA[rep] = F + (size_t)(J * 128 + row) * 4096 + lseg * 16;
    lB[rep] = sB + (wv * 32 + rep * 16) * 64;
    lA[rep] = sA + (wv * 32 + rep * 16) * 64;
  }
  const int s_n = (n15 & 3) ^ (n15 >> 2);
  const int q2  = quad >> 1;
  const int q8  = (quad & 1) * 8;
  const int rB0 = (wv * 32 + n15) * 64;
  const int rB1 = rB0 + 16 * 64;

  f32x4 acc[2][8];
  #pragma unroll
  for (int tf = 0; tf < 2; ++tf)
    #pragma unroll
    for (int af = 0; af < 8; ++af) { f32x4 z = {0.f,0.f,0.f,0.f}; acc[tf][af] = z; }

  for (int k0 = 0; k0 < 4096; k0 += 128) {
    __syncthreads();
    gl_lds16(gB[0] + k0,      lB[0]);
    gl_lds16(gB[0] + k0 + 64, lB[0] + 8192);
    gl_lds16(gB[1] + k0,      lB[1]);
    gl_lds16(gB[1] + k0 + 64, lB[1] + 8192);
    gl_lds16(gA[0] + k0,      lA[0]);
    gl_lds16(gA[0] + k0 + 64, lA[0] + 8192);
    gl_lds16(gA[1] + k0,      lA[1]);
    gl_lds16(gA[1] + k0 + 64, lA[1] + 8192);
    if (k0 == 0) {
      if (tid < 128) sRNJ[tid] = rn[J * 128 + tid];
      else           sRNI[tid - 128] = rn[I * 128 + (tid - 128)];
    }
    __syncthreads();
    #pragma unroll
    for (int ksub = 0; ksub < 2; ++ksub) {
      const u8* bBase = sB + ksub * 8192;
      const u8* aBase = sA + ksub * 8192;
      #pragma unroll
      for (int ks = 0; ks < 2; ++ks) {
        const int sw = (((ks * 2 + q2) ^ s_n) << 4) + q8;
        long long b0 = *(const long long*)(bBase + rB0 + sw);
        long long b1 = *(const long long*)(bBase + rB1 + sw);
        #pragma unroll
        for (int af = 0; af < 8; ++af) {
          long long a = *(const long long*)(aBase + (af * 16 + n15) * 64 + sw);
          acc[0][af] = __builtin_amdgcn_mfma_f32_16x16x32_fp8_fp8(a, b0, acc[0][af], 0, 0, 0);
          acc[1][af] = __builtin_amdgcn_mfma_f32_16x16x32_fp8_fp8(a, b1, acc[1][af], 0, 0, 0);
        }
      }
    }
  }

  // ---- I-side: target rows in I, cands in J ----
  int bk[2][10];
  #pragma unroll
  for (int tf = 0; tf < 2; ++tf)
    #pragma unroll
    for (int j = 0; j < 10; ++j) bk[tf][j] = 0;

  #pragma unroll
  for (int af = 0; af < 8; ++af) {
    const float4 rn4 = *(const float4*)(sRNJ + af * 16 + quad * 4);
    const float rna[4] = {rn4.x, rn4.y, rn4.z, rn4.w};
    #pragma unroll
    for (int r = 0; r < 4; ++r) {
      const int ci = J * 128 + af * 16 + quad * 4 + r;
      #pragma unroll
      for (int tf = 0; tf < 2; ++tf) {
        float v = acc[tf][af][r] * rna[r];
        int key = (int)((__float_as_uint(v) & 0xFFFFE000u) | (u32)ci);
        if (ci < NI_C && key > bk[tf][9]) {
          bk[tf][9] = key;
          #pragma unroll
          for (int j = 9; j > 0; --j)
            if (bk[tf][j] > bk[tf][j-1]) { int t = bk[tf][j]; bk[tf][j] = bk[tf][j-1]; bk[tf][j-1] = t; }
        }
      }
    }
  }
  __syncthreads();
  #pragma unroll
  for (int tf = 0; tf < 2; ++tf) {
    int rl = wv * 32 + tf * 16 + n15;
    #pragma unroll
    for (int j = 0; j < 10; ++j) mk[rl * 40 + quad * 10 + j] = bk[tf][j];
  }
  __syncthreads();
  if (tid < 128) {                            // 4-way sorted-list tournament
    int* m = mk + tid * 40;
    int h0 = 0, h1 = 10, h2 = 20, h3 = 30;
    int v0 = m[0], v1 = m[10], v2 = m[20], v3 = m[30];
    #pragma unroll
    for (int s = 0; s < 10; ++s) {
      int m01 = v0 > v1 ? v0 : v1, m23 = v2 > v3 ? v2 : v3;
      int mx = m01 > m23 ? m01 : m23;
      mk2[tid * 10 + s] = mx;
      if      (mx == v0) { ++h0; v0 = (h0 < 10) ? m[h0] : (int)0x80000000; }
      else if (mx == v1) { ++h1; v1 = (h1 < 20) ? m[h1] : (int)0x80000000; }
      else if (mx == v2) { ++h2; v2 = (h2 < 30) ? m[h2] : (int)0x80000000; }
      else               { ++h3; v3 = (h3 < 40) ? m[h3] : (int)0x80000000; }
    }
  }
  __syncthreads();
  { u32* o = tv + ((size_t)J * NPAD_C + I * 128) * 10;
    for (int g = tid; g < 1280; g += 256) o[g] = (u32)mk2[g]; }

  if (I == J) return;

  // ---- J-side: target rows in J, cands in I (via transpose) ----
  int bj[2][10];
  #pragma unroll
  for (int s = 0; s < 2; ++s)
    #pragma unroll
    for (int j = 0; j < 10; ++j) bj[s][j] = 0;

  #pragma unroll
  for (int tf = 0; tf < 2; ++tf) {
    __syncthreads();
    #pragma unroll
    for (int af = 0; af < 8; ++af)
      #pragma unroll
      for (int r = 0; r < 4; ++r)
        T[(af * 16 + quad * 4 + r) * 66 + wv * 16 + n15] = acc[tf][af][r];
    __syncthreads();
    #pragma unroll
    for (int s = 0; s < 2; ++s) {
      const int c_own = wv * 32 + s * 16 + n15;
      #pragma unroll
      for (int j = 0; j < 16; ++j) {
        const int t  = quad * 32 + tf * 16 + j;
        const int t64 = quad * 16 + j;
        float v = T[c_own * 66 + t64] * sRNI[t];
        const int ti = I * 128 + t;
        int key = (int)((__float_as_uint(v) & 0xFFFFE000u) | (u32)ti);
        if (ti < NI_C && key > bj[s][9]) {
          bj[s][9] = key;
          #pragma unroll
          for (int q = 9; q > 0; --q)
            if (bj[s][q] > bj[s][q-1]) { int tt = bj[s][q]; bj[s][q] = bj[s][q-1]; bj[s][q-1] = tt; }
        }
      }
    }
  }
  __syncthreads();
  #pragma unroll
  for (int s = 0; s < 2; ++s) {
    int rl = wv * 32 + s * 16 + n15;
    #pragma unroll
    for (int j = 0; j < 10; ++j) mk[rl * 40 + quad * 10 + j] = bj[s][j];
  }
  __syncthreads();
  if (tid < 128) {
    int* m = mk + tid * 40;
    int h0 = 0, h1 = 10, h2 = 20, h3 = 30;
    int v0 = m[0], v1 = m[10], v2 = m[20], v3 = m[30];
    #pragma unroll
    for (int s = 0; s < 10; ++s) {
      int m01 = v0 > v1 ? v0 : v1, m23 = v2 > v3 ? v2 : v3;
      int mx = m01 > m23 ? m01 : m23;
      mk2[tid * 10 + s] = mx;
      if      (mx == v0) { ++h0; v0 = (h0 < 10) ? m[h0] : (int)0x80000000; }
      else if (mx == v1) { ++h1; v1 = (h1 < 20) ? m[h1] : (int)0x80000000; }
      else if (mx == v2) { ++h2; v2 = (h2 < 30) ? m[h2] : (int)0x80000000; }
      else               { ++h3; v3 = (h3 < 40) ? m[h3] : (int)0x80000000; }
    }
  }
  __syncthreads();
  { u32* o = tv + ((size_t)I * NPAD_C + J * 128) * 10;
    for (int g = tid; g < 1280; g += 256) o[g] = (u32)mk2[g]; }
}

// ---------------- bf16 symmetric fused Gram + top-10 body (t-graph, D=768) ----------------
// LDS compacted to 34816 B: sRNI@33792 sRNJ@34304 (disjoint from staging [0,32768)
// and T [0,33792); mk/mk2 < 33792).
static __device__ __forceinline__ void simtopk_bf16_body(
    int bid, char* smem, const u16* __restrict__ F, const float* __restrict__ rn,
    u32* __restrict__ tv) {
  u16*   sB   = (u16*)smem;
  u16*   sA   = (u16*)(smem + 16384);
  float* T    = (float*)smem;
  int*   mk   = (int*)smem;
  int*   mk2  = (int*)(smem + 20480);
  float* sRNI = (float*)(smem + 33792);
  float* sRNJ = (float*)(smem + 34304);

  const int tid  = threadIdx.x;
  const int lane = tid & 63;
  const int wv   = tid >> 6;
  const int n15  = lane & 15;
  const int quad = lane >> 4;

  int I = 0, rem = xcd_swz(bid);
  { int rowlen = NCHUNK;
    while (rem >= rowlen) { rem -= rowlen; rowlen--; I++; } }
  const int J = I + rem;

  const int l8  = lane >> 3;
  const int sgu = ((lane & 7) ^ l8) << 3;
  const u16* gB[4]; const u16* gA[4]; u16* lB[4]; u16* lA[4];
  #pragma unroll
  for (int rep = 0; rep < 4; ++rep) {
    int row = wv * 32 + rep * 8 + l8;
    gB[rep] = F + (size_t)(I * 128 + row) * 768 + sgu;
    gA[rep] = F + (size_t)(J * 128 + row) * 768 + sgu;
    lB[rep] = sB + wv * 2048 + rep * 512;
    lA[rep] = sA + wv * 2048 + rep * 512;
  }
  const int swu0 = ((quad    ) ^ (n15 & 7)) << 3;
  const int swu1 = ((quad + 4) ^ (n15 & 7)) << 3;
  const int rowB0 = (wv * 32 + n15) * 64;
  const int rowB1 = rowB0 + 16 * 64;

  f32x4 acc[2][8];
  #pragma unroll
  for (int tf = 0; tf < 2; ++tf)
    #pragma unroll
    for (int af = 0; af < 8; ++af) { f32x4 z = {0.f,0.f,0.f,0.f}; acc[tf][af] = z; }

  for (int k0 = 0; k0 < 768; k0 += 64) {
    __syncthreads();
    #pragma unroll
    for (int rep = 0; rep < 4; ++rep) gl_lds16(gB[rep] + k0, lB[rep]);
    #pragma unroll
    for (int rep = 0; rep < 4; ++rep) gl_lds16(gA[rep] + k0, lA[rep]);
    if (k0 == 0) {
      if (tid < 128) sRNJ[tid] = rn[J * 128 + tid];
      else           sRNI[tid - 128] = rn[I * 128 + (tid - 128)];
    }
    __syncthreads();
    #pragma unroll
    for (int ks = 0; ks < 2; ++ks) {
      const int swu = ks ? swu1 : swu0;
      bf16x8 b0 = *(const bf16x8*)(sB + rowB0 + swu);
      bf16x8 b1 = *(const bf16x8*)(sB + rowB1 + swu);
      #pragma unroll
      for (int af = 0; af < 8; ++af) {
        bf16x8 a = *(const bf16x8*)(sA + (af * 16 + n15) * 64 + swu);
        acc[0][af] = __builtin_amdgcn_mfma_f32_16x16x32_bf16(a, b0, acc[0][af], 0, 0, 0);
        acc[1][af] = __builtin_amdgcn_mfma_f32_16x16x32_bf16(a, b1, acc[1][af], 0, 0, 0);
      }
    }
  }

  int bk[2][10];
  #pragma unroll
  for (int tf = 0; tf < 2; ++tf)
    #pragma unroll
    for (int j = 0; j < 10; ++j) bk[tf][j] = 0;

  #pragma unroll
  for (int af = 0; af < 8; ++af) {
    const float4 rn4 = *(const float4*)(sRNJ + af * 16 + quad * 4);
    const float rna[4] = {rn4.x, rn4.y, rn4.z, rn4.w};
    #pragma unroll
    for (int r = 0; r < 4; ++r) {
      const int ci = J * 128 + af * 16 + quad * 4 + r;
      #pragma unroll
      for (int tf = 0; tf < 2; ++tf) {
        float v = acc[tf][af][r] * rna[r];
        int key = (int)((__float_as_uint(v) & 0xFFFFE000u) | (u32)ci);
        if (ci < NI_C && key > bk[tf][9]) {
          bk[tf][9] = key;
          #pragma unroll
          for (int j = 9; j > 0; --j)
            if (bk[tf][j] > bk[tf][j-1]) { int t = bk[tf][j]; bk[tf][j] = bk[tf][j-1]; bk[tf][j-1] = t; }
        }
      }
    }
  }
  __syncthreads();
  #pragma unroll
  for (int tf = 0; tf < 2; ++tf) {
    int rl = wv * 32 + tf * 16 + n15;
    #pragma unroll
    for (int j = 0; j < 10; ++j) mk[rl * 40 + quad * 10 + j] = bk[tf][j];
  }
  __syncthreads();
  if (tid < 128) {
    int* m = mk + tid * 40;
    int h0 = 0, h1 = 10, h2 = 20, h3 = 30;
    int v0 = m[0], v1 = m[10], v2 = m[20], v3 = m[30];
    #pragma unroll
    for (int s = 0; s < 10; ++s) {
      int m01 = v0 > v1 ? v0 : v1, m23 = v2 > v3 ? v2 : v3;
      int mx = m01 > m23 ? m01 : m23;
      mk2[tid * 10 + s] = mx;
      if      (mx == v0) { ++h0; v0 = (h0 < 10) ? m[h0] : (int)0x80000000; }
      else if (mx == v1) { ++h1; v1 = (h1 < 20) ? m[h1] : (int)0x80000000; }
      else if (mx == v2) { ++h2; v2 = (h2 < 30) ? m[h2] : (int)0x80000000; }
      else               { ++h3; v3 = (h3 < 40) ? m[h3] : (int)0x80000000; }
    }
  }
  __syncthreads();
  { u32* o = tv + ((size_t)J * NPAD_C + I * 128) * 10;
    for (int g = tid; g < 1280; g += 256) o[g] = (u32)mk2[g]; }

  if (I == J) return;

  int bj[2][10];
  #pragma unroll
  for (int s = 0; s < 2; ++s)
    #pragma unroll
    for (int j = 0; j < 10; ++j) bj[s][j] = 0;

  #pragma unroll
  for (int tf = 0; tf < 2; ++tf) {
    __syncthreads();
    #pragma unroll
    for (int af = 0; af < 8; ++af)
      #pragma unroll
      for (int r = 0; r < 4; ++r)
        T[(af * 16 + quad * 4 + r) * 66 + wv * 16 + n15] = acc[tf][af][r];
    __syncthreads();
    #pragma unroll
    for (int s = 0; s < 2; ++s) {
      const int c_own = wv * 32 + s * 16 + n15;
      #pragma unroll
      for (int j = 0; j < 16; ++j) {
        const int t  = quad * 32 + tf * 16 + j;
        const int t64 = quad * 16 + j;
        float v = T[c_own * 66 + t64] * sRNI[t];
        const int ti = I * 128 + t;
        int key = (int)((__float_as_uint(v) & 0xFFFFE000u) | (u32)ti);
        if (ti < NI_C && key > bj[s][9]) {
          bj[s][9] = key;
          #pragma unroll
          for (int q = 9; q > 0; --q)
            if (bj[s][q] > bj[s][q-1]) { int tt = bj[s][q]; bj[s][q] = bj[s][q-1]; bj[s][q-1] = tt; }
        }
      }
    }
  }
  __syncthreads();
  #pragma unroll
  for (int s = 0; s < 2; ++s) {
    int rl = wv * 32 + s * 16 + n15;
    #pragma unroll
    for (int j = 0; j < 10; ++j) mk[rl * 40 + quad * 10 + j] = bj[s][j];
  }
  __syncthreads();
  if (tid < 128) {
    int* m = mk + tid * 40;
    int h0 = 0, h1 = 10, h2 = 20, h3 = 30;
    int v0 = m[0], v1 = m[10], v2 = m[20], v3 = m[30];
    #pragma unroll
    for (int s = 0; s < 10; ++s) {
      int m01 = v0 > v1 ? v0 : v1, m23 = v2 > v3 ? v2 : v3;
      int mx = m01 > m23 ? m01 : m23;
      mk2[tid * 10 + s] = mx;
      if      (mx == v0) { ++h0; v0 = (h0 < 10) ? m[h0] : (int)0x80000000; }
      else if (mx == v1) { ++h1; v1 = (h1 < 20) ? m[h1] : (int)0x80000000; }
      else if (mx == v2) { ++h2; v2 = (h2 < 30) ? m[h2] : (int)0x80000000; }
      else               { ++h3; v3 = (h3 < 40) ? m[h3] : (int)0x80000000; }
    }
  }
  __syncthreads();
  { u32* o = tv + ((size_t)I * NPAD_C + J * 128) * 10;
    for (int g = tid; g < 1280; g += 256) o[g] = (u32)mk2[g]; }
}

// ---------------- merge: 63 sorted lists x 10 -> top-10, 4 rows per 256-thr block ----
static __device__ __forceinline__ void merge4_body(int mb, int* fkbase,
                                                   const u32* __restrict__ tv,
                                                   int* __restrict__ idx) {
  const int w    = threadIdx.x >> 6;
  const int lane = threadIdx.x & 63;
  const int row  = mb * 4 + w;
  int* fk = fkbase + w * 640;
  for (int g = lane; g < 630; g += 64)
    fk[g] = (int)tv[((size_t)(g / 10) * NPAD_C + row) * 10 + (g % 10)];
  if (lane < 10) fk[630 + lane] = (int)0x80000000;
  __syncthreads();
  int v[10];
  #pragma unroll
  for (int j = 0; j < 10; ++j) v[j] = fk[lane + j * 64];
  #pragma unroll 1
  for (int s = 0; s < 10; ++s) {
    int loc = v[0];
    #pragma unroll
    for (int j = 1; j < 10; ++j) loc = v[j] > loc ? v[j] : loc;
    #pragma unroll
    for (int off = 32; off; off >>= 1) {
      int o = __shfl_xor(loc, off); loc = o > loc ? o : loc;
    }
    if (lane == 0) idx[row * 10 + s] = loc & 0x1FFF;
    #pragma unroll
    for (int j = 0; j < 10; ++j) if (v[j] == loc) v[j] = (int)0x80000000;
  }
}

// ---------------- feat @ W via bf16 MFMA body, M=64 tiles ----------------
template<int D>
static __device__ __forceinline__ void gemm_xw_body(
    int bid, char* smem, const u16* __restrict__ F, const u16* __restrict__ Wt,
    float* __restrict__ x2, int modeoff) {
  u16* sF = (u16*)smem;                      // 8192 B
  const int tid  = threadIdx.x;
  const int lane = tid & 63;
  const int wv   = tid >> 6;
  const int n15  = lane & 15;
  const int quad = lane >> 4;
  const int l8   = lane >> 3;
  const int sgu  = ((lane & 7) ^ l8) << 3;
  const u16* gF[2]; u16* lF[2];
  #pragma unroll
  for (int rep = 0; rep < 2; ++rep) {
    int row = rep * 32 + wv * 8 + l8;
    gF[rep] = F + (size_t)(bid * 64 + row) * D + sgu;
    lF[rep] = sF + (rep * 32 + wv * 8) * 64;
  }
  const int swu0 = ((quad    ) ^ (n15 & 7)) << 3;
  const int swu1 = ((quad + 4) ^ (n15 & 7)) << 3;

  f32x4 acc[4];
  #pragma unroll
  for (int nf = 0; nf < 4; ++nf) { f32x4 z = {0.f,0.f,0.f,0.f}; acc[nf] = z; }

  for (int k0 = 0; k0 < D; k0 += 64) {
    __syncthreads();
    gl_lds16(gF[0] + k0, lF[0]);
    gl_lds16(gF[1] + k0, lF[1]);
    __syncthreads();
    #pragma unroll
    for (int ks = 0; ks < 2; ++ks) {
      const int swu = ks ? swu1 : swu0;
      bf16x8 a = *(const bf16x8*)(sF + (wv * 16 + n15) * 64 + swu);
      #pragma unroll
      for (int nf = 0; nf < 4; ++nf) {
        bf16x8 b = *(const bf16x8*)(Wt + (size_t)(nf * 16 + n15) * D + k0 + ks * 32 + quad * 8);
        acc[nf] = __builtin_amdgcn_mfma_f32_16x16x32_bf16(a, b, acc[nf], 0, 0, 0);
      }
    }
  }
  #pragma unroll
  for (int nf = 0; nf < 4; ++nf)
    #pragma unroll
    for (int r = 0; r < 4; ++r) {
      int row = bid * 64 + wv * 16 + quad * 4 + r;
      if (row < NI_C)
        x2[(size_t)(NU_C + row) * 128 + modeoff + nf * 16 + n15] = acc[nf][r];
    }
}

// ---------------- gather bodies ----------------
static __device__ __forceinline__ void gather2_body(
    int bid, const int* __restrict__ row_start, const int* __restrict__ esrc,
    const float* __restrict__ ew, const float* __restrict__ x2, float* __restrict__ h1) {
  const int node = bid * 2 + (threadIdx.x >> 7);
  const int ch   = threadIdx.x & 127;
  if (node >= NTOT_C) return;
  const int b = row_start[node], e = row_start[node + 1];
  float acc = 0.f;
  for (int i = b; i < e; ++i)
    acc += ew[i] * x2[(size_t)esrc[i] * 128 + ch];
  h1[(size_t)node * 128 + ch] = acc;
}

static __device__ __forceinline__ void gather_comb2_body(
    int bid, const int* __restrict__ row_start, const int* __restrict__ esrc,
    const float* __restrict__ ew, const float* __restrict__ x2,
    const float* __restrict__ h1, const float* __restrict__ alpha,
    float* __restrict__ uf, float* __restrict__ ifb) {
  const int node = bid * 2 + (threadIdx.x >> 7);
  const int ch   = threadIdx.x & 127;
  if (node >= NTOT_C) return;
  const int b = row_start[node], e = row_start[node + 1];
  float acc = 0.f;
  for (int i = b; i < e; ++i)
    acc += ew[i] * h1[(size_t)esrc[i] * 128 + ch];
  float val = x2[(size_t)node * 128 + ch] + h1[(size_t)node * 128 + ch] + acc;
  if (node < NU_C) {
    float av = 1.f / (1.f + expf(-alpha[0]));
    float coef = (ch < 64) ? av : (1.f - av);
    uf[(size_t)node * 128 + ch] = coef * val;
  } else {
    ifb[(size_t)(node - NU_C) * 128 + ch] = val;
  }
}

// ---------------- place body (CSR fill) ----------------
static __device__ __forceinline__ void place_body(
    int bid, const int* __restrict__ eu, const int* __restrict__ ei,
    const float* __restrict__ dinv, int* __restrict__ cursor,
    int* __restrict__ esrc, float* __restrict__ ew) {
  int e = bid * 256 + threadIdx.x;
  if (e >= NE_C) return;
  int u = eu[e], v = NU_C + ei[e];
  float w = dinv[u] * dinv[v];
  int p1 = atomicAdd(&cursor[v], 1);  esrc[p1] = u; ew[p1] = w;
  int p2 = atomicAdd(&cursor[u], 1);  esrc[p2] = v; ew[p2] = w;
}

// ---------------- fused launches (LPT ordering: long/latency-bound blocks FIRST) ----
// F1: gemm_xw<4096> (125) ++ gemm_xw<768> (125) ++ simtopk_fp8 (2016, pole) ++
//     place (782 trivial blocks, slot into the drain tail; feeds gather kernels).
__launch_bounds__(256)
__global__ void fusedA_kernel(const u8* __restrict__ F8, const float* __restrict__ rnv,
                              u32* __restrict__ tv,
                              const u16* __restrict__ Fvb, const u16* __restrict__ Wtv,
                              const u16* __restrict__ Ftb, const u16* __restrict__ Wtt,
                              float* __restrict__ x2,
                              const int* __restrict__ eu, const int* __restrict__ ei,
                              const float* __restrict__ dinv, int* __restrict__ cursor,
                              int* __restrict__ esrc, float* __restrict__ ew) {
  __shared__ __align__(16) char smem[34816];
  int b = blockIdx.x;
  if (b < 125) { gemm_xw_body<4096>(b, smem, Fvb, Wtv, x2, 0); return; }
  b -= 125;
  if (b < 125) { gemm_xw_body<768>(b, smem, Ftb, Wtt, x2, 64); return; }
  b -= 125;
  if (b < NPAIR) { simtopk_fp8_body(b, smem, F8, rnv, tv); return; }
  place_body(b - NPAIR, eu, ei, dinv, cursor, esrc, ew);
}

// FB1: simtopk_t (2016, pole, first; tvb2 = dead fvbf) ++ merge_v (2000).
// Split from gather2 so the gathers get full wave occupancy (LDS here caps
// blocks/CU at 4; the gathers don't need that LDS).
__launch_bounds__(256)
__global__ void fusedB1_kernel(const u16* __restrict__ Ftb, const float* __restrict__ rnt,
                               u32* __restrict__ tv2,
                               const u32* __restrict__ tv, int* __restrict__ idx) {
  __shared__ __align__(16) char smem[34816];
  int b = blockIdx.x;
  if (b < NPAIR) { simtopk_bf16_body(b, smem, Ftb, rnt, tv2); return; }
  merge4_body(b - NPAIR, (int*)smem, tv, idx);
}

// FB2: gather2 (14000, first, full occupancy) ++ merge_t (2000; tvb2 from FB1).
__launch_bounds__(256)
__global__ void fusedB2_kernel(const int* __restrict__ row_start, const int* __restrict__ esrc,
                               const float* __restrict__ ew, const float* __restrict__ x2,
                               float* __restrict__ h1,
                               const u32* __restrict__ tv2, int* __restrict__ idxt) {
  __shared__ __align__(16) int fk[4 * 640];
  int b = blockIdx.x;
  if (b < 14000) { gather2_body(b, row_start, esrc, ew, x2, h1); return; }
  merge4_body(b - 14000, fk, tv2, idxt);
}

// FC: gather_comb2 alone (no LDS -> full occupancy).
// Safe: tvb (pC) was consumed by merge_v in FB1, so u_f/i_f writes over pC are race-free.
__launch_bounds__(256)
__global__ void gcomb_kernel(const int* __restrict__ row_start, const int* __restrict__ esrc,
                             const float* __restrict__ ew, const float* __restrict__ x2,
                             const float* __restrict__ h1, const float* __restrict__ alpha,
                             float* __restrict__ uf, float* __restrict__ ifb) {
  gather_comb2_body(blockIdx.x, row_start, esrc, ew, x2, h1, alpha, uf, ifb);
}

// ---------------- scan (CSR prefix) ----------------
__global__ void scan_kernel(float* __restrict__ deg, int* __restrict__ row_start,
                            int* __restrict__ cursor) {
  __shared__ int part[1024];
  const int tid = threadIdx.x;
  const int base = tid * 28;
  float dl[28];
  int local[28];
  int s = 0;
  #pragma unroll
  for (int j = 0; j < 28; ++j) {
    int n = base + j;
    float df = (n < NTOT_C) ? deg[n] : 0.f;
    dl[j] = df;
    local[j] = s; s += (int)df;
  }
  part[tid] = s;
  __syncthreads();
  for (int off = 1; off < 1024; off <<= 1) {
    int v = (tid >= off) ? part[tid - off] : 0;
    __syncthreads();
    part[tid] += v;
    __syncthreads();
  }
  int pre = (tid > 0) ? part[tid - 1] : 0;
  #pragma unroll
  for (int j = 0; j < 28; ++j) {
    int n = base + j;
    if (n < NTOT_C) {
      row_start[n] = pre + local[j];
      cursor[n]    = pre + local[j];
      deg[n]       = rsqrtf(fmaxf(dl[j], 1.f));
    }
  }
  if (tid == 1023) row_start[NTOT_C] = part[1023];
}

// ---------------- fused zu/zi + bpr loss: one wave per batch element ----------------
// Same per-value arithmetic as the old zuzi+loss pair; softmax exp is computed
// once per wave (lane k<20) and broadcast (bit-identical: max is order-free,
// ssum accumulated k=0..19 in original order).
__launch_bounds__(256)
__global__ void zuloss_kernel(const float* __restrict__ uf, const float* __restrict__ w,
                              const int* __restrict__ nb, const float* __restrict__ ifb,
                              const int* __restrict__ iv, const int* __restrict__ it,
                              const int* __restrict__ uid, const int* __restrict__ pid,
                              const int* __restrict__ nid, float* __restrict__ out) {
  const int wv = threadIdx.x >> 6, lane = threadIdx.x & 63;
  const int b = blockIdx.x * 4 + wv;
  const int u = uid[b], p = pid[b], n = nid[b];
  const int c = lane * 2;

  // distributed softmax over the 20 user-attn weights
  float mv = (lane < 20) ? w[u * 20 + lane] : -1e30f;
  float m = mv;
  #pragma unroll
  for (int off = 32; off; off >>= 1) m = fmaxf(m, __shfl_xor(m, off));
  float ek_own = expf(mv - m);               // valid for lanes 0..19
  float e[20]; float ssum = 0.f;
  #pragma unroll
  for (int k = 0; k < 20; ++k) { e[k] = __shfl(ek_own, k); ssum += e[k]; }
  float inv = 1.f / ssum;

  // z_u = uf[u] + sum_k e[k]*inv*uf[nb[u,k]]   (same accumulation order as zuzi)
  float2 zu = *(const float2*)(uf + (size_t)u * 128 + c);
  float ax = 0.f, ay = 0.f;
  #pragma unroll
  for (int k = 0; k < 20; ++k) {
    int j = nb[u * 20 + k];
    float2 t = *(const float2*)(uf + (size_t)j * 128 + c);
    ax += e[k] * inv * t.x;
    ay += e[k] * inv * t.y;
  }
  zu.x += ax; zu.y += ay;

  // z_i = ifb[i] + 0.01*sum(iv rows) + 0.09*sum(it rows)   (same order as zuzi)
  float2 zp, zn;
  #pragma unroll
  for (int side = 0; side < 2; ++side) {
    const int i = side ? n : p;
    float svx = 0.f, svy = 0.f, stx = 0.f, sty = 0.f;
    #pragma unroll
    for (int k = 0; k < 10; ++k) {
      float2 t = *(const float2*)(ifb + (size_t)iv[i * 10 + k] * 128 + c);
      svx += t.x; svy += t.y;
    }
    #pragma unroll
    for (int k = 0; k < 10; ++k) {
      float2 t = *(const float2*)(ifb + (size_t)it[i * 10 + k] * 128 + c);
      stx += t.x; sty += t.y;
    }
    float2 base = *(const float2*)(ifb + (size_t)i * 128 + c);
    float2 r;
    r.x = base.x + 0.01f * svx + 0.09f * stx;
    r.y = base.y + 0.01f * svy + 0.09f * sty;
    if (side) zn = r; else zp = r;
  }

  float d = zu.x * (zp.x - zn.x) + zu.y * (zp.y - zn.y);
  #pragma unroll
  for (int off = 32; off; off >>= 1) d += __shfl_xor(d, off);
  if (lane == 0) {
    float xv = -d;
    float sp = fmaxf(xv, 0.f) + log1pf(expf(-fabsf(xv)));
    atomicAdd(out, sp * (1.f / (float)B_C));
  }
}

// ---------------- launcher ----------------
extern "C" void kernel_launch(void* const* d_in, const int* in_sizes, int n_in,
                              void* d_out, int out_size, void* d_ws, size_t ws_size,
                              hipStream_t stream) {
  const float* feat_v = (const float*)d_in[0];
  const float* feat_t = (const float*)d_in[1];
  const float* pref_v = (const float*)d_in[2];
  const float* pref_t = (const float*)d_in[3];
  const float* W_v    = (const float*)d_in[4];
  const float* W_t    = (const float*)d_in[5];
  const float* alpha  = (const float*)d_in[6];
  const float* unw    = (const float*)d_in[7];
  const int* eu       = (const int*)d_in[8];
  const int* ei       = (const int*)d_in[9];
  const int* u_ids    = (const int*)d_in[10];
  const int* pos_ids  = (const int*)d_in[11];
  const int* neg_ids  = (const int*)d_in[12];
  const int* user_nb  = (const int*)d_in[13];
  float* out = (float*)d_out;
  char* ws = (char*)d_ws;

  size_t off = 0;
  auto alloc = [&](size_t bytes) { char* p = ws + off; off += (bytes + 255) & ~(size_t)255; return p; };
  u16*   fvbf  = (u16*)alloc((size_t)NPAD_C * 4096 * 2);   // 66.06 MB (gemm; tvb2 after F1)
  u8*    fv8   = (u8*)alloc((size_t)NPAD_C * 4096);        // 33.03 MB (fp8 simtopk)
  u16*   ftbf  = (u16*)alloc((size_t)NPAD_C * 768 * 2);    // 12.39 MB
  u16*   wtv   = (u16*)alloc((size_t)64 * 4096 * 2);
  u16*   wtt   = (u16*)alloc((size_t)64 * 768 * 2);
  float* rn_v  = (float*)alloc(NPAD_C * 4);
  float* rn_t  = (float*)alloc(NPAD_C * 4);
  int*   idx_v = (int*)alloc(NI_C * 10 * 4);
  int*   idx_t = (int*)alloc(NI_C * 10 * 4);
  float* dinv  = (float*)alloc(NTOT_C * 4);
  int*   rowst = (int*)alloc((NTOT_C + 1) * 4);
  int*   curs  = (int*)alloc(NTOT_C * 4);
  int*   esrc  = (int*)alloc((size_t)2 * NE_C * 4);
  float* ew    = (float*)alloc((size_t)2 * NE_C * 4);
  float* x2    = (float*)alloc((size_t)NTOT_C * 128 * 4);  // 14.3 MB
  float* h1    = (float*)alloc((size_t)NTOT_C * 128 * 4);  // 14.3 MB
  char*  pC    = alloc((size_t)(NU_C + NI_C) * 128 * 4);   // 14.3 MB (u_f | i_f)
  u32*   tvb   = (u32*)pC;                                  // v-graph tv (needs 20.3 MB)
  char*  pC2   = alloc((size_t)6 * 1024 * 1024 + 256);      // pad pC region past 20.3 MB
  (void)pC2;
  u32*   tvb2  = (u32*)fvbf;                                // t-graph tv: fvbf dead after F1 gemm
  float* u_f   = (float*)pC;
  float* i_f   = (float*)(pC + (size_t)NU_C * 128 * 4);

  hipMemsetAsync(out, 0, sizeof(float), stream);
  hipMemsetAsync(dinv, 0, NTOT_C * 4, stream);

  // --- K1: conv + wtrans + fill_pref + deg_count + reg-sum ---
  conv_kernel2<<<2 * NPAD_C + 76 + 1250 + NEB + 512, 256, 0, stream>>>(
      feat_v, feat_t, fvbf, ftbf, fv8, rn_v, rn_t, pref_v, pref_t, x2,
      W_v, W_t, wtv, wtt, eu, ei, dinv, alpha, out);

  // --- scan (single block; rowst/curs + dinv finalize) ---
  scan_kernel<<<1, 1024, 0, stream>>>(dinv, rowst, curs);

  // --- F1: gemm_xw x2 ++ simtopk_fp8 ++ place ---
  fusedA_kernel<<<250 + NPAIR + NEB, 256, 0, stream>>>(
      fv8, rn_v, tvb, fvbf, wtv, ftbf, wtt, x2, eu, ei, dinv, curs, esrc, ew);

  // --- FB1: simtopk_t (tv -> tvb2) ++ merge_v ---
  fusedB1_kernel<<<NPAIR + 2000, 256, 0, stream>>>(ftbf, rn_t, tvb2, tvb, idx_v);

  // --- FB2: gather2 (full occupancy) ++ merge_t ---
  fusedB2_kernel<<<14000 + 2000, 256, 0, stream>>>(rowst, esrc, ew, x2, h1, tvb2, idx_t);

  // --- FC: gather_comb2 (full occupancy) ---
  gcomb_kernel<<<14000, 256, 0, stream>>>(rowst, esrc, ew, x2, h1, alpha, u_f, i_f);

  // --- fused zu/zi + loss ---
  zuloss_kernel<<<1024, 256, 0, stream>>>(u_f, unw, user_nb, i_f, idx_v, idx_t,
                                          u_ids, pos_ids, neg_ids, out);
}